// Round 1
// baseline (707.115 us; speedup 1.0000x reference)
//
#include <hip/hip_runtime.h>
#include <math.h>

// Problem constants
#define BB 4
#define TT 2048
#define DD 1024
#define HH 16
#define QKD 64
#define MM (BB*TT)          // 8192
#define NN 1024             // H*QK == D
#define KK 1024

typedef unsigned short u16;
typedef __attribute__((ext_vector_type(8))) short short8;   // 8 bf16 = 4 VGPRs
typedef __attribute__((ext_vector_type(4))) float float4v;  // MFMA C/D

// fp32 -> bf16 round-to-nearest-even
__device__ __forceinline__ u16 f2bf(float f) {
    union { float f; unsigned u; } v; v.f = f;
    unsigned r = (v.u + 0x7FFFu + ((v.u >> 16) & 1u)) >> 16;
    return (u16)r;
}

// packed fp32x2 -> bf16x2 (RTNE), single instruction on gfx950
__device__ __forceinline__ unsigned cvt_pk_bf16(float lo, float hi) {
    unsigned r;
    asm("v_cvt_pk_bf16_f32 %0, %1, %2" : "=v"(r) : "v"(lo), "v"(hi));
    return r;
}

// async global->LDS, 16B per lane; LDS dest = wave-uniform base + lane*16
typedef __attribute__((address_space(3))) unsigned lds_u32_t;
typedef __attribute__((address_space(1))) const unsigned glb_u32_t;
__device__ __forceinline__ void gl2lds16(const u16* g, u16* l) {
    __builtin_amdgcn_global_load_lds((glb_u32_t*)g, (lds_u32_t*)l, 16, 0, 0);
}

// ---------------------------------------------------------------------------
// fp32 -> bf16 cast for activations (q, kv)
// ---------------------------------------------------------------------------
__global__ __launch_bounds__(256) void acast_kernel(
    const float* __restrict__ a, const float* __restrict__ b,
    u16* __restrict__ da, u16* __restrict__ db)
{
    const float* s = blockIdx.y ? b : a;
    u16* d = blockIdx.y ? db : da;
    size_t i = ((size_t)blockIdx.x * 256 + threadIdx.x) * 4;
    float4 v = *(const float4*)&s[i];
    ushort4 o = { f2bf(v.x), f2bf(v.y), f2bf(v.z), f2bf(v.w) };
    *(ushort4*)&d[i] = o;
}

// ---------------------------------------------------------------------------
// Weight transpose + cast: W[K][N] fp32 -> Wt[N][K] bf16, z selects matrix
// ---------------------------------------------------------------------------
__global__ __launch_bounds__(256) void wt_kernel(
    const float* __restrict__ Wq, const float* __restrict__ Wk,
    const float* __restrict__ Wv, const float* __restrict__ Wo,
    u16* __restrict__ dstbase)
{
    const int z = blockIdx.z;
    const float* src = (z == 0) ? Wq : (z == 1) ? Wk : (z == 2) ? Wv : Wo;
    u16* out = dstbase + (size_t)z * (KK * NN);
    const int bi = blockIdx.y, bj = blockIdx.x;  // 64x64 tile: k-block, n-block
    __shared__ float tile[64][65];
    const int t = threadIdx.x;
    #pragma unroll
    for (int p = 0; p < 4; p++) {
        int idx = p * 256 + t;
        int r = idx >> 4, c4 = (idx & 15) << 2;
        float4 v = *(const float4*)&src[(size_t)(bi * 64 + r) * NN + bj * 64 + c4];
        tile[r][c4 + 0] = v.x; tile[r][c4 + 1] = v.y;
        tile[r][c4 + 2] = v.z; tile[r][c4 + 3] = v.w;
    }
    __syncthreads();
    #pragma unroll
    for (int p = 0; p < 4; p++) {
        int idx = p * 256 + t;
        int rn = idx >> 4, c4 = (idx & 15) << 2;
        ushort4 o = { f2bf(tile[c4 + 0][rn]), f2bf(tile[c4 + 1][rn]),
                      f2bf(tile[c4 + 2][rn]), f2bf(tile[c4 + 3][rn]) };
        *(ushort4*)&out[(size_t)(bj * 64 + rn) * KK + bi * 64 + c4] = o;
    }
}

// ---------------------------------------------------------------------------
// bf16 MFMA GEMM main loop (m97 structure): C[128,128] tile, 4 waves, each
// 64x64 via 4x4 grid of 16x16x32 MFMA. BK=64, global_load_lds width-16
// staging, XOR bank swizzle on the k-colblock (slot s of row r holds global
// colblock s^(r&7)).
// A: [M,K] bf16 row-major.  Bt: [N,K] bf16 row-major (i.e. W^T).
// ---------------------------------------------------------------------------
__device__ __forceinline__ void gemm_mainloop(
    const u16* __restrict__ A, const u16* __restrict__ Bt,
    int m0, int n0, u16* As, u16* Bs, float4v (&acc)[4][4])
{
    const int tid = threadIdx.x;
    const int wave = tid >> 6, lane = tid & 63;
    const int l15 = lane & 15, lg = lane >> 4;
    const int wm = wave >> 1, wn = wave & 1;

    const int lr = lane >> 3;   // row within 8-row chunk
    const int lc = lane & 7;    // colblock slot

    for (int k0 = 0; k0 < KK; k0 += 64) {
        #pragma unroll
        for (int i = 0; i < 4; i++) {
            int chunk = wave * 4 + i;          // 0..15
            int row = chunk * 8 + lr;          // 0..127
            int gcb = lc ^ (row & 7);          // swizzled global colblock
            gl2lds16(A  + (size_t)(m0 + row) * KK + k0 + gcb * 8, As + chunk * 512);
            gl2lds16(Bt + (size_t)(n0 + row) * KK + k0 + gcb * 8, Bs + chunk * 512);
        }
        __syncthreads();

        short8 af[2][4], bf[2][4];
        #pragma unroll
        for (int kc = 0; kc < 2; kc++) {
            #pragma unroll
            for (int x = 0; x < 4; x++) {
                int ra = wm * 64 + x * 16 + l15;
                int sa = (kc * 4 + lg) ^ (ra & 7);
                af[kc][x] = *(const short8*)(As + ra * 64 + sa * 8);
                int rb = wn * 64 + x * 16 + l15;
                int sb = (kc * 4 + lg) ^ (rb & 7);
                bf[kc][x] = *(const short8*)(Bs + rb * 64 + sb * 8);
            }
        }
        #pragma unroll
        for (int mi = 0; mi < 4; mi++)
            #pragma unroll
            for (int nj = 0; nj < 4; nj++) {
                acc[mi][nj] = __builtin_amdgcn_mfma_f32_16x16x32_bf16(af[0][mi], bf[0][nj], acc[mi][nj], 0, 0, 0);
                acc[mi][nj] = __builtin_amdgcn_mfma_f32_16x16x32_bf16(af[1][mi], bf[1][nj], acc[mi][nj], 0, 0, 0);
            }
        __syncthreads();
    }
}

// ---------------------------------------------------------------------------
// QKV projection GEMM, z in {0:Q, 1:K, 2:V}. Epilogue fuses bias + RMSNorm +
// RoPE (Q,K) and writes bf16. Q,K -> (B,H,T,QK); V -> transposed (B,H,QK,T)
// so attention can consume V^T rows directly (no in-kernel transpose).
// Q also gets 0.125*log2(e).
// ---------------------------------------------------------------------------
__global__ __launch_bounds__(256) void qkv_gemm(
    const u16* __restrict__ qb, const u16* __restrict__ kvb,
    const u16* __restrict__ Wt,
    const float* __restrict__ bq, const float* __restrict__ bk, const float* __restrict__ bv,
    const int* __restrict__ qpos, const int* __restrict__ kpos,
    const float* __restrict__ q_scale, const float* __restrict__ k_scale,
    u16* __restrict__ qh, u16* __restrict__ kh, u16* __restrict__ vt)
{
    __shared__ u16 As[128 * 64];
    __shared__ u16 Bs[128 * 64];

    const int z = blockIdx.z;
    const u16* A        = (z == 0) ? qb : kvb;
    const u16* B        = Wt + (size_t)z * (KK * NN);
    const float* bias   = (z == 0) ? bq : (z == 1) ? bk : bv;
    const float* scl    = (z == 0) ? q_scale : k_scale;
    const int* pos_arr  = (z == 0) ? qpos : kpos;
    u16* dst            = (z == 0) ? qh : (z == 1) ? kh : vt;

    const int m0 = blockIdx.y * 128, n0 = blockIdx.x * 128;

    float4v acc[4][4];
    #pragma unroll
    for (int i = 0; i < 4; i++)
        #pragma unroll
        for (int j = 0; j < 4; j++) acc[i][j] = (float4v){0.f, 0.f, 0.f, 0.f};

    gemm_mainloop(A, B, m0, n0, As, Bs, acc);

    const int lane = threadIdx.x & 63, wave = threadIdx.x >> 6;
    const int l15 = lane & 15, lg = lane >> 4;
    const int wm = wave >> 1, wn = wave & 1;
    const int mbase = m0 + wm * 64;
    const int nbase = n0 + wn * 64;
    const int h = nbase >> 6;

    // per-lane constants
    float bia[4], sc[4];
    #pragma unroll
    for (int nj = 0; nj < 4; nj++) {
        bia[nj] = bias[nbase - (h << 6) + h * 64 + nj * 16 + l15];  // = bias[h*64+c]
        sc[nj]  = 1.0f + scl[nj * 16 + l15];
    }
    // RoPE inverse timescales for this lane's two low cols (j = p*16+l15)
    float invts[2];
    #pragma unroll
    for (int p = 0; p < 2; p++)
        invts[p] = powf(10000.0f, -(float)(p * 16 + l15) * (1.0f / 32.0f));

    const float QMUL = 0.125f * 1.44269504088896340736f;

    #pragma unroll
    for (int mi = 0; mi < 4; mi++) {
        #pragma unroll
        for (int r = 0; r < 4; r++) {
            const int m = mbase + mi * 16 + lg * 4 + r;
            const int b = m >> 11, t = m & 2047;
            float v[4];
            #pragma unroll
            for (int nj = 0; nj < 4; nj++) v[nj] = acc[mi][nj][r] + bia[nj];

            if (z < 2) {
                float ss = v[0]*v[0] + v[1]*v[1] + v[2]*v[2] + v[3]*v[3];
                ss += __shfl_xor(ss, 1);
                ss += __shfl_xor(ss, 2);
                ss += __shfl_xor(ss, 4);
                ss += __shfl_xor(ss, 8);
                float rn = rsqrtf(ss * (1.0f / 64.0f) + 1e-6f);
                #pragma unroll
                for (int nj = 0; nj < 4; nj++) v[nj] = v[nj] * rn * sc[nj];

                const float pos = (float)pos_arr[b * TT + t];
                #pragma unroll
                for (int p = 0; p < 2; p++) {
                    float ang = pos * invts[p];
                    float s = sinf(ang), c = cosf(ang);
                    float x1 = v[p], x2 = v[p + 2];
                    v[p]     = x1 * c - x2 * s;
                    v[p + 2] = x2 * c + x1 * s;
                }
                if (z == 0) {
                    #pragma unroll
                    for (int nj = 0; nj < 4; nj++) v[nj] *= QMUL;
                }
                u16* op = dst + ((size_t)((b * HH + h) * TT + t)) * QKD + l15;
                #pragma unroll
                for (int nj = 0; nj < 4; nj++) op[nj * 16] = f2bf(v[nj]);
            } else {
                // V: write transposed (B,H,QK,T); d = nj*16 + l15
                u16* op = dst + ((size_t)((b * HH + h) * QKD) + l15) * TT + t;
                #pragma unroll
                for (int nj = 0; nj < 4; nj++) op[(size_t)(nj * 16) * TT] = f2bf(v[nj]);
            }
        }
    }
}

// ---------------------------------------------------------------------------
// Output projection GEMM: attn_b[M,K] bf16 @ Wo_t[N,K]^T + bo -> out fp32
// ---------------------------------------------------------------------------
__global__ __launch_bounds__(256) void out_gemm(
    const u16* __restrict__ A, const u16* __restrict__ Bt,
    const float* __restrict__ bo, float* __restrict__ out)
{
    __shared__ u16 As[128 * 64];
    __shared__ u16 Bs[128 * 64];

    const int m0 = blockIdx.y * 128, n0 = blockIdx.x * 128;

    float4v acc[4][4];
    #pragma unroll
    for (int i = 0; i < 4; i++)
        #pragma unroll
        for (int j = 0; j < 4; j++) acc[i][j] = (float4v){0.f, 0.f, 0.f, 0.f};

    gemm_mainloop(A, Bt, m0, n0, As, Bs, acc);

    const int lane = threadIdx.x & 63, wave = threadIdx.x >> 6;
    const int l15 = lane & 15, lg = lane >> 4;
    const int wm = wave >> 1, wn = wave & 1;
    const int mbase = m0 + wm * 64;
    const int nbase = n0 + wn * 64;

    float bov[4];
    #pragma unroll
    for (int nj = 0; nj < 4; nj++) bov[nj] = bo[nbase + nj * 16 + l15];

    #pragma unroll
    for (int mi = 0; mi < 4; mi++)
        #pragma unroll
        for (int r = 0; r < 4; r++) {
            const int m = mbase + mi * 16 + lg * 4 + r;
            float* op = out + (size_t)m * NN + nbase + l15;
            #pragma unroll
            for (int nj = 0; nj < 4; nj++)
                op[nj * 16] = acc[mi][nj][r] + bov[nj];
        }
}

// ---------------------------------------------------------------------------
// MFMA flash attention, causal.  v3 structure:
//  - K rows and V^T rows staged via global_load_lds (16B) into XOR-swizzled
//    linear LDS (slot s of row r holds global colblock s^(r&7))
//  - double-buffered K/V: next tile's loads issued before current compute,
//    __syncthreads' vmcnt drain is the per-tile wait (T3 minimal 2-phase)
//  - defer-max rescale (T13, THR=8 in exp2 domain)
//  - packed v_cvt_pk_bf16_f32 for the P->bf16 LDS store
//  - per-lane partial rowsum; cross-lane l-reduce once in the epilogue
// ---------------------------------------------------------------------------
__global__ __launch_bounds__(256) void attn_mfma(
    const u16* __restrict__ qh, const u16* __restrict__ kh,
    const u16* __restrict__ vt, const float* __restrict__ head_scale,
    u16* __restrict__ out)
{
    __shared__ __align__(16) u16 Ks[2][64 * 64];   // K rows (swizzled)
    __shared__ __align__(16) u16 Vs[2][64 * 64];   // V^T rows = d (swizzled)
    __shared__ __align__(16) u16 Ps[4][16 * 64];   // per-wave P tile (swizzled)

    const int b = blockIdx.z, h = blockIdx.y, qt = blockIdx.x;
    const int t0 = qt * 64;
    const int tid  = threadIdx.x;
    const int wave = tid >> 6, lane = tid & 63;
    const int l15 = lane & 15, lg = lane >> 4;
    const int l7 = l15 & 7;

    const size_t bh = (size_t)(b * HH + h);
    const u16* qbh  = qh + bh * TT * QKD;
    const u16* kbh  = kh + bh * TT * QKD;
    const u16* vtbh = vt + bh * QKD * TT;   // [QKD][TT]

    short8 qfrag[2];
    #pragma unroll
    for (int kc = 0; kc < 2; kc++)
        qfrag[kc] = *(const short8*)(qbh + (size_t)(t0 + wave * 16 + l15) * QKD
                                      + kc * 32 + lg * 8);

    // stage one 64-key tile (K rows + V^T rows) into buffer `buf`
    auto stage = [&](int buf, int j0s) {
        #pragma unroll
        for (int rr = 0; rr < 2; rr++) {
            const int c   = rr * 256 + tid;     // chunk 0..511 (16B each)
            const int row = c >> 3;             // 0..63
            const int g   = (c & 7) ^ (row & 7);// pre-swizzled global colblock
            u16* ldsK = &Ks[buf][(rr * 256 + (wave << 6)) * 8];
            u16* ldsV = &Vs[buf][(rr * 256 + (wave << 6)) * 8];
            gl2lds16(kbh  + (size_t)(j0s + row) * QKD + g * 8, ldsK);
            gl2lds16(vtbh + (size_t)row * TT + j0s + g * 8, ldsV);
        }
    };

    float4v o_acc[4];
    #pragma unroll
    for (int nt = 0; nt < 4; nt++) o_acc[nt] = (float4v){0.f, 0.f, 0.f, 0.f};
    float m_run[4] = {-INFINITY, -INFINITY, -INFINITY, -INFINITY};
    float l_run[4] = {0.f, 0.f, 0.f, 0.f};

    stage(0, 0);
    __syncthreads();

    const int qbase = t0 + wave * 16 + lg * 4;

    for (int j0 = 0; j0 <= t0; j0 += 64) {
        const int cur = (j0 >> 6) & 1;
        if (j0 + 64 <= t0) stage(cur ^ 1, j0 + 64);   // prefetch next tile

        // ---- QK^T (swizzled K reads) ----
        float4v sarr[4];
        #pragma unroll
        for (int nt = 0; nt < 4; nt++) {
            float4v s = (float4v){0.f, 0.f, 0.f, 0.f};
            #pragma unroll
            for (int kc = 0; kc < 2; kc++) {
                const short8 bfrag = *(const short8*)
                    &Ks[cur][(nt * 16 + l15) * 64 + ((kc * 4 + lg) ^ l7) * 8];
                s = __builtin_amdgcn_mfma_f32_16x16x32_bf16(qfrag[kc], bfrag, s, 0, 0, 0);
            }
            sarr[nt] = s;
        }

        // ---- causal mask (diagonal tile only) ----
        if (j0 == t0) {
            #pragma unroll
            for (int nt = 0; nt < 4; nt++) {
                int jkey = j0 + nt * 16 + l15;
                #pragma unroll
                for (int r = 0; r < 4; r++)
                    if (jkey > qbase + r) sarr[nt][r] = -INFINITY;
            }
        }

        // ---- row max + defer-max rescale (T13) ----
        float pm[4];
        #pragma unroll
        for (int r = 0; r < 4; r++) {
            float m = fmaxf(fmaxf(sarr[0][r], sarr[1][r]), fmaxf(sarr[2][r], sarr[3][r]));
            m = fmaxf(m, __shfl_xor(m, 1));
            m = fmaxf(m, __shfl_xor(m, 2));
            m = fmaxf(m, __shfl_xor(m, 4));
            m = fmaxf(m, __shfl_xor(m, 8));
            pm[r] = m;
        }
        float grow = fmaxf(fmaxf(pm[0] - m_run[0], pm[1] - m_run[1]),
                           fmaxf(pm[2] - m_run[2], pm[3] - m_run[3]));
        if (__any(grow > 8.0f)) {
            #pragma unroll
            for (int r = 0; r < 4; r++) {
                float mn = fmaxf(m_run[r], pm[r]);
                float a  = exp2f(m_run[r] - mn);
                m_run[r] = mn;
                l_run[r] *= a;
                #pragma unroll
                for (int nt = 0; nt < 4; nt++) o_acc[nt][r] *= a;
            }
        }

        // ---- P = exp2(S - m), partial rowsum, packed bf16 store to Ps ----
        u16* pw = Ps[wave];
        float lp[4] = {0.f, 0.f, 0.f, 0.f};
        #pragma unroll
        for (int nt = 0; nt < 4; nt++) {
            float p0 = exp2f(sarr[nt][0] - m_run[0]);
            float p1 = exp2f(sarr[nt][1] - m_run[1]);
            float p2 = exp2f(sarr[nt][2] - m_run[2]);
            float p3 = exp2f(sarr[nt][3] - m_run[3]);
            lp[0] += p0; lp[1] += p1; lp[2] += p2; lp[3] += p3;
            unsigned wlo = cvt_pk_bf16(p0, p1);
            unsigned whi = cvt_pk_bf16(p2, p3);
            const int gb = nt * 2 + (l15 >> 3);
            const int r0 = lg * 4;
            pw[(r0 + 0) * 64 + ((gb ^ ((r0 + 0) & 7))) * 8 + l7] = (u16)wlo;
            pw[(r0 + 1) * 64 + ((gb ^ ((r0 + 1) & 7))) * 8 + l7] = (u16)(wlo >> 16);
            pw[(r0 + 2) * 64 + ((gb ^ ((r0 + 2) & 7))) * 8 + l7] = (u16)whi;
            pw[(r0 + 3) * 64 + ((gb ^ ((r0 + 3) & 7))) * 8 + l7] = (u16)(whi >> 16);
        }
        #pragma unroll
        for (int r = 0; r < 4; r++) l_run[r] += lp[r];

        // ---- read P fragments back (same wave; lgkmcnt ordered) ----
        short8 pf[2];
        #pragma unroll
        for (int kc = 0; kc < 2; kc++)
            pf[kc] = *(const short8*)&pw[l15 * 64 + ((kc * 4 + lg) ^ l7) * 8];

        // ---- PV (swizzled V^T reads) ----
        #pragma unroll
        for (int nt = 0; nt < 4; nt++) {
            #pragma unroll
            for (int kc = 0; kc < 2; kc++) {
                const short8 vfrag = *(const short8*)
                    &Vs[cur][(nt * 16 + l15) * 64 + ((kc * 4 + lg) ^ l7) * 8];
                o_acc[nt] = __builtin_amdgcn_mfma_f32_16x16x32_bf16(pf[kc], vfrag, o_acc[nt], 0, 0, 0);
            }
        }
        __syncthreads();   // drains prefetch vmcnt + protects buffer reuse
    }

    const float hs = 1.0f + head_scale[h];
    #pragma unroll
    for (int r = 0; r < 4; r++) {
        float l = l_run[r];
        l += __shfl_xor(l, 1);
        l += __shfl_xor(l, 2);
        l += __shfl_xor(l, 4);
        l += __shfl_xor(l, 8);
        const int q = t0 + wave * 16 + lg * 4 + r;
        const float f = hs / l;
        u16* op = out + ((size_t)(b * TT + q) * NN) + h * QKD + l15;
        #pragma unroll
        for (int nt = 0; nt < 4; nt++)
            op[nt * 16] = f2bf(o_acc[nt][r] * f);
    }
}

// ---------------------------------------------------------------------------
extern "C" void kernel_launch(void* const* d_in, const int* in_sizes, int n_in,
                              void* d_out, int out_size, void* d_ws, size_t ws_size,
                              hipStream_t stream)
{
    const float* q          = (const float*)d_in[0];
    const float* kv         = (const float*)d_in[1];
    /* d_in[2] = causal mask -- handled analytically */
    const int*   qpos       = (const int*)d_in[3];
    const int*   kpos       = (const int*)d_in[4];
    const float* Wq         = (const float*)d_in[5];
    const float* bq         = (const float*)d_in[6];
    const float* Wk         = (const float*)d_in[7];
    const float* bk         = (const float*)d_in[8];
    const float* Wv         = (const float*)d_in[9];
    const float* bv         = (const float*)d_in[10];
    const float* q_scale    = (const float*)d_in[11];
    const float* k_scale    = (const float*)d_in[12];
    const float* head_scale = (const float*)d_in[13];
    const float* Wo         = (const float*)d_in[14];
    const float* bo         = (const float*)d_in[15];
    float* out = (float*)d_out;

    // workspace layout (bytes):
    //   [  0 MB, 16 MB)  qb    (M,K) bf16
    //   [ 16 MB, 32 MB)  kvb   (M,K) bf16
    //   [ 32 MB, 40 MB)  Wt    4 x (N,K) bf16 transposed: Wq,Wk,Wv,Wo
    //   [ 40 MB, 56 MB)  qh_b  (B,H,T,QK) bf16
    //   [ 56 MB, 72 MB)  kh_b  (B,H,T,QK) bf16
    //   [ 72 MB, 88 MB)  vt_b  (B,H,QK,T) bf16  <-- V stored transposed
    //   [ 88 MB,104 MB)  attn_b (B,T,N) bf16
    char* ws = (char*)d_ws;
    u16* qb     = (u16*)(ws);
    u16* kvb    = (u16*)(ws + (16u << 20));
    u16* Wt     = (u16*)(ws + (32u << 20));
    u16* qh_b   = (u16*)(ws + (40u << 20));
    u16* kh_b   = (u16*)(ws + (56u << 20));
    u16* vt_b   = (u16*)(ws + (72u << 20));
    u16* attn_b = (u16*)(ws + (88u << 20));

    // 1. cast activations to bf16
    acast_kernel<<<dim3(MM * DD / (256 * 4), 2), 256, 0, stream>>>(q, kv, qb, kvb);
    // 2. transpose+cast the four weight matrices
    wt_kernel<<<dim3(16, 16, 4), 256, 0, stream>>>(Wq, Wk, Wv, Wo, Wt);
    // 3. fused QKV projection + bias + RMSNorm + RoPE -> Q,K:(B,H,T,QK), V:(B,H,QK,T)
    qkv_gemm<<<dim3(NN / 128, MM / 128, 3), 256, 0, stream>>>(
        qb, kvb, Wt, bq, bk, bv, qpos, kpos, q_scale, k_scale, qh_b, kh_b, vt_b);
    // 4. causal MFMA flash attention + head_scale -> (B,T,N) bf16
    attn_mfma<<<dim3(TT / 64, HH, BB), 256, 0, stream>>>(qh_b, kh_b, vt_b, head_scale, attn_b);
    // 5. output projection + bias -> fp32
    out_gemm<<<dim3(NN / 128, MM / 128), 256, 0, stream>>>(attn_b, Wt + (size_t)3 * KK * NN, bo, out);
}

// Round 2
// 697.494 us; speedup vs baseline: 1.0138x; 1.0138x over previous
//
#include <hip/hip_runtime.h>
#include <math.h>

// Problem constants
#define BB 4
#define TT 2048
#define DD 1024
#define HH 16
#define QKD 64
#define MM (BB*TT)          // 8192
#define NN 1024             // H*QK == D
#define KK 1024

typedef unsigned short u16;
typedef __attribute__((ext_vector_type(8))) short short8;   // 8 bf16 = 4 VGPRs
typedef __attribute__((ext_vector_type(4))) float float4v;  // MFMA C/D

// fp32 -> bf16 round-to-nearest-even
__device__ __forceinline__ u16 f2bf(float f) {
    union { float f; unsigned u; } v; v.f = f;
    unsigned r = (v.u + 0x7FFFu + ((v.u >> 16) & 1u)) >> 16;
    return (u16)r;
}

// packed fp32x2 -> bf16x2 (RTNE), single instruction on gfx950
__device__ __forceinline__ unsigned cvt_pk_bf16(float lo, float hi) {
    unsigned r;
    asm("v_cvt_pk_bf16_f32 %0, %1, %2" : "=v"(r) : "v"(lo), "v"(hi));
    return r;
}

// async global->LDS, 16B per lane; LDS dest = wave-uniform base + lane*16
typedef __attribute__((address_space(3))) unsigned lds_u32_t;
typedef __attribute__((address_space(1))) const unsigned glb_u32_t;
__device__ __forceinline__ void gl2lds16(const u16* g, u16* l) {
    __builtin_amdgcn_global_load_lds((glb_u32_t*)g, (lds_u32_t*)l, 16, 0, 0);
}

// ---------------------------------------------------------------------------
// fp32 -> bf16 cast for activations (q, kv)
// ---------------------------------------------------------------------------
__global__ __launch_bounds__(256) void acast_kernel(
    const float* __restrict__ a, const float* __restrict__ b,
    u16* __restrict__ da, u16* __restrict__ db)
{
    const float* s = blockIdx.y ? b : a;
    u16* d = blockIdx.y ? db : da;
    size_t i = ((size_t)blockIdx.x * 256 + threadIdx.x) * 4;
    float4 v = *(const float4*)&s[i];
    ushort4 o = { f2bf(v.x), f2bf(v.y), f2bf(v.z), f2bf(v.w) };
    *(ushort4*)&d[i] = o;
}

// ---------------------------------------------------------------------------
// Weight transpose + cast: W[K][N] fp32 -> Wt[N][K] bf16, z selects matrix
// ---------------------------------------------------------------------------
__global__ __launch_bounds__(256) void wt_kernel(
    const float* __restrict__ Wq, const float* __restrict__ Wk,
    const float* __restrict__ Wv, const float* __restrict__ Wo,
    u16* __restrict__ dstbase)
{
    const int z = blockIdx.z;
    const float* src = (z == 0) ? Wq : (z == 1) ? Wk : (z == 2) ? Wv : Wo;
    u16* out = dstbase + (size_t)z * (KK * NN);
    const int bi = blockIdx.y, bj = blockIdx.x;  // 64x64 tile: k-block, n-block
    __shared__ float tile[64][65];
    const int t = threadIdx.x;
    #pragma unroll
    for (int p = 0; p < 4; p++) {
        int idx = p * 256 + t;
        int r = idx >> 4, c4 = (idx & 15) << 2;
        float4 v = *(const float4*)&src[(size_t)(bi * 64 + r) * NN + bj * 64 + c4];
        tile[r][c4 + 0] = v.x; tile[r][c4 + 1] = v.y;
        tile[r][c4 + 2] = v.z; tile[r][c4 + 3] = v.w;
    }
    __syncthreads();
    #pragma unroll
    for (int p = 0; p < 4; p++) {
        int idx = p * 256 + t;
        int rn = idx >> 4, c4 = (idx & 15) << 2;
        ushort4 o = { f2bf(tile[c4 + 0][rn]), f2bf(tile[c4 + 1][rn]),
                      f2bf(tile[c4 + 2][rn]), f2bf(tile[c4 + 3][rn]) };
        *(ushort4*)&out[(size_t)(bj * 64 + rn) * KK + bi * 64 + c4] = o;
    }
}

// ---------------------------------------------------------------------------
// bf16 MFMA GEMM main loop (m97 structure): C[128,128] tile, 4 waves, each
// 64x64 via 4x4 grid of 16x16x32 MFMA. BK=64, global_load_lds width-16
// staging, XOR bank swizzle on the k-colblock (slot s of row r holds global
// colblock s^(r&7)).
// A: [M,K] bf16 row-major.  Bt: [N,K] bf16 row-major (i.e. W^T).
// ---------------------------------------------------------------------------
__device__ __forceinline__ void gemm_mainloop(
    const u16* __restrict__ A, const u16* __restrict__ Bt,
    int m0, int n0, u16* As, u16* Bs, float4v (&acc)[4][4])
{
    const int tid = threadIdx.x;
    const int wave = tid >> 6, lane = tid & 63;
    const int l15 = lane & 15, lg = lane >> 4;
    const int wm = wave >> 1, wn = wave & 1;

    const int lr = lane >> 3;   // row within 8-row chunk
    const int lc = lane & 7;    // colblock slot

    for (int k0 = 0; k0 < KK; k0 += 64) {
        #pragma unroll
        for (int i = 0; i < 4; i++) {
            int chunk = wave * 4 + i;          // 0..15
            int row = chunk * 8 + lr;          // 0..127
            int gcb = lc ^ (row & 7);          // swizzled global colblock
            gl2lds16(A  + (size_t)(m0 + row) * KK + k0 + gcb * 8, As + chunk * 512);
            gl2lds16(Bt + (size_t)(n0 + row) * KK + k0 + gcb * 8, Bs + chunk * 512);
        }
        __syncthreads();

        short8 af[2][4], bf[2][4];
        #pragma unroll
        for (int kc = 0; kc < 2; kc++) {
            #pragma unroll
            for (int x = 0; x < 4; x++) {
                int ra = wm * 64 + x * 16 + l15;
                int sa = (kc * 4 + lg) ^ (ra & 7);
                af[kc][x] = *(const short8*)(As + ra * 64 + sa * 8);
                int rb = wn * 64 + x * 16 + l15;
                int sb = (kc * 4 + lg) ^ (rb & 7);
                bf[kc][x] = *(const short8*)(Bs + rb * 64 + sb * 8);
            }
        }
        #pragma unroll
        for (int mi = 0; mi < 4; mi++)
            #pragma unroll
            for (int nj = 0; nj < 4; nj++) {
                acc[mi][nj] = __builtin_amdgcn_mfma_f32_16x16x32_bf16(af[0][mi], bf[0][nj], acc[mi][nj], 0, 0, 0);
                acc[mi][nj] = __builtin_amdgcn_mfma_f32_16x16x32_bf16(af[1][mi], bf[1][nj], acc[mi][nj], 0, 0, 0);
            }
        __syncthreads();
    }
}

// ---------------------------------------------------------------------------
// QKV projection GEMM, z in {0:Q, 1:K, 2:V}. Epilogue fuses bias + RMSNorm +
// RoPE (Q,K) and writes bf16. Q,K -> (B,H,T,QK); V -> transposed (B,H,QK,T).
// The V transpose goes through the (now free) GEMM LDS so the global store
// is fully coalesced (256B contiguous per d-row) -- the direct scalar-u16
// strided store was a 32x write amplification (1.6 GB measured).
// Q also gets 0.125*log2(e).
// ---------------------------------------------------------------------------
__global__ __launch_bounds__(256) void qkv_gemm(
    const u16* __restrict__ qb, const u16* __restrict__ kvb,
    const u16* __restrict__ Wt,
    const float* __restrict__ bq, const float* __restrict__ bk, const float* __restrict__ bv,
    const int* __restrict__ qpos, const int* __restrict__ kpos,
    const float* __restrict__ q_scale, const float* __restrict__ k_scale,
    u16* __restrict__ qh, u16* __restrict__ kh, u16* __restrict__ vt)
{
    __shared__ __align__(16) u16 sh[2][128 * 64];   // As / Bs, reused for V-transpose

    const int z = blockIdx.z;
    const u16* A        = (z == 0) ? qb : kvb;
    const u16* B        = Wt + (size_t)z * (KK * NN);
    const float* bias   = (z == 0) ? bq : (z == 1) ? bk : bv;
    const float* scl    = (z == 0) ? q_scale : k_scale;
    const int* pos_arr  = (z == 0) ? qpos : kpos;
    u16* dst            = (z == 0) ? qh : (z == 1) ? kh : vt;

    const int m0 = blockIdx.y * 128, n0 = blockIdx.x * 128;

    float4v acc[4][4];
    #pragma unroll
    for (int i = 0; i < 4; i++)
        #pragma unroll
        for (int j = 0; j < 4; j++) acc[i][j] = (float4v){0.f, 0.f, 0.f, 0.f};

    gemm_mainloop(A, B, m0, n0, &sh[0][0], &sh[1][0], acc);

    const int tid = threadIdx.x;
    const int lane = tid & 63, wave = tid >> 6;
    const int l15 = lane & 15, lg = lane >> 4;
    const int wm = wave >> 1, wn = wave & 1;
    const int mbase = m0 + wm * 64;
    const int nbase = n0 + wn * 64;
    const int h = nbase >> 6;

    // per-lane constants
    float bia[4], sc[4];
    #pragma unroll
    for (int nj = 0; nj < 4; nj++) {
        bia[nj] = bias[nbase - (h << 6) + h * 64 + nj * 16 + l15];  // = bias[h*64+c]
        sc[nj]  = 1.0f + scl[nj * 16 + l15];
    }
    // RoPE inverse timescales for this lane's two low cols (j = p*16+l15)
    float invts[2];
    #pragma unroll
    for (int p = 0; p < 2; p++)
        invts[p] = powf(10000.0f, -(float)(p * 16 + l15) * (1.0f / 32.0f));

    const float QMUL = 0.125f * 1.44269504088896340736f;

    u16* sh_flat = &sh[0][0];   // 128(d) x 128(t) u16, 16B-block XOR swizzle

    #pragma unroll
    for (int mi = 0; mi < 4; mi++) {
        #pragma unroll
        for (int r = 0; r < 4; r++) {
            const int m = mbase + mi * 16 + lg * 4 + r;
            const int b = m >> 11, t = m & 2047;
            float v[4];
            #pragma unroll
            for (int nj = 0; nj < 4; nj++) v[nj] = acc[mi][nj][r] + bia[nj];

            if (z < 2) {
                float ss = v[0]*v[0] + v[1]*v[1] + v[2]*v[2] + v[3]*v[3];
                ss += __shfl_xor(ss, 1);
                ss += __shfl_xor(ss, 2);
                ss += __shfl_xor(ss, 4);
                ss += __shfl_xor(ss, 8);
                float rn = rsqrtf(ss * (1.0f / 64.0f) + 1e-6f);
                #pragma unroll
                for (int nj = 0; nj < 4; nj++) v[nj] = v[nj] * rn * sc[nj];

                const float pos = (float)pos_arr[b * TT + t];
                #pragma unroll
                for (int p = 0; p < 2; p++) {
                    float ang = pos * invts[p];
                    float s = sinf(ang), c = cosf(ang);
                    float x1 = v[p], x2 = v[p + 2];
                    v[p]     = x1 * c - x2 * s;
                    v[p + 2] = x2 * c + x1 * s;
                }
                if (z == 0) {
                    #pragma unroll
                    for (int nj = 0; nj < 4; nj++) v[nj] *= QMUL;
                }
                u16* op = dst + ((size_t)((b * HH + h) * TT + t)) * QKD + l15;
                #pragma unroll
                for (int nj = 0; nj < 4; nj++) op[nj * 16] = f2bf(v[nj]);
            } else {
                // V: stash into LDS transposed [d_local][t_local ^ swz]
                const int tl = wm * 64 + mi * 16 + lg * 4 + r;   // t_local
                #pragma unroll
                for (int nj = 0; nj < 4; nj++) {
                    const int dl = wn * 64 + nj * 16 + l15;      // d_local
                    sh_flat[dl * 128 + (tl ^ ((dl & 7) << 3))] = f2bf(v[nj]);
                }
            }
        }
    }

    if (z == 2) {
        __syncthreads();
        const int bb_ = m0 >> 11;       // batch
        const int t0g = m0 & 2047;      // global t base of this tile
        #pragma unroll
        for (int p = 0; p < 8; p++) {
            int idx = p * 256 + tid;    // 0..2047
            int dl  = idx >> 4;         // 0..127
            int tc  = (idx & 15) << 3;  // 0..120 step 8
            short8 v8 = *(const short8*)&sh_flat[dl * 128 + (tc ^ ((dl & 7) << 3))];
            int hh_ = (n0 + dl) >> 6, dih = (n0 + dl) & 63;
            *(short8*)&dst[((size_t)(bb_ * HH + hh_) * QKD + dih) * TT + t0g + tc] = v8;
        }
    }
}

// ---------------------------------------------------------------------------
// Output projection GEMM: attn_b[M,K] bf16 @ Wo_t[N,K]^T + bo -> out fp32
// ---------------------------------------------------------------------------
__global__ __launch_bounds__(256) void out_gemm(
    const u16* __restrict__ A, const u16* __restrict__ Bt,
    const float* __restrict__ bo, float* __restrict__ out)
{
    __shared__ u16 As[128 * 64];
    __shared__ u16 Bs[128 * 64];

    const int m0 = blockIdx.y * 128, n0 = blockIdx.x * 128;

    float4v acc[4][4];
    #pragma unroll
    for (int i = 0; i < 4; i++)
        #pragma unroll
        for (int j = 0; j < 4; j++) acc[i][j] = (float4v){0.f, 0.f, 0.f, 0.f};

    gemm_mainloop(A, Bt, m0, n0, As, Bs, acc);

    const int lane = threadIdx.x & 63, wave = threadIdx.x >> 6;
    const int l15 = lane & 15, lg = lane >> 4;
    const int wm = wave >> 1, wn = wave & 1;
    const int mbase = m0 + wm * 64;
    const int nbase = n0 + wn * 64;

    float bov[4];
    #pragma unroll
    for (int nj = 0; nj < 4; nj++) bov[nj] = bo[nbase + nj * 16 + l15];

    #pragma unroll
    for (int mi = 0; mi < 4; mi++)
        #pragma unroll
        for (int r = 0; r < 4; r++) {
            const int m = mbase + mi * 16 + lg * 4 + r;
            float* op = out + (size_t)m * NN + nbase + l15;
            #pragma unroll
            for (int nj = 0; nj < 4; nj++)
                op[nj * 16] = acc[mi][nj][r] + bov[nj];
        }
}

// ---------------------------------------------------------------------------
// MFMA flash attention, causal.  v3 structure (unchanged this round):
//  - K rows and V^T rows staged via global_load_lds (16B) into XOR-swizzled
//    linear LDS (slot s of row r holds global colblock s^(r&7))
//  - double-buffered K/V: next tile's loads issued before current compute,
//    __syncthreads' vmcnt drain is the per-tile wait (T3 minimal 2-phase)
//  - defer-max rescale (T13, THR=8 in exp2 domain)
//  - packed v_cvt_pk_bf16_f32 for the P->bf16 LDS store
//  - per-lane partial rowsum; cross-lane l-reduce once in the epilogue
// ---------------------------------------------------------------------------
__global__ __launch_bounds__(256) void attn_mfma(
    const u16* __restrict__ qh, const u16* __restrict__ kh,
    const u16* __restrict__ vt, const float* __restrict__ head_scale,
    u16* __restrict__ out)
{
    __shared__ __align__(16) u16 Ks[2][64 * 64];   // K rows (swizzled)
    __shared__ __align__(16) u16 Vs[2][64 * 64];   // V^T rows = d (swizzled)
    __shared__ __align__(16) u16 Ps[4][16 * 64];   // per-wave P tile (swizzled)

    const int b = blockIdx.z, h = blockIdx.y, qt = blockIdx.x;
    const int t0 = qt * 64;
    const int tid  = threadIdx.x;
    const int wave = tid >> 6, lane = tid & 63;
    const int l15 = lane & 15, lg = lane >> 4;
    const int l7 = l15 & 7;

    const size_t bh = (size_t)(b * HH + h);
    const u16* qbh  = qh + bh * TT * QKD;
    const u16* kbh  = kh + bh * TT * QKD;
    const u16* vtbh = vt + bh * QKD * TT;   // [QKD][TT]

    short8 qfrag[2];
    #pragma unroll
    for (int kc = 0; kc < 2; kc++)
        qfrag[kc] = *(const short8*)(qbh + (size_t)(t0 + wave * 16 + l15) * QKD
                                      + kc * 32 + lg * 8);

    // stage one 64-key tile (K rows + V^T rows) into buffer `buf`
    auto stage = [&](int buf, int j0s) {
        #pragma unroll
        for (int rr = 0; rr < 2; rr++) {
            const int c   = rr * 256 + tid;     // chunk 0..511 (16B each)
            const int row = c >> 3;             // 0..63
            const int g   = (c & 7) ^ (row & 7);// pre-swizzled global colblock
            u16* ldsK = &Ks[buf][(rr * 256 + (wave << 6)) * 8];
            u16* ldsV = &Vs[buf][(rr * 256 + (wave << 6)) * 8];
            gl2lds16(kbh  + (size_t)(j0s + row) * QKD + g * 8, ldsK);
            gl2lds16(vtbh + (size_t)row * TT + j0s + g * 8, ldsV);
        }
    };

    float4v o_acc[4];
    #pragma unroll
    for (int nt = 0; nt < 4; nt++) o_acc[nt] = (float4v){0.f, 0.f, 0.f, 0.f};
    float m_run[4] = {-INFINITY, -INFINITY, -INFINITY, -INFINITY};
    float l_run[4] = {0.f, 0.f, 0.f, 0.f};

    stage(0, 0);
    __syncthreads();

    const int qbase = t0 + wave * 16 + lg * 4;

    for (int j0 = 0; j0 <= t0; j0 += 64) {
        const int cur = (j0 >> 6) & 1;
        if (j0 + 64 <= t0) stage(cur ^ 1, j0 + 64);   // prefetch next tile

        // ---- QK^T (swizzled K reads) ----
        float4v sarr[4];
        #pragma unroll
        for (int nt = 0; nt < 4; nt++) {
            float4v s = (float4v){0.f, 0.f, 0.f, 0.f};
            #pragma unroll
            for (int kc = 0; kc < 2; kc++) {
                const short8 bfrag = *(const short8*)
                    &Ks[cur][(nt * 16 + l15) * 64 + ((kc * 4 + lg) ^ l7) * 8];
                s = __builtin_amdgcn_mfma_f32_16x16x32_bf16(qfrag[kc], bfrag, s, 0, 0, 0);
            }
            sarr[nt] = s;
        }

        // ---- causal mask (diagonal tile only) ----
        if (j0 == t0) {
            #pragma unroll
            for (int nt = 0; nt < 4; nt++) {
                int jkey = j0 + nt * 16 + l15;
                #pragma unroll
                for (int r = 0; r < 4; r++)
                    if (jkey > qbase + r) sarr[nt][r] = -INFINITY;
            }
        }

        // ---- row max + defer-max rescale (T13) ----
        float pm[4];
        #pragma unroll
        for (int r = 0; r < 4; r++) {
            float m = fmaxf(fmaxf(sarr[0][r], sarr[1][r]), fmaxf(sarr[2][r], sarr[3][r]));
            m = fmaxf(m, __shfl_xor(m, 1));
            m = fmaxf(m, __shfl_xor(m, 2));
            m = fmaxf(m, __shfl_xor(m, 4));
            m = fmaxf(m, __shfl_xor(m, 8));
            pm[r] = m;
        }
        float grow = fmaxf(fmaxf(pm[0] - m_run[0], pm[1] - m_run[1]),
                           fmaxf(pm[2] - m_run[2], pm[3] - m_run[3]));
        if (__any(grow > 8.0f)) {
            #pragma unroll
            for (int r = 0; r < 4; r++) {
                float mn = fmaxf(m_run[r], pm[r]);
                float a  = exp2f(m_run[r] - mn);
                m_run[r] = mn;
                l_run[r] *= a;
                #pragma unroll
                for (int nt = 0; nt < 4; nt++) o_acc[nt][r] *= a;
            }
        }

        // ---- P = exp2(S - m), partial rowsum, packed bf16 store to Ps ----
        u16* pw = Ps[wave];
        float lp[4] = {0.f, 0.f, 0.f, 0.f};
        #pragma unroll
        for (int nt = 0; nt < 4; nt++) {
            float p0 = exp2f(sarr[nt][0] - m_run[0]);
            float p1 = exp2f(sarr[nt][1] - m_run[1]);
            float p2 = exp2f(sarr[nt][2] - m_run[2]);
            float p3 = exp2f(sarr[nt][3] - m_run[3]);
            lp[0] += p0; lp[1] += p1; lp[2] += p2; lp[3] += p3;
            unsigned wlo = cvt_pk_bf16(p0, p1);
            unsigned whi = cvt_pk_bf16(p2, p3);
            const int gb = nt * 2 + (l15 >> 3);
            const int r0 = lg * 4;
            pw[(r0 + 0) * 64 + ((gb ^ ((r0 + 0) & 7))) * 8 + l7] = (u16)wlo;
            pw[(r0 + 1) * 64 + ((gb ^ ((r0 + 1) & 7))) * 8 + l7] = (u16)(wlo >> 16);
            pw[(r0 + 2) * 64 + ((gb ^ ((r0 + 2) & 7))) * 8 + l7] = (u16)whi;
            pw[(r0 + 3) * 64 + ((gb ^ ((r0 + 3) & 7))) * 8 + l7] = (u16)(whi >> 16);
        }
        #pragma unroll
        for (int r = 0; r < 4; r++) l_run[r] += lp[r];

        // ---- read P fragments back (same wave; lgkmcnt ordered) ----
        short8 pf[2];
        #pragma unroll
        for (int kc = 0; kc < 2; kc++)
            pf[kc] = *(const short8*)&pw[l15 * 64 + ((kc * 4 + lg) ^ l7) * 8];

        // ---- PV (swizzled V^T reads) ----
        #pragma unroll
        for (int nt = 0; nt < 4; nt++) {
            #pragma unroll
            for (int kc = 0; kc < 2; kc++) {
                const short8 vfrag = *(const short8*)
                    &Vs[cur][(nt * 16 + l15) * 64 + ((kc * 4 + lg) ^ l7) * 8];
                o_acc[nt] = __builtin_amdgcn_mfma_f32_16x16x32_bf16(pf[kc], vfrag, o_acc[nt], 0, 0, 0);
            }
        }
        __syncthreads();   // drains prefetch vmcnt + protects buffer reuse
    }

    const float hs = 1.0f + head_scale[h];
    #pragma unroll
    for (int r = 0; r < 4; r++) {
        float l = l_run[r];
        l += __shfl_xor(l, 1);
        l += __shfl_xor(l, 2);
        l += __shfl_xor(l, 4);
        l += __shfl_xor(l, 8);
        const int q = t0 + wave * 16 + lg * 4 + r;
        const float f = hs / l;
        u16* op = out + ((size_t)(b * TT + q) * NN) + h * QKD + l15;
        #pragma unroll
        for (int nt = 0; nt < 4; nt++)
            op[nt * 16] = f2bf(o_acc[nt][r] * f);
    }
}

// ---------------------------------------------------------------------------
extern "C" void kernel_launch(void* const* d_in, const int* in_sizes, int n_in,
                              void* d_out, int out_size, void* d_ws, size_t ws_size,
                              hipStream_t stream)
{
    const float* q          = (const float*)d_in[0];
    const float* kv         = (const float*)d_in[1];
    /* d_in[2] = causal mask -- handled analytically */
    const int*   qpos       = (const int*)d_in[3];
    const int*   kpos       = (const int*)d_in[4];
    const float* Wq         = (const float*)d_in[5];
    const float* bq         = (const float*)d_in[6];
    const float* Wk         = (const float*)d_in[7];
    const float* bk         = (const float*)d_in[8];
    const float* Wv         = (const float*)d_in[9];
    const float* bv         = (const float*)d_in[10];
    const float* q_scale    = (const float*)d_in[11];
    const float* k_scale    = (const float*)d_in[12];
    const float* head_scale = (const float*)d_in[13];
    const float* Wo         = (const float*)d_in[14];
    const float* bo         = (const float*)d_in[15];
    float* out = (float*)d_out;

    // workspace layout (bytes):
    //   [  0 MB, 16 MB)  qb    (M,K) bf16
    //   [ 16 MB, 32 MB)  kvb   (M,K) bf16
    //   [ 32 MB, 40 MB)  Wt    4 x (N,K) bf16 transposed: Wq,Wk,Wv,Wo
    //   [ 40 MB, 56 MB)  qh_b  (B,H,T,QK) bf16
    //   [ 56 MB, 72 MB)  kh_b  (B,H,T,QK) bf16
    //   [ 72 MB, 88 MB)  vt_b  (B,H,QK,T) bf16  <-- V stored transposed
    //   [ 88 MB,104 MB)  attn_b (B,T,N) bf16
    char* ws = (char*)d_ws;
    u16* qb     = (u16*)(ws);
    u16* kvb    = (u16*)(ws + (16u << 20));
    u16* Wt     = (u16*)(ws + (32u << 20));
    u16* qh_b   = (u16*)(ws + (40u << 20));
    u16* kh_b   = (u16*)(ws + (56u << 20));
    u16* vt_b   = (u16*)(ws + (72u << 20));
    u16* attn_b = (u16*)(ws + (88u << 20));

    // 1. cast activations to bf16
    acast_kernel<<<dim3(MM * DD / (256 * 4), 2), 256, 0, stream>>>(q, kv, qb, kvb);
    // 2. transpose+cast the four weight matrices
    wt_kernel<<<dim3(16, 16, 4), 256, 0, stream>>>(Wq, Wk, Wv, Wo, Wt);
    // 3. fused QKV projection + bias + RMSNorm + RoPE -> Q,K:(B,H,T,QK), V:(B,H,QK,T)
    qkv_gemm<<<dim3(NN / 128, MM / 128, 3), 256, 0, stream>>>(
        qb, kvb, Wt, bq, bk, bv, qpos, kpos, q_scale, k_scale, qh_b, kh_b, vt_b);
    // 4. causal MFMA flash attention + head_scale -> (B,T,N) bf16
    attn_mfma<<<dim3(TT / 64, HH, BB), 256, 0, stream>>>(qh_b, kh_b, vt_b, head_scale, attn_b);
    // 5. output projection + bias -> fp32
    out_gemm<<<dim3(NN / 128, MM / 128), 256, 0, stream>>>(attn_b, Wt + (size_t)3 * KK * NN, bo, out);
}

// Round 3
// 656.518 us; speedup vs baseline: 1.0771x; 1.0624x over previous
//
#include <hip/hip_runtime.h>
#include <math.h>

// Problem constants
#define BB 4
#define TT 2048
#define DD 1024
#define HH 16
#define QKD 64
#define MM (BB*TT)          // 8192
#define NN 1024             // H*QK == D
#define KK 1024

typedef unsigned short u16;
typedef __attribute__((ext_vector_type(8))) short short8;   // 8 bf16 = 4 VGPRs
typedef __attribute__((ext_vector_type(4))) float float4v;  // MFMA C/D
typedef __attribute__((ext_vector_type(4))) unsigned uint4v; // 16B staging reg

// fp32 -> bf16 round-to-nearest-even
__device__ __forceinline__ u16 f2bf(float f) {
    union { float f; unsigned u; } v; v.f = f;
    unsigned r = (v.u + 0x7FFFu + ((v.u >> 16) & 1u)) >> 16;
    return (u16)r;
}

// packed fp32x2 -> bf16x2 (RTNE), single instruction on gfx950
__device__ __forceinline__ unsigned cvt_pk_bf16(float lo, float hi) {
    unsigned r;
    asm("v_cvt_pk_bf16_f32 %0, %1, %2" : "=v"(r) : "v"(lo), "v"(hi));
    return r;
}

// async global->LDS, 16B per lane; LDS dest = wave-uniform base + lane*16
// (still used by attn_mfma this round)
typedef __attribute__((address_space(3))) unsigned lds_u32_t;
typedef __attribute__((address_space(1))) const unsigned glb_u32_t;
__device__ __forceinline__ void gl2lds16(const u16* g, u16* l) {
    __builtin_amdgcn_global_load_lds((glb_u32_t*)g, (lds_u32_t*)l, 16, 0, 0);
}

// ---------------------------------------------------------------------------
// fp32 -> bf16 cast for activations (q, kv)
// ---------------------------------------------------------------------------
__global__ __launch_bounds__(256) void acast_kernel(
    const float* __restrict__ a, const float* __restrict__ b,
    u16* __restrict__ da, u16* __restrict__ db)
{
    const float* s = blockIdx.y ? b : a;
    u16* d = blockIdx.y ? db : da;
    size_t i = ((size_t)blockIdx.x * 256 + threadIdx.x) * 4;
    float4 v = *(const float4*)&s[i];
    ushort4 o = { f2bf(v.x), f2bf(v.y), f2bf(v.z), f2bf(v.w) };
    *(ushort4*)&d[i] = o;
}

// ---------------------------------------------------------------------------
// Weight transpose + cast: W[K][N] fp32 -> Wt[N][K] bf16, z selects matrix
// ---------------------------------------------------------------------------
__global__ __launch_bounds__(256) void wt_kernel(
    const float* __restrict__ Wq, const float* __restrict__ Wk,
    const float* __restrict__ Wv, const float* __restrict__ Wo,
    u16* __restrict__ dstbase)
{
    const int z = blockIdx.z;
    const float* src = (z == 0) ? Wq : (z == 1) ? Wk : (z == 2) ? Wv : Wo;
    u16* out = dstbase + (size_t)z * (KK * NN);
    const int bi = blockIdx.y, bj = blockIdx.x;  // 64x64 tile: k-block, n-block
    __shared__ float tile[64][65];
    const int t = threadIdx.x;
    #pragma unroll
    for (int p = 0; p < 4; p++) {
        int idx = p * 256 + t;
        int r = idx >> 4, c4 = (idx & 15) << 2;
        float4 v = *(const float4*)&src[(size_t)(bi * 64 + r) * NN + bj * 64 + c4];
        tile[r][c4 + 0] = v.x; tile[r][c4 + 1] = v.y;
        tile[r][c4 + 2] = v.z; tile[r][c4 + 3] = v.w;
    }
    __syncthreads();
    #pragma unroll
    for (int p = 0; p < 4; p++) {
        int idx = p * 256 + t;
        int rn = idx >> 4, c4 = (idx & 15) << 2;
        ushort4 o = { f2bf(tile[c4 + 0][rn]), f2bf(tile[c4 + 1][rn]),
                      f2bf(tile[c4 + 2][rn]), f2bf(tile[c4 + 3][rn]) };
        *(ushort4*)&out[(size_t)(bj * 64 + rn) * KK + bi * 64 + c4] = o;
    }
}

// ---------------------------------------------------------------------------
// bf16 MFMA GEMM main loop, v3: reg-staged (NO global_load_lds), double-
// buffered LDS, ONE barrier per k-step.  Tile t+1 is loaded to VGPRs before
// tile t's MFMA block (T14 async-stage split); ds_write goes to the other
// buffer after the MFMAs.  LDS layout identical to v2: slot s of row r holds
// global colblock s^(r&7), so the fragment-read path is unchanged.
// A: [M,K] bf16 row-major.  Bt: [N,K] bf16 row-major (i.e. W^T).
// ---------------------------------------------------------------------------
__device__ __forceinline__ void gemm_mainloop(
    const u16* __restrict__ A, const u16* __restrict__ Bt,
    int m0, int n0,
    u16* __restrict__ sA0, u16* __restrict__ sB0,
    u16* __restrict__ sA1, u16* __restrict__ sB1,
    float4v (&acc)[4][4])
{
    const int tid = threadIdx.x;
    const int wave = tid >> 6, lane = tid & 63;
    const int l15 = lane & 15, lg = lane >> 4;
    const int wm = wave >> 1, wn = wave & 1;

    const int lr = lane >> 3;   // row within 8-row chunk (== row&7)
    const int lc = lane & 7;    // colblock (UNswizzled global load)

    // per-thread global base: chunk i covers row (wave*4+i)*8 + lr
    const u16* gA = A  + (size_t)(m0 + wave * 32 + lr) * KK + lc * 8;
    const u16* gB = Bt + (size_t)(n0 + wave * 32 + lr) * KK + lc * 8;
    const int wslot = (lc ^ lr) * 8;   // swizzled LDS slot (row&7 == lr)

    uint4v ar[4], br[4];
    auto gload = [&](int k0) {
        #pragma unroll
        for (int i = 0; i < 4; i++) {
            ar[i] = *(const uint4v*)(gA + (size_t)i * 8 * KK + k0);
            br[i] = *(const uint4v*)(gB + (size_t)i * 8 * KK + k0);
        }
    };
    auto swrite = [&](u16* sA, u16* sB) {
        #pragma unroll
        for (int i = 0; i < 4; i++) {
            const int chunk = wave * 4 + i;
            *(uint4v*)(sA + chunk * 512 + lr * 64 + wslot) = ar[i];
            *(uint4v*)(sB + chunk * 512 + lr * 64 + wslot) = br[i];
        }
    };

    gload(0);
    swrite(sA0, sB0);
    __syncthreads();

    for (int t = 0; t < 16; t++) {
        if (t < 15) gload((t + 1) * 64);          // overlap with compute
        u16* sA = (t & 1) ? sA1 : sA0;
        u16* sB = (t & 1) ? sB1 : sB0;

        short8 af[2][4], bf[2][4];
        #pragma unroll
        for (int kc = 0; kc < 2; kc++) {
            #pragma unroll
            for (int x = 0; x < 4; x++) {
                int ra = wm * 64 + x * 16 + l15;
                int sa = (kc * 4 + lg) ^ (ra & 7);
                af[kc][x] = *(const short8*)(sA + ra * 64 + sa * 8);
                int rb = wn * 64 + x * 16 + l15;
                int sb = (kc * 4 + lg) ^ (rb & 7);
                bf[kc][x] = *(const short8*)(sB + rb * 64 + sb * 8);
            }
        }
        #pragma unroll
        for (int mi = 0; mi < 4; mi++)
            #pragma unroll
            for (int nj = 0; nj < 4; nj++) {
                acc[mi][nj] = __builtin_amdgcn_mfma_f32_16x16x32_bf16(af[0][mi], bf[0][nj], acc[mi][nj], 0, 0, 0);
                acc[mi][nj] = __builtin_amdgcn_mfma_f32_16x16x32_bf16(af[1][mi], bf[1][nj], acc[mi][nj], 0, 0, 0);
            }
        // write NEXT tile into the other buffer (no WAR with current reads)
        if (t < 15) swrite((t & 1) ? sA0 : sA1, (t & 1) ? sB0 : sB1);
        __syncthreads();   // publishes next buffer; orders buffer reuse
    }
}

// ---------------------------------------------------------------------------
// QKV projection GEMM, z in {0:Q, 1:K, 2:V}. Epilogue fuses bias + RMSNorm +
// RoPE (Q,K) and writes bf16. Q,K -> (B,H,T,QK); V -> transposed (B,H,QK,T).
// ALL epilogue stores are routed through LDS so every global store
// instruction writes full 128B lines (8 lines per wave instruction).
// Q also gets 0.125*log2(e).
// ---------------------------------------------------------------------------
__global__ __launch_bounds__(256) void qkv_gemm(
    const u16* __restrict__ qb, const u16* __restrict__ kvb,
    const u16* __restrict__ Wt,
    const float* __restrict__ bq, const float* __restrict__ bk, const float* __restrict__ bv,
    const int* __restrict__ qpos, const int* __restrict__ kpos,
    const float* __restrict__ q_scale, const float* __restrict__ k_scale,
    u16* __restrict__ qh, u16* __restrict__ kh, u16* __restrict__ vt)
{
    __shared__ __align__(16) u16 sh[4][128 * 64];   // A0,B0,A1,B1; [0..1] reused by epilogue

    const int z = blockIdx.z;
    const u16* A        = (z == 0) ? qb : kvb;
    const u16* B        = Wt + (size_t)z * (KK * NN);
    const float* bias   = (z == 0) ? bq : (z == 1) ? bk : bv;
    const float* scl    = (z == 0) ? q_scale : k_scale;
    const int* pos_arr  = (z == 0) ? qpos : kpos;
    u16* dst            = (z == 0) ? qh : (z == 1) ? kh : vt;

    const int m0 = blockIdx.y * 128, n0 = blockIdx.x * 128;

    float4v acc[4][4];
    #pragma unroll
    for (int i = 0; i < 4; i++)
        #pragma unroll
        for (int j = 0; j < 4; j++) acc[i][j] = (float4v){0.f, 0.f, 0.f, 0.f};

    gemm_mainloop(A, B, m0, n0, &sh[0][0], &sh[1][0], &sh[2][0], &sh[3][0], acc);

    const int tid = threadIdx.x;
    const int lane = tid & 63, wave = tid >> 6;
    const int l15 = lane & 15, lg = lane >> 4;
    const int wm = wave >> 1, wn = wave & 1;
    const int mbase = m0 + wm * 64;
    const int nbase = n0 + wn * 64;
    const int h = nbase >> 6;

    // per-lane constants
    float bia[4], sc[4];
    #pragma unroll
    for (int nj = 0; nj < 4; nj++) {
        bia[nj] = bias[nbase - (h << 6) + h * 64 + nj * 16 + l15];  // = bias[h*64+c]
        sc[nj]  = 1.0f + scl[nj * 16 + l15];
    }
    // RoPE inverse timescales for this lane's two low cols (j = p*16+l15)
    float invts[2];
    #pragma unroll
    for (int p = 0; p < 2; p++)
        invts[p] = powf(10000.0f, -(float)(p * 16 + l15) * (1.0f / 32.0f));

    const float QMUL = 0.125f * 1.44269504088896340736f;

    u16* sh_ep = &sh[0][0];   // 128 x 128 u16 epilogue stash (32 KB)

    #pragma unroll
    for (int mi = 0; mi < 4; mi++) {
        #pragma unroll
        for (int r = 0; r < 4; r++) {
            const int m = mbase + mi * 16 + lg * 4 + r;
            const int b = m >> 11, t = m & 2047;
            const int tl = wm * 64 + mi * 16 + lg * 4 + r;   // local row 0..127
            float v[4];
            #pragma unroll
            for (int nj = 0; nj < 4; nj++) v[nj] = acc[mi][nj][r] + bia[nj];

            if (z < 2) {
                float ss = v[0]*v[0] + v[1]*v[1] + v[2]*v[2] + v[3]*v[3];
                ss += __shfl_xor(ss, 1);
                ss += __shfl_xor(ss, 2);
                ss += __shfl_xor(ss, 4);
                ss += __shfl_xor(ss, 8);
                float rn = rsqrtf(ss * (1.0f / 64.0f) + 1e-6f);
                #pragma unroll
                for (int nj = 0; nj < 4; nj++) v[nj] = v[nj] * rn * sc[nj];

                const float pos = (float)pos_arr[b * TT + t];
                #pragma unroll
                for (int p = 0; p < 2; p++) {
                    float ang = pos * invts[p];
                    float s = sinf(ang), c = cosf(ang);
                    float x1 = v[p], x2 = v[p + 2];
                    v[p]     = x1 * c - x2 * s;
                    v[p + 2] = x2 * c + x1 * s;
                }
                if (z == 0) {
                    #pragma unroll
                    for (int nj = 0; nj < 4; nj++) v[nj] *= QMUL;
                }
                // stash row-major [tl][d ^ swz(tl)]
                #pragma unroll
                for (int nj = 0; nj < 4; nj++) {
                    const int dl = wn * 64 + nj * 16 + l15;
                    sh_ep[tl * 128 + (dl ^ ((tl & 7) << 3))] = f2bf(v[nj]);
                }
            } else {
                // V: stash transposed [dl][t ^ swz(dl)]
                #pragma unroll
                for (int nj = 0; nj < 4; nj++) {
                    const int dl = wn * 64 + nj * 16 + l15;
                    sh_ep[dl * 128 + (tl ^ ((dl & 7) << 3))] = f2bf(v[nj]);
                }
            }
        }
    }

    __syncthreads();
    const int bb_ = m0 >> 11;       // batch (tile never straddles a batch)
    const int t0g = m0 & 2047;      // global t base of this tile
    if (z < 2) {
        // coalesced (B,H,T,QK) store: 8 full 128B lines per wave instruction
        #pragma unroll
        for (int p = 0; p < 8; p++) {
            int idx = p * 256 + tid;    // 0..2047
            int tl  = idx >> 4;         // 0..127
            int c8  = (idx & 15) << 3;  // 0..120 step 8
            short8 v8 = *(const short8*)&sh_ep[tl * 128 + (c8 ^ ((tl & 7) << 3))];
            int hh_ = (n0 + c8) >> 6, dih = (n0 + c8) & 63;
            *(short8*)&dst[((size_t)(bb_ * HH + hh_) * TT + t0g + tl) * QKD + dih] = v8;
        }
    } else {
        // coalesced (B,H,QK,T) store
        #pragma unroll
        for (int p = 0; p < 8; p++) {
            int idx = p * 256 + tid;    // 0..2047
            int dl  = idx >> 4;         // 0..127
            int tc  = (idx & 15) << 3;  // 0..120 step 8
            short8 v8 = *(const short8*)&sh_ep[dl * 128 + (tc ^ ((dl & 7) << 3))];
            int hh_ = (n0 + dl) >> 6, dih = (n0 + dl) & 63;
            *(short8*)&dst[((size_t)(bb_ * HH + hh_) * QKD + dih) * TT + t0g + tc] = v8;
        }
    }
}

// ---------------------------------------------------------------------------
// Output projection GEMM: attn_b[M,K] bf16 @ Wo_t[N,K]^T + bo -> out fp32
// ---------------------------------------------------------------------------
__global__ __launch_bounds__(256) void out_gemm(
    const u16* __restrict__ A, const u16* __restrict__ Bt,
    const float* __restrict__ bo, float* __restrict__ out)
{
    __shared__ __align__(16) u16 sh[4][128 * 64];

    const int m0 = blockIdx.y * 128, n0 = blockIdx.x * 128;

    float4v acc[4][4];
    #pragma unroll
    for (int i = 0; i < 4; i++)
        #pragma unroll
        for (int j = 0; j < 4; j++) acc[i][j] = (float4v){0.f, 0.f, 0.f, 0.f};

    gemm_mainloop(A, Bt, m0, n0, &sh[0][0], &sh[1][0], &sh[2][0], &sh[3][0], acc);

    const int lane = threadIdx.x & 63, wave = threadIdx.x >> 6;
    const int l15 = lane & 15, lg = lane >> 4;
    const int wm = wave >> 1, wn = wave & 1;
    const int mbase = m0 + wm * 64;
    const int nbase = n0 + wn * 64;

    float bov[4];
    #pragma unroll
    for (int nj = 0; nj < 4; nj++) bov[nj] = bo[nbase + nj * 16 + l15];

    #pragma unroll
    for (int mi = 0; mi < 4; mi++)
        #pragma unroll
        for (int r = 0; r < 4; r++) {
            const int m = mbase + mi * 16 + lg * 4 + r;
            float* op = out + (size_t)m * NN + nbase + l15;
            #pragma unroll
            for (int nj = 0; nj < 4; nj++)
                op[nj * 16] = acc[mi][nj][r] + bov[nj];
        }
}

// ---------------------------------------------------------------------------
// MFMA flash attention, causal (unchanged this round):
//  - K rows and V^T rows staged via global_load_lds (16B) into XOR-swizzled
//    linear LDS; double-buffered K/V prefetch (T3 minimal 2-phase)
//  - defer-max rescale (T13, THR=8 in exp2 domain)
//  - packed v_cvt_pk_bf16_f32 for the P->bf16 LDS store
//  - per-lane partial rowsum; cross-lane l-reduce once in the epilogue
// ---------------------------------------------------------------------------
__global__ __launch_bounds__(256) void attn_mfma(
    const u16* __restrict__ qh, const u16* __restrict__ kh,
    const u16* __restrict__ vt, const float* __restrict__ head_scale,
    u16* __restrict__ out)
{
    __shared__ __align__(16) u16 Ks[2][64 * 64];   // K rows (swizzled)
    __shared__ __align__(16) u16 Vs[2][64 * 64];   // V^T rows = d (swizzled)
    __shared__ __align__(16) u16 Ps[4][16 * 64];   // per-wave P tile (swizzled)

    const int b = blockIdx.z, h = blockIdx.y, qt = blockIdx.x;
    const int t0 = qt * 64;
    const int tid  = threadIdx.x;
    const int wave = tid >> 6, lane = tid & 63;
    const int l15 = lane & 15, lg = lane >> 4;
    const int l7 = l15 & 7;

    const size_t bh = (size_t)(b * HH + h);
    const u16* qbh  = qh + bh * TT * QKD;
    const u16* kbh  = kh + bh * TT * QKD;
    const u16* vtbh = vt + bh * QKD * TT;   // [QKD][TT]

    short8 qfrag[2];
    #pragma unroll
    for (int kc = 0; kc < 2; kc++)
        qfrag[kc] = *(const short8*)(qbh + (size_t)(t0 + wave * 16 + l15) * QKD
                                      + kc * 32 + lg * 8);

    // stage one 64-key tile (K rows + V^T rows) into buffer `buf`
    auto stage = [&](int buf, int j0s) {
        #pragma unroll
        for (int rr = 0; rr < 2; rr++) {
            const int c   = rr * 256 + tid;     // chunk 0..511 (16B each)
            const int row = c >> 3;             // 0..63
            const int g   = (c & 7) ^ (row & 7);// pre-swizzled global colblock
            u16* ldsK = &Ks[buf][(rr * 256 + (wave << 6)) * 8];
            u16* ldsV = &Vs[buf][(rr * 256 + (wave << 6)) * 8];
            gl2lds16(kbh  + (size_t)(j0s + row) * QKD + g * 8, ldsK);
            gl2lds16(vtbh + (size_t)row * TT + j0s + g * 8, ldsV);
        }
    };

    float4v o_acc[4];
    #pragma unroll
    for (int nt = 0; nt < 4; nt++) o_acc[nt] = (float4v){0.f, 0.f, 0.f, 0.f};
    float m_run[4] = {-INFINITY, -INFINITY, -INFINITY, -INFINITY};
    float l_run[4] = {0.f, 0.f, 0.f, 0.f};

    stage(0, 0);
    __syncthreads();

    const int qbase = t0 + wave * 16 + lg * 4;

    for (int j0 = 0; j0 <= t0; j0 += 64) {
        const int cur = (j0 >> 6) & 1;
        if (j0 + 64 <= t0) stage(cur ^ 1, j0 + 64);   // prefetch next tile

        // ---- QK^T (swizzled K reads) ----
        float4v sarr[4];
        #pragma unroll
        for (int nt = 0; nt < 4; nt++) {
            float4v s = (float4v){0.f, 0.f, 0.f, 0.f};
            #pragma unroll
            for (int kc = 0; kc < 2; kc++) {
                const short8 bfrag = *(const short8*)
                    &Ks[cur][(nt * 16 + l15) * 64 + ((kc * 4 + lg) ^ l7) * 8];
                s = __builtin_amdgcn_mfma_f32_16x16x32_bf16(qfrag[kc], bfrag, s, 0, 0, 0);
            }
            sarr[nt] = s;
        }

        // ---- causal mask (diagonal tile only) ----
        if (j0 == t0) {
            #pragma unroll
            for (int nt = 0; nt < 4; nt++) {
                int jkey = j0 + nt * 16 + l15;
                #pragma unroll
                for (int r = 0; r < 4; r++)
                    if (jkey > qbase + r) sarr[nt][r] = -INFINITY;
            }
        }

        // ---- row max + defer-max rescale (T13) ----
        float pm[4];
        #pragma unroll
        for (int r = 0; r < 4; r++) {
            float m = fmaxf(fmaxf(sarr[0][r], sarr[1][r]), fmaxf(sarr[2][r], sarr[3][r]));
            m = fmaxf(m, __shfl_xor(m, 1));
            m = fmaxf(m, __shfl_xor(m, 2));
            m = fmaxf(m, __shfl_xor(m, 4));
            m = fmaxf(m, __shfl_xor(m, 8));
            pm[r] = m;
        }
        float grow = fmaxf(fmaxf(pm[0] - m_run[0], pm[1] - m_run[1]),
                           fmaxf(pm[2] - m_run[2], pm[3] - m_run[3]));
        if (__any(grow > 8.0f)) {
            #pragma unroll
            for (int r = 0; r < 4; r++) {
                float mn = fmaxf(m_run[r], pm[r]);
                float a  = exp2f(m_run[r] - mn);
                m_run[r] = mn;
                l_run[r] *= a;
                #pragma unroll
                for (int nt = 0; nt < 4; nt++) o_acc[nt][r] *= a;
            }
        }

        // ---- P = exp2(S - m), partial rowsum, packed bf16 store to Ps ----
        u16* pw = Ps[wave];
        float lp[4] = {0.f, 0.f, 0.f, 0.f};
        #pragma unroll
        for (int nt = 0; nt < 4; nt++) {
            float p0 = exp2f(sarr[nt][0] - m_run[0]);
            float p1 = exp2f(sarr[nt][1] - m_run[1]);
            float p2 = exp2f(sarr[nt][2] - m_run[2]);
            float p3 = exp2f(sarr[nt][3] - m_run[3]);
            lp[0] += p0; lp[1] += p1; lp[2] += p2; lp[3] += p3;
            unsigned wlo = cvt_pk_bf16(p0, p1);
            unsigned whi = cvt_pk_bf16(p2, p3);
            const int gb = nt * 2 + (l15 >> 3);
            const int r0 = lg * 4;
            pw[(r0 + 0) * 64 + ((gb ^ ((r0 + 0) & 7))) * 8 + l7] = (u16)wlo;
            pw[(r0 + 1) * 64 + ((gb ^ ((r0 + 1) & 7))) * 8 + l7] = (u16)(wlo >> 16);
            pw[(r0 + 2) * 64 + ((gb ^ ((r0 + 2) & 7))) * 8 + l7] = (u16)whi;
            pw[(r0 + 3) * 64 + ((gb ^ ((r0 + 3) & 7))) * 8 + l7] = (u16)(whi >> 16);
        }
        #pragma unroll
        for (int r = 0; r < 4; r++) l_run[r] += lp[r];

        // ---- read P fragments back (same wave; lgkmcnt ordered) ----
        short8 pf[2];
        #pragma unroll
        for (int kc = 0; kc < 2; kc++)
            pf[kc] = *(const short8*)&pw[l15 * 64 + ((kc * 4 + lg) ^ l7) * 8];

        // ---- PV (swizzled V^T reads) ----
        #pragma unroll
        for (int nt = 0; nt < 4; nt++) {
            #pragma unroll
            for (int kc = 0; kc < 2; kc++) {
                const short8 vfrag = *(const short8*)
                    &Vs[cur][(nt * 16 + l15) * 64 + ((kc * 4 + lg) ^ l7) * 8];
                o_acc[nt] = __builtin_amdgcn_mfma_f32_16x16x32_bf16(pf[kc], vfrag, o_acc[nt], 0, 0, 0);
            }
        }
        __syncthreads();   // drains prefetch vmcnt + protects buffer reuse
    }

    const float hs = 1.0f + head_scale[h];
    #pragma unroll
    for (int r = 0; r < 4; r++) {
        float l = l_run[r];
        l += __shfl_xor(l, 1);
        l += __shfl_xor(l, 2);
        l += __shfl_xor(l, 4);
        l += __shfl_xor(l, 8);
        const int q = t0 + wave * 16 + lg * 4 + r;
        const float f = hs / l;
        u16* op = out + ((size_t)(b * TT + q) * NN) + h * QKD + l15;
        #pragma unroll
        for (int nt = 0; nt < 4; nt++)
            op[nt * 16] = f2bf(o_acc[nt][r] * f);
    }
}

// ---------------------------------------------------------------------------
extern "C" void kernel_launch(void* const* d_in, const int* in_sizes, int n_in,
                              void* d_out, int out_size, void* d_ws, size_t ws_size,
                              hipStream_t stream)
{
    const float* q          = (const float*)d_in[0];
    const float* kv         = (const float*)d_in[1];
    /* d_in[2] = causal mask -- handled analytically */
    const int*   qpos       = (const int*)d_in[3];
    const int*   kpos       = (const int*)d_in[4];
    const float* Wq         = (const float*)d_in[5];
    const float* bq         = (const float*)d_in[6];
    const float* Wk         = (const float*)d_in[7];
    const float* bk         = (const float*)d_in[8];
    const float* Wv         = (const float*)d_in[9];
    const float* bv         = (const float*)d_in[10];
    const float* q_scale    = (const float*)d_in[11];
    const float* k_scale    = (const float*)d_in[12];
    const float* head_scale = (const float*)d_in[13];
    const float* Wo         = (const float*)d_in[14];
    const float* bo         = (const float*)d_in[15];
    float* out = (float*)d_out;

    // workspace layout (bytes):
    //   [  0 MB, 16 MB)  qb    (M,K) bf16
    //   [ 16 MB, 32 MB)  kvb   (M,K) bf16
    //   [ 32 MB, 40 MB)  Wt    4 x (N,K) bf16 transposed: Wq,Wk,Wv,Wo
    //   [ 40 MB, 56 MB)  qh_b  (B,H,T,QK) bf16
    //   [ 56 MB, 72 MB)  kh_b  (B,H,T,QK) bf16
    //   [ 72 MB, 88 MB)  vt_b  (B,H,QK,T) bf16  <-- V stored transposed
    //   [ 88 MB,104 MB)  attn_b (B,T,N) bf16
    char* ws = (char*)d_ws;
    u16* qb     = (u16*)(ws);
    u16* kvb    = (u16*)(ws + (16u << 20));
    u16* Wt     = (u16*)(ws + (32u << 20));
    u16* qh_b   = (u16*)(ws + (40u << 20));
    u16* kh_b   = (u16*)(ws + (56u << 20));
    u16* vt_b   = (u16*)(ws + (72u << 20));
    u16* attn_b = (u16*)(ws + (88u << 20));

    // 1. cast activations to bf16
    acast_kernel<<<dim3(MM * DD / (256 * 4), 2), 256, 0, stream>>>(q, kv, qb, kvb);
    // 2. transpose+cast the four weight matrices
    wt_kernel<<<dim3(16, 16, 4), 256, 0, stream>>>(Wq, Wk, Wv, Wo, Wt);
    // 3. fused QKV projection + bias + RMSNorm + RoPE -> Q,K:(B,H,T,QK), V:(B,H,QK,T)
    qkv_gemm<<<dim3(NN / 128, MM / 128, 3), 256, 0, stream>>>(
        qb, kvb, Wt, bq, bk, bv, qpos, kpos, q_scale, k_scale, qh_b, kh_b, vt_b);
    // 4. causal MFMA flash attention + head_scale -> (B,T,N) bf16
    attn_mfma<<<dim3(TT / 64, HH, BB), 256, 0, stream>>>(qh_b, kh_b, vt_b, head_scale, attn_b);
    // 5. output projection + bias -> fp32
    out_gemm<<<dim3(NN / 128, MM / 128), 256, 0, stream>>>(attn_b, Wt + (size_t)3 * KK * NN, bo, out);
}

// Round 4
// 580.090 us; speedup vs baseline: 1.2190x; 1.1318x over previous
//
#include <hip/hip_runtime.h>
#include <math.h>

// Problem constants
#define BB 4
#define TT 2048
#define DD 1024
#define HH 16
#define QKD 64
#define MM (BB*TT)          // 8192
#define NN 1024             // H*QK == D
#define KK 1024

typedef unsigned short u16;
typedef __attribute__((ext_vector_type(8))) short short8;   // 8 bf16 = 4 VGPRs
typedef __attribute__((ext_vector_type(4))) float float4v;  // MFMA C/D
typedef __attribute__((ext_vector_type(4))) unsigned uint4v; // 16B staging reg

// fp32 -> bf16 round-to-nearest-even
__device__ __forceinline__ u16 f2bf(float f) {
    union { float f; unsigned u; } v; v.f = f;
    unsigned r = (v.u + 0x7FFFu + ((v.u >> 16) & 1u)) >> 16;
    return (u16)r;
}

// packed fp32x2 -> bf16x2 (RTNE), single instruction on gfx950
__device__ __forceinline__ unsigned cvt_pk_bf16(float lo, float hi) {
    unsigned r;
    asm("v_cvt_pk_bf16_f32 %0, %1, %2" : "=v"(r) : "v"(lo), "v"(hi));
    return r;
}

// async global->LDS, 16B per lane; LDS dest = wave-uniform base + lane*16
// (used by attn_mfma)
typedef __attribute__((address_space(3))) unsigned lds_u32_t;
typedef __attribute__((address_space(1))) const unsigned glb_u32_t;
__device__ __forceinline__ void gl2lds16(const u16* g, u16* l) {
    __builtin_amdgcn_global_load_lds((glb_u32_t*)g, (lds_u32_t*)l, 16, 0, 0);
}

// XCD band swizzle for an 8(n) x 64(m) grid: each XCD owns 8 m-rows x all 8
// n-tiles (2MB A-panel + 2MB B fits the 4MB per-XCD L2).  Bijective.
__device__ __forceinline__ void xcd_swizzle_8x64(int& m_idx, int& n_idx) {
    const int flat = blockIdx.y * 8 + blockIdx.x;   // 0..511
    const int xcd = flat & 7, q = flat >> 3;        // q: 0..63
    m_idx = xcd * 8 + (q & 7);                      // 0..63
    n_idx = q >> 3;                                 // 0..7
}

// ---------------------------------------------------------------------------
// fp32 -> bf16 cast for activations (q, kv)
// ---------------------------------------------------------------------------
__global__ __launch_bounds__(256) void acast_kernel(
    const float* __restrict__ a, const float* __restrict__ b,
    u16* __restrict__ da, u16* __restrict__ db)
{
    const float* s = blockIdx.y ? b : a;
    u16* d = blockIdx.y ? db : da;
    size_t i = ((size_t)blockIdx.x * 256 + threadIdx.x) * 4;
    float4 v = *(const float4*)&s[i];
    ushort4 o = { f2bf(v.x), f2bf(v.y), f2bf(v.z), f2bf(v.w) };
    *(ushort4*)&d[i] = o;
}

// ---------------------------------------------------------------------------
// Weight transpose + cast: W[K][N] fp32 -> Wt[N][K] bf16, z selects matrix
// ---------------------------------------------------------------------------
__global__ __launch_bounds__(256) void wt_kernel(
    const float* __restrict__ Wq, const float* __restrict__ Wk,
    const float* __restrict__ Wv, const float* __restrict__ Wo,
    u16* __restrict__ dstbase)
{
    const int z = blockIdx.z;
    const float* src = (z == 0) ? Wq : (z == 1) ? Wk : (z == 2) ? Wv : Wo;
    u16* out = dstbase + (size_t)z * (KK * NN);
    const int bi = blockIdx.y, bj = blockIdx.x;  // 64x64 tile: k-block, n-block
    __shared__ float tile[64][65];
    const int t = threadIdx.x;
    #pragma unroll
    for (int p = 0; p < 4; p++) {
        int idx = p * 256 + t;
        int r = idx >> 4, c4 = (idx & 15) << 2;
        float4 v = *(const float4*)&src[(size_t)(bi * 64 + r) * NN + bj * 64 + c4];
        tile[r][c4 + 0] = v.x; tile[r][c4 + 1] = v.y;
        tile[r][c4 + 2] = v.z; tile[r][c4 + 3] = v.w;
    }
    __syncthreads();
    #pragma unroll
    for (int p = 0; p < 4; p++) {
        int idx = p * 256 + t;
        int rn = idx >> 4, c4 = (idx & 15) << 2;
        ushort4 o = { f2bf(tile[c4 + 0][rn]), f2bf(tile[c4 + 1][rn]),
                      f2bf(tile[c4 + 2][rn]), f2bf(tile[c4 + 3][rn]) };
        *(ushort4*)&out[(size_t)(bj * 64 + rn) * KK + bi * 64 + c4] = o;
    }
}

// ---------------------------------------------------------------------------
// bf16 MFMA GEMM main loop: reg-staged, double-buffered LDS, one barrier per
// k-step.  Tile t+1 loaded to VGPRs before tile t's MFMA block (T14); the
// ds_write goes to the other buffer after the MFMAs.  LDS layout: slot s of
// row r holds global colblock s^(r&7).
// A: [M,K] bf16 row-major.  Bt: [N,K] bf16 row-major (i.e. W^T).
// ---------------------------------------------------------------------------
__device__ __forceinline__ void gemm_mainloop(
    const u16* __restrict__ A, const u16* __restrict__ Bt,
    int m0, int n0,
    u16* __restrict__ sA0, u16* __restrict__ sB0,
    u16* __restrict__ sA1, u16* __restrict__ sB1,
    float4v (&acc)[4][4])
{
    const int tid = threadIdx.x;
    const int wave = tid >> 6, lane = tid & 63;
    const int l15 = lane & 15, lg = lane >> 4;
    const int wm = wave >> 1, wn = wave & 1;

    const int lr = lane >> 3;   // row within 8-row chunk (== row&7)
    const int lc = lane & 7;    // colblock (UNswizzled global load)

    const u16* gA = A  + (size_t)(m0 + wave * 32 + lr) * KK + lc * 8;
    const u16* gB = Bt + (size_t)(n0 + wave * 32 + lr) * KK + lc * 8;
    const int wslot = (lc ^ lr) * 8;   // swizzled LDS slot (row&7 == lr)

    uint4v ar[4], br[4];
    auto gload = [&](int k0) {
        #pragma unroll
        for (int i = 0; i < 4; i++) {
            ar[i] = *(const uint4v*)(gA + (size_t)i * 8 * KK + k0);
            br[i] = *(const uint4v*)(gB + (size_t)i * 8 * KK + k0);
        }
    };
    auto swrite = [&](u16* sA, u16* sB) {
        #pragma unroll
        for (int i = 0; i < 4; i++) {
            const int chunk = wave * 4 + i;
            *(uint4v*)(sA + chunk * 512 + lr * 64 + wslot) = ar[i];
            *(uint4v*)(sB + chunk * 512 + lr * 64 + wslot) = br[i];
        }
    };

    gload(0);
    swrite(sA0, sB0);
    __syncthreads();

    for (int t = 0; t < 16; t++) {
        if (t < 15) gload((t + 1) * 64);          // overlap with compute
        u16* sA = (t & 1) ? sA1 : sA0;
        u16* sB = (t & 1) ? sB1 : sB0;

        short8 af[2][4], bf[2][4];
        #pragma unroll
        for (int kc = 0; kc < 2; kc++) {
            #pragma unroll
            for (int x = 0; x < 4; x++) {
                int ra = wm * 64 + x * 16 + l15;
                int sa = (kc * 4 + lg) ^ (ra & 7);
                af[kc][x] = *(const short8*)(sA + ra * 64 + sa * 8);
                int rb = wn * 64 + x * 16 + l15;
                int sb = (kc * 4 + lg) ^ (rb & 7);
                bf[kc][x] = *(const short8*)(sB + rb * 64 + sb * 8);
            }
        }
        #pragma unroll
        for (int mi = 0; mi < 4; mi++)
            #pragma unroll
            for (int nj = 0; nj < 4; nj++) {
                acc[mi][nj] = __builtin_amdgcn_mfma_f32_16x16x32_bf16(af[0][mi], bf[0][nj], acc[mi][nj], 0, 0, 0);
                acc[mi][nj] = __builtin_amdgcn_mfma_f32_16x16x32_bf16(af[1][mi], bf[1][nj], acc[mi][nj], 0, 0, 0);
            }
        if (t < 15) swrite((t & 1) ? sA0 : sA1, (t & 1) ? sB0 : sB1);
        __syncthreads();
    }
}

// ---------------------------------------------------------------------------
// Q/K projection GEMM, z in {0:Q, 1:K}. Epilogue fuses bias + RMSNorm + RoPE
// and writes bf16 (B,H,T,QK) via LDS (coalesced 128B-line stores).
// Q also gets 0.125*log2(e).
// ---------------------------------------------------------------------------
__global__ __launch_bounds__(256) void qk_gemm(
    const u16* __restrict__ qb, const u16* __restrict__ kvb,
    const u16* __restrict__ Wt,
    const float* __restrict__ bq, const float* __restrict__ bk,
    const int* __restrict__ qpos, const int* __restrict__ kpos,
    const float* __restrict__ q_scale, const float* __restrict__ k_scale,
    u16* __restrict__ qh, u16* __restrict__ kh)
{
    __shared__ __align__(16) u16 sh[4][128 * 64];   // A0,B0,A1,B1; [0..1] reused by epilogue

    const int z = blockIdx.z;
    const u16* A        = (z == 0) ? qb : kvb;
    const u16* B        = Wt + (size_t)z * (KK * NN);
    const float* bias   = (z == 0) ? bq : bk;
    const float* scl    = (z == 0) ? q_scale : k_scale;
    const int* pos_arr  = (z == 0) ? qpos : kpos;
    u16* dst            = (z == 0) ? qh : kh;

    int m_idx, n_idx;
    xcd_swizzle_8x64(m_idx, n_idx);
    const int m0 = m_idx * 128, n0 = n_idx * 128;

    float4v acc[4][4];
    #pragma unroll
    for (int i = 0; i < 4; i++)
        #pragma unroll
        for (int j = 0; j < 4; j++) acc[i][j] = (float4v){0.f, 0.f, 0.f, 0.f};

    gemm_mainloop(A, B, m0, n0, &sh[0][0], &sh[1][0], &sh[2][0], &sh[3][0], acc);

    const int tid = threadIdx.x;
    const int lane = tid & 63, wave = tid >> 6;
    const int l15 = lane & 15, lg = lane >> 4;
    const int wm = wave >> 1, wn = wave & 1;
    const int mbase = m0 + wm * 64;
    const int nbase = n0 + wn * 64;
    const int h = nbase >> 6;

    float bia[4], sc[4];
    #pragma unroll
    for (int nj = 0; nj < 4; nj++) {
        bia[nj] = bias[nbase - (h << 6) + h * 64 + nj * 16 + l15];  // = bias[h*64+c]
        sc[nj]  = 1.0f + scl[nj * 16 + l15];
    }
    float invts[2];
    #pragma unroll
    for (int p = 0; p < 2; p++)
        invts[p] = powf(10000.0f, -(float)(p * 16 + l15) * (1.0f / 32.0f));

    const float QMUL = 0.125f * 1.44269504088896340736f;

    u16* sh_ep = &sh[0][0];   // 128 x 128 u16 epilogue stash (32 KB)

    #pragma unroll
    for (int mi = 0; mi < 4; mi++) {
        #pragma unroll
        for (int r = 0; r < 4; r++) {
            const int m = mbase + mi * 16 + lg * 4 + r;
            const int b = m >> 11, t = m & 2047;
            const int tl = wm * 64 + mi * 16 + lg * 4 + r;   // local row 0..127
            float v[4];
            #pragma unroll
            for (int nj = 0; nj < 4; nj++) v[nj] = acc[mi][nj][r] + bia[nj];

            float ss = v[0]*v[0] + v[1]*v[1] + v[2]*v[2] + v[3]*v[3];
            ss += __shfl_xor(ss, 1);
            ss += __shfl_xor(ss, 2);
            ss += __shfl_xor(ss, 4);
            ss += __shfl_xor(ss, 8);
            float rn = rsqrtf(ss * (1.0f / 64.0f) + 1e-6f);
            #pragma unroll
            for (int nj = 0; nj < 4; nj++) v[nj] = v[nj] * rn * sc[nj];

            const float pos = (float)pos_arr[b * TT + t];
            #pragma unroll
            for (int p = 0; p < 2; p++) {
                float ang = pos * invts[p];
                float s = sinf(ang), c = cosf(ang);
                float x1 = v[p], x2 = v[p + 2];
                v[p]     = x1 * c - x2 * s;
                v[p + 2] = x2 * c + x1 * s;
            }
            if (z == 0) {
                #pragma unroll
                for (int nj = 0; nj < 4; nj++) v[nj] *= QMUL;
            }
            #pragma unroll
            for (int nj = 0; nj < 4; nj++) {
                const int dl = wn * 64 + nj * 16 + l15;
                sh_ep[tl * 128 + (dl ^ ((tl & 7) << 3))] = f2bf(v[nj]);
            }
        }
    }

    __syncthreads();
    const int bb_ = m0 >> 11;       // batch (tile never straddles a batch)
    const int t0g = m0 & 2047;      // global t base of this tile
    #pragma unroll
    for (int p = 0; p < 8; p++) {
        int idx = p * 256 + tid;    // 0..2047
        int tl  = idx >> 4;         // 0..127
        int c8  = (idx & 15) << 3;  // 0..120 step 8
        short8 v8 = *(const short8*)&sh_ep[tl * 128 + (c8 ^ ((tl & 7) << 3))];
        int hh_ = (n0 + c8) >> 6, dih = (n0 + c8) & 63;
        *(short8*)&dst[((size_t)(bb_ * HH + hh_) * TT + t0g + tl) * QKD + dih] = v8;
    }
}

// ---------------------------------------------------------------------------
// V projection GEMM. Epilogue: bias only, writes bf16 transposed (B,H,QK,T)
// via LDS transpose stash (coalesced 128B-line stores).  Separate dispatch
// so rocprof attributes its FETCH/WRITE independently of Q/K.
// ---------------------------------------------------------------------------
__global__ __launch_bounds__(256) void v_gemm(
    const u16* __restrict__ kvb, const u16* __restrict__ Wt,
    const float* __restrict__ bv, u16* __restrict__ vt)
{
    __shared__ __align__(16) u16 sh[4][128 * 64];

    const u16* B = Wt + (size_t)2 * (KK * NN);

    int m_idx, n_idx;
    xcd_swizzle_8x64(m_idx, n_idx);
    const int m0 = m_idx * 128, n0 = n_idx * 128;

    float4v acc[4][4];
    #pragma unroll
    for (int i = 0; i < 4; i++)
        #pragma unroll
        for (int j = 0; j < 4; j++) acc[i][j] = (float4v){0.f, 0.f, 0.f, 0.f};

    gemm_mainloop(kvb, B, m0, n0, &sh[0][0], &sh[1][0], &sh[2][0], &sh[3][0], acc);

    const int tid = threadIdx.x;
    const int lane = tid & 63, wave = tid >> 6;
    const int l15 = lane & 15, lg = lane >> 4;
    const int wm = wave >> 1, wn = wave & 1;
    const int nbase = n0 + wn * 64;
    const int h = nbase >> 6;

    float bia[4];
    #pragma unroll
    for (int nj = 0; nj < 4; nj++)
        bia[nj] = bv[nbase - (h << 6) + h * 64 + nj * 16 + l15];

    u16* sh_ep = &sh[0][0];   // 128(d) x 128(t) u16 transpose stash

    #pragma unroll
    for (int mi = 0; mi < 4; mi++) {
        #pragma unroll
        for (int r = 0; r < 4; r++) {
            const int tl = wm * 64 + mi * 16 + lg * 4 + r;   // local t 0..127
            #pragma unroll
            for (int nj = 0; nj < 4; nj++) {
                const int dl = wn * 64 + nj * 16 + l15;      // local d 0..127
                sh_ep[dl * 128 + (tl ^ ((dl & 7) << 3))] = f2bf(acc[mi][nj][r] + bia[nj]);
            }
        }
    }

    __syncthreads();
    const int bb_ = m0 >> 11;
    const int t0g = m0 & 2047;
    #pragma unroll
    for (int p = 0; p < 8; p++) {
        int idx = p * 256 + tid;    // 0..2047
        int dl  = idx >> 4;         // 0..127
        int tc  = (idx & 15) << 3;  // 0..120 step 8
        short8 v8 = *(const short8*)&sh_ep[dl * 128 + (tc ^ ((dl & 7) << 3))];
        int hh_ = (n0 + dl) >> 6, dih = (n0 + dl) & 63;
        *(short8*)&vt[((size_t)(bb_ * HH + hh_) * QKD + dih) * TT + t0g + tc] = v8;
    }
}

// ---------------------------------------------------------------------------
// Output projection GEMM: attn_b[M,K] bf16 @ Wo_t[N,K]^T + bo -> out fp32
// ---------------------------------------------------------------------------
__global__ __launch_bounds__(256) void out_gemm(
    const u16* __restrict__ A, const u16* __restrict__ Bt,
    const float* __restrict__ bo, float* __restrict__ out)
{
    __shared__ __align__(16) u16 sh[4][128 * 64];

    int m_idx, n_idx;
    xcd_swizzle_8x64(m_idx, n_idx);
    const int m0 = m_idx * 128, n0 = n_idx * 128;

    float4v acc[4][4];
    #pragma unroll
    for (int i = 0; i < 4; i++)
        #pragma unroll
        for (int j = 0; j < 4; j++) acc[i][j] = (float4v){0.f, 0.f, 0.f, 0.f};

    gemm_mainloop(A, Bt, m0, n0, &sh[0][0], &sh[1][0], &sh[2][0], &sh[3][0], acc);

    const int lane = threadIdx.x & 63, wave = threadIdx.x >> 6;
    const int l15 = lane & 15, lg = lane >> 4;
    const int wm = wave >> 1, wn = wave & 1;
    const int mbase = m0 + wm * 64;
    const int nbase = n0 + wn * 64;

    float bov[4];
    #pragma unroll
    for (int nj = 0; nj < 4; nj++) bov[nj] = bo[nbase + nj * 16 + l15];

    #pragma unroll
    for (int mi = 0; mi < 4; mi++)
        #pragma unroll
        for (int r = 0; r < 4; r++) {
            const int m = mbase + mi * 16 + lg * 4 + r;
            float* op = out + (size_t)m * NN + nbase + l15;
            #pragma unroll
            for (int nj = 0; nj < 4; nj++)
                op[nj * 16] = acc[mi][nj][r] + bov[nj];
        }
}

// ---------------------------------------------------------------------------
// MFMA flash attention, causal (unchanged this round):
//  - K rows and V^T rows staged via global_load_lds (16B) into XOR-swizzled
//    linear LDS; double-buffered K/V prefetch (T3 minimal 2-phase)
//  - defer-max rescale (T13, THR=8 in exp2 domain)
//  - packed v_cvt_pk_bf16_f32 for the P->bf16 LDS store
//  - per-lane partial rowsum; cross-lane l-reduce once in the epilogue
// ---------------------------------------------------------------------------
__global__ __launch_bounds__(256) void attn_mfma(
    const u16* __restrict__ qh, const u16* __restrict__ kh,
    const u16* __restrict__ vt, const float* __restrict__ head_scale,
    u16* __restrict__ out)
{
    __shared__ __align__(16) u16 Ks[2][64 * 64];   // K rows (swizzled)
    __shared__ __align__(16) u16 Vs[2][64 * 64];   // V^T rows = d (swizzled)
    __shared__ __align__(16) u16 Ps[4][16 * 64];   // per-wave P tile (swizzled)

    const int b = blockIdx.z, h = blockIdx.y, qt = blockIdx.x;
    const int t0 = qt * 64;
    const int tid  = threadIdx.x;
    const int wave = tid >> 6, lane = tid & 63;
    const int l15 = lane & 15, lg = lane >> 4;
    const int l7 = l15 & 7;

    const size_t bh = (size_t)(b * HH + h);
    const u16* qbh  = qh + bh * TT * QKD;
    const u16* kbh  = kh + bh * TT * QKD;
    const u16* vtbh = vt + bh * QKD * TT;   // [QKD][TT]

    short8 qfrag[2];
    #pragma unroll
    for (int kc = 0; kc < 2; kc++)
        qfrag[kc] = *(const short8*)(qbh + (size_t)(t0 + wave * 16 + l15) * QKD
                                      + kc * 32 + lg * 8);

    auto stage = [&](int buf, int j0s) {
        #pragma unroll
        for (int rr = 0; rr < 2; rr++) {
            const int c   = rr * 256 + tid;     // chunk 0..511 (16B each)
            const int row = c >> 3;             // 0..63
            const int g   = (c & 7) ^ (row & 7);// pre-swizzled global colblock
            u16* ldsK = &Ks[buf][(rr * 256 + (wave << 6)) * 8];
            u16* ldsV = &Vs[buf][(rr * 256 + (wave << 6)) * 8];
            gl2lds16(kbh  + (size_t)(j0s + row) * QKD + g * 8, ldsK);
            gl2lds16(vtbh + (size_t)row * TT + j0s + g * 8, ldsV);
        }
    };

    float4v o_acc[4];
    #pragma unroll
    for (int nt = 0; nt < 4; nt++) o_acc[nt] = (float4v){0.f, 0.f, 0.f, 0.f};
    float m_run[4] = {-INFINITY, -INFINITY, -INFINITY, -INFINITY};
    float l_run[4] = {0.f, 0.f, 0.f, 0.f};

    stage(0, 0);
    __syncthreads();

    const int qbase = t0 + wave * 16 + lg * 4;

    for (int j0 = 0; j0 <= t0; j0 += 64) {
        const int cur = (j0 >> 6) & 1;
        if (j0 + 64 <= t0) stage(cur ^ 1, j0 + 64);   // prefetch next tile

        // ---- QK^T (swizzled K reads) ----
        float4v sarr[4];
        #pragma unroll
        for (int nt = 0; nt < 4; nt++) {
            float4v s = (float4v){0.f, 0.f, 0.f, 0.f};
            #pragma unroll
            for (int kc = 0; kc < 2; kc++) {
                const short8 bfrag = *(const short8*)
                    &Ks[cur][(nt * 16 + l15) * 64 + ((kc * 4 + lg) ^ l7) * 8];
                s = __builtin_amdgcn_mfma_f32_16x16x32_bf16(qfrag[kc], bfrag, s, 0, 0, 0);
            }
            sarr[nt] = s;
        }

        // ---- causal mask (diagonal tile only) ----
        if (j0 == t0) {
            #pragma unroll
            for (int nt = 0; nt < 4; nt++) {
                int jkey = j0 + nt * 16 + l15;
                #pragma unroll
                for (int r = 0; r < 4; r++)
                    if (jkey > qbase + r) sarr[nt][r] = -INFINITY;
            }
        }

        // ---- row max + defer-max rescale (T13) ----
        float pm[4];
        #pragma unroll
        for (int r = 0; r < 4; r++) {
            float m = fmaxf(fmaxf(sarr[0][r], sarr[1][r]), fmaxf(sarr[2][r], sarr[3][r]));
            m = fmaxf(m, __shfl_xor(m, 1));
            m = fmaxf(m, __shfl_xor(m, 2));
            m = fmaxf(m, __shfl_xor(m, 4));
            m = fmaxf(m, __shfl_xor(m, 8));
            pm[r] = m;
        }
        float grow = fmaxf(fmaxf(pm[0] - m_run[0], pm[1] - m_run[1]),
                           fmaxf(pm[2] - m_run[2], pm[3] - m_run[3]));
        if (__any(grow > 8.0f)) {
            #pragma unroll
            for (int r = 0; r < 4; r++) {
                float mn = fmaxf(m_run[r], pm[r]);
                float a  = exp2f(m_run[r] - mn);
                m_run[r] = mn;
                l_run[r] *= a;
                #pragma unroll
                for (int nt = 0; nt < 4; nt++) o_acc[nt][r] *= a;
            }
        }

        // ---- P = exp2(S - m), partial rowsum, packed bf16 store to Ps ----
        u16* pw = Ps[wave];
        float lp[4] = {0.f, 0.f, 0.f, 0.f};
        #pragma unroll
        for (int nt = 0; nt < 4; nt++) {
            float p0 = exp2f(sarr[nt][0] - m_run[0]);
            float p1 = exp2f(sarr[nt][1] - m_run[1]);
            float p2 = exp2f(sarr[nt][2] - m_run[2]);
            float p3 = exp2f(sarr[nt][3] - m_run[3]);
            lp[0] += p0; lp[1] += p1; lp[2] += p2; lp[3] += p3;
            unsigned wlo = cvt_pk_bf16(p0, p1);
            unsigned whi = cvt_pk_bf16(p2, p3);
            const int gb = nt * 2 + (l15 >> 3);
            const int r0 = lg * 4;
            pw[(r0 + 0) * 64 + ((gb ^ ((r0 + 0) & 7))) * 8 + l7] = (u16)wlo;
            pw[(r0 + 1) * 64 + ((gb ^ ((r0 + 1) & 7))) * 8 + l7] = (u16)(wlo >> 16);
            pw[(r0 + 2) * 64 + ((gb ^ ((r0 + 2) & 7))) * 8 + l7] = (u16)whi;
            pw[(r0 + 3) * 64 + ((gb ^ ((r0 + 3) & 7))) * 8 + l7] = (u16)(whi >> 16);
        }
        #pragma unroll
        for (int r = 0; r < 4; r++) l_run[r] += lp[r];

        // ---- read P fragments back (same wave; lgkmcnt ordered) ----
        short8 pf[2];
        #pragma unroll
        for (int kc = 0; kc < 2; kc++)
            pf[kc] = *(const short8*)&pw[l15 * 64 + ((kc * 4 + lg) ^ l7) * 8];

        // ---- PV (swizzled V^T reads) ----
        #pragma unroll
        for (int nt = 0; nt < 4; nt++) {
            #pragma unroll
            for (int kc = 0; kc < 2; kc++) {
                const short8 vfrag = *(const short8*)
                    &Vs[cur][(nt * 16 + l15) * 64 + ((kc * 4 + lg) ^ l7) * 8];
                o_acc[nt] = __builtin_amdgcn_mfma_f32_16x16x32_bf16(pf[kc], vfrag, o_acc[nt], 0, 0, 0);
            }
        }
        __syncthreads();   // drains prefetch vmcnt + protects buffer reuse
    }

    const float hs = 1.0f + head_scale[h];
    #pragma unroll
    for (int r = 0; r < 4; r++) {
        float l = l_run[r];
        l += __shfl_xor(l, 1);
        l += __shfl_xor(l, 2);
        l += __shfl_xor(l, 4);
        l += __shfl_xor(l, 8);
        const int q = t0 + wave * 16 + lg * 4 + r;
        const float f = hs / l;
        u16* op = out + ((size_t)(b * TT + q) * NN) + h * QKD + l15;
        #pragma unroll
        for (int nt = 0; nt < 4; nt++)
            op[nt * 16] = f2bf(o_acc[nt][r] * f);
    }
}

// ---------------------------------------------------------------------------
extern "C" void kernel_launch(void* const* d_in, const int* in_sizes, int n_in,
                              void* d_out, int out_size, void* d_ws, size_t ws_size,
                              hipStream_t stream)
{
    const float* q          = (const float*)d_in[0];
    const float* kv         = (const float*)d_in[1];
    /* d_in[2] = causal mask -- handled analytically */
    const int*   qpos       = (const int*)d_in[3];
    const int*   kpos       = (const int*)d_in[4];
    const float* Wq         = (const float*)d_in[5];
    const float* bq         = (const float*)d_in[6];
    const float* Wk         = (const float*)d_in[7];
    const float* bk         = (const float*)d_in[8];
    const float* Wv         = (const float*)d_in[9];
    const float* bv         = (const float*)d_in[10];
    const float* q_scale    = (const float*)d_in[11];
    const float* k_scale    = (const float*)d_in[12];
    const float* head_scale = (const float*)d_in[13];
    const float* Wo         = (const float*)d_in[14];
    const float* bo         = (const float*)d_in[15];
    float* out = (float*)d_out;

    // workspace layout (bytes):
    //   [  0 MB, 16 MB)  qb    (M,K) bf16
    //   [ 16 MB, 32 MB)  kvb   (M,K) bf16
    //   [ 32 MB, 40 MB)  Wt    4 x (N,K) bf16 transposed: Wq,Wk,Wv,Wo
    //   [ 40 MB, 56 MB)  qh_b  (B,H,T,QK) bf16
    //   [ 56 MB, 72 MB)  kh_b  (B,H,T,QK) bf16
    //   [ 72 MB, 88 MB)  vt_b  (B,H,QK,T) bf16  <-- V stored transposed
    //   [ 88 MB,104 MB)  attn_b (B,T,N) bf16
    char* ws = (char*)d_ws;
    u16* qb     = (u16*)(ws);
    u16* kvb    = (u16*)(ws + (16u << 20));
    u16* Wt     = (u16*)(ws + (32u << 20));
    u16* qh_b   = (u16*)(ws + (40u << 20));
    u16* kh_b   = (u16*)(ws + (56u << 20));
    u16* vt_b   = (u16*)(ws + (72u << 20));
    u16* attn_b = (u16*)(ws + (88u << 20));

    // 1. cast activations to bf16
    acast_kernel<<<dim3(MM * DD / (256 * 4), 2), 256, 0, stream>>>(q, kv, qb, kvb);
    // 2. transpose+cast the four weight matrices
    wt_kernel<<<dim3(16, 16, 4), 256, 0, stream>>>(Wq, Wk, Wv, Wo, Wt);
    // 3a. Q/K projection + bias + RMSNorm + RoPE -> (B,H,T,QK) bf16
    qk_gemm<<<dim3(NN / 128, MM / 128, 2), 256, 0, stream>>>(
        qb, kvb, Wt, bq, bk, qpos, kpos, q_scale, k_scale, qh_b, kh_b);
    // 3b. V projection + bias -> (B,H,QK,T) bf16 (separate dispatch for
    //     independent rocprof attribution of the write-traffic anomaly)
    v_gemm<<<dim3(NN / 128, MM / 128), 256, 0, stream>>>(kvb, Wt, bv, vt_b);
    // 4. causal MFMA flash attention + head_scale -> (B,T,N) bf16
    attn_mfma<<<dim3(TT / 64, HH, BB), 256, 0, stream>>>(qh_b, kh_b, vt_b, head_scale, attn_b);
    // 5. output projection + bias -> fp32
    out_gemm<<<dim3(NN / 128, MM / 128), 256, 0, stream>>>(attn_b, Wt + (size_t)3 * KK * NN, bo, out);
}

// Round 5
// 544.447 us; speedup vs baseline: 1.2988x; 1.0655x over previous
//
#include <hip/hip_runtime.h>
#include <math.h>

// Problem constants
#define BB 4
#define TT 2048
#define DD 1024
#define HH 16
#define QKD 64
#define MM (BB*TT)          // 8192
#define NN 1024             // H*QK == D
#define KK 1024

// 256x256 GEMM tile geometry
#define BKQ 32              // K-step
#define NTS (KK/BKQ)        // 32 k-steps

typedef unsigned short u16;
typedef __attribute__((ext_vector_type(8))) short short8;   // 8 bf16 = 4 VGPRs
typedef __attribute__((ext_vector_type(4))) float float4v;  // MFMA C/D

// fp32 -> bf16 round-to-nearest-even
__device__ __forceinline__ u16 f2bf(float f) {
    union { float f; unsigned u; } v; v.f = f;
    unsigned r = (v.u + 0x7FFFu + ((v.u >> 16) & 1u)) >> 16;
    return (u16)r;
}

// packed fp32x2 -> bf16x2 (RTNE), single instruction on gfx950
__device__ __forceinline__ unsigned cvt_pk_bf16(float lo, float hi) {
    unsigned r;
    asm("v_cvt_pk_bf16_f32 %0, %1, %2" : "=v"(r) : "v"(lo), "v"(hi));
    return r;
}

// async global->LDS, 16B per lane; LDS dest = wave-uniform base + lane*16
typedef __attribute__((address_space(3))) unsigned lds_u32_t;
typedef __attribute__((address_space(1))) const unsigned glb_u32_t;
__device__ __forceinline__ void gl2lds16(const u16* g, u16* l) {
    __builtin_amdgcn_global_load_lds((glb_u32_t*)g, (lds_u32_t*)l, 16, 0, 0);
}

// ---------------------------------------------------------------------------
// fp32 -> bf16 cast for activations (q, kv)
// ---------------------------------------------------------------------------
__global__ __launch_bounds__(256) void acast_kernel(
    const float* __restrict__ a, const float* __restrict__ b,
    u16* __restrict__ da, u16* __restrict__ db)
{
    const float* s = blockIdx.y ? b : a;
    u16* d = blockIdx.y ? db : da;
    size_t i = ((size_t)blockIdx.x * 256 + threadIdx.x) * 4;
    float4 v = *(const float4*)&s[i];
    ushort4 o = { f2bf(v.x), f2bf(v.y), f2bf(v.z), f2bf(v.w) };
    *(ushort4*)&d[i] = o;
}

// ---------------------------------------------------------------------------
// Weight transpose + cast: W[K][N] fp32 -> Wt[N][K] bf16, z selects matrix
// ---------------------------------------------------------------------------
__global__ __launch_bounds__(256) void wt_kernel(
    const float* __restrict__ Wq, const float* __restrict__ Wk,
    const float* __restrict__ Wv, const float* __restrict__ Wo,
    u16* __restrict__ dstbase)
{
    const int z = blockIdx.z;
    const float* src = (z == 0) ? Wq : (z == 1) ? Wk : (z == 2) ? Wv : Wo;
    u16* out = dstbase + (size_t)z * (KK * NN);
    const int bi = blockIdx.y, bj = blockIdx.x;  // 64x64 tile: k-block, n-block
    __shared__ float tile[64][65];
    const int t = threadIdx.x;
    #pragma unroll
    for (int p = 0; p < 4; p++) {
        int idx = p * 256 + t;
        int r = idx >> 4, c4 = (idx & 15) << 2;
        float4 v = *(const float4*)&src[(size_t)(bi * 64 + r) * NN + bj * 64 + c4];
        tile[r][c4 + 0] = v.x; tile[r][c4 + 1] = v.y;
        tile[r][c4 + 2] = v.z; tile[r][c4 + 3] = v.w;
    }
    __syncthreads();
    #pragma unroll
    for (int p = 0; p < 4; p++) {
        int idx = p * 256 + t;
        int rn = idx >> 4, c4 = (idx & 15) << 2;
        ushort4 o = { f2bf(tile[c4 + 0][rn]), f2bf(tile[c4 + 1][rn]),
                      f2bf(tile[c4 + 2][rn]), f2bf(tile[c4 + 3][rn]) };
        *(ushort4*)&out[(size_t)(bj * 64 + rn) * KK + bi * 64 + c4] = o;
    }
}

// ---------------------------------------------------------------------------
// 256x256 bf16 MFMA GEMM mainloop.  8 waves (512 thr), wave grid 2(m)x4(n),
// per-wave output 128x64 = acc[8][4].  BK=32, double-buffered 64KB LDS,
// gl_lds staging with pre-swizzled global source (slot cb of row r holds
// global colblock cb^(r&3)), raw s_barrier + counted vmcnt(4) (never 0 in
// steady state), setprio(1) around the 32-MFMA cluster.
// A: [M,K] bf16 row-major.  Bt: [N,K] bf16 row-major (i.e. W^T).
// sh: 64KB u16[32768]: A bufs at [0], B bufs at [16384].
// ---------------------------------------------------------------------------
__device__ __forceinline__ void gemm256_mainloop(
    const u16* __restrict__ A, const u16* __restrict__ Bt,
    int m0, int n0, u16* __restrict__ sh, float4v (&acc)[8][4])
{
    const int tid = threadIdx.x;          // 0..511
    const int lane = tid & 63;
    const int l15 = lane & 15, lg = lane >> 4;
    const int wave = tid >> 6;
    const int wm = wave >> 2, wn = wave & 3;

    u16* sA = sh;                 // [2][256*32]
    u16* sB = sh + 16384;         // [2][256*32]

    // staging chunks: c0 = tid, c1 = 512+tid; chunk c -> row r=c>>2, cb=c&3,
    // global colblock g = cb ^ (r&3)
    const int c0 = tid, c1 = 512 + tid;
    const int r0s = c0 >> 2, g0 = (c0 & 3) ^ (r0s & 3);
    const int r1s = c1 >> 2, g1 = (c1 & 3) ^ (r1s & 3);

    const u16* gA0 = A  + (size_t)(m0 + r0s) * KK + g0 * 8;
    const u16* gA1 = A  + (size_t)(m0 + r1s) * KK + g1 * 8;
    const u16* gB0 = Bt + (size_t)(n0 + r0s) * KK + g0 * 8;
    const u16* gB1 = Bt + (size_t)(n0 + r1s) * KK + g1 * 8;

    auto issue = [&](int buf, int k0) {
        u16* dA = sA + buf * (256 * 32);
        u16* dB = sB + buf * (256 * 32);
        gl2lds16(gA0 + k0, dA + c0 * 8);
        gl2lds16(gA1 + k0, dA + c1 * 8);
        gl2lds16(gB0 + k0, dB + c0 * 8);
        gl2lds16(gB1 + k0, dB + c1 * 8);
    };

    issue(0, 0);
    issue(1, BKQ);
    asm volatile("s_waitcnt vmcnt(4)" ::: "memory");   // tile 0 landed
    __builtin_amdgcn_s_barrier();
    __builtin_amdgcn_sched_barrier(0);

    for (int t = 0; t < NTS; t++) {
        const int buf = t & 1;
        const u16* cA = sA + buf * (256 * 32);
        const u16* cB = sB + buf * (256 * 32);

        short8 af[8], bf[4];
        #pragma unroll
        for (int x = 0; x < 8; x++) {
            int ra = wm * 128 + x * 16 + l15;
            af[x] = *(const short8*)(cA + (ra * 4 + (lg ^ (ra & 3))) * 8);
        }
        #pragma unroll
        for (int x = 0; x < 4; x++) {
            int rb = wn * 64 + x * 16 + l15;
            bf[x] = *(const short8*)(cB + (rb * 4 + (lg ^ (rb & 3))) * 8);
        }
        __builtin_amdgcn_s_setprio(1);
        #pragma unroll
        for (int mi = 0; mi < 8; mi++)
            #pragma unroll
            for (int nj = 0; nj < 4; nj++)
                acc[mi][nj] = __builtin_amdgcn_mfma_f32_16x16x32_bf16(af[mi], bf[nj], acc[mi][nj], 0, 0, 0);
        __builtin_amdgcn_s_setprio(0);

        __builtin_amdgcn_s_barrier();          // all waves done reading buf
        if (t + 2 < NTS) {
            issue(buf, (t + 2) * BKQ);         // refill just-freed buffer
            asm volatile("s_waitcnt vmcnt(4)" ::: "memory");  // tile t+1 landed
        } else {
            asm volatile("s_waitcnt vmcnt(0)" ::: "memory");  // tail drain
        }
        __builtin_amdgcn_s_barrier();          // collective: t+1 visible to all
        __builtin_amdgcn_sched_barrier(0);
    }
}

// XCD band swizzle for a 4(n) x 32(m) grid: flat -> (m_idx, n_idx) so each
// XCD owns a contiguous band of 4 m-rows x all 4 n-tiles (A 2MB + B 2MB fits
// the 4MB per-XCD L2).  Bijective (128 = 8 x 16).
__device__ __forceinline__ void xcd_swizzle_4x32(int& m_idx, int& n_idx) {
    const int flat = blockIdx.y * 4 + blockIdx.x;   // 0..127
    const int xcd = flat & 7, q = flat >> 3;        // q: 0..15
    m_idx = xcd * 4 + (q & 3);                      // 0..31
    n_idx = q >> 2;                                 // 0..3
}

// ---------------------------------------------------------------------------
// QKV projection GEMM (256^2 tile), z in {0:Q, 1:K, 2:V}.
// Q,K: bias + RMSNorm + RoPE -> (B,H,T,QK) bf16 (Q also * 0.125*log2e).
// V:   bias -> transposed (B,H,QK,T) bf16.
// Epilogue stores route through the freed 64KB LDS in two 128-row passes so
// every global store instruction writes full 128B lines.
// ---------------------------------------------------------------------------
__global__ __launch_bounds__(512) void qkv_gemm(
    const u16* __restrict__ qb, const u16* __restrict__ kvb,
    const u16* __restrict__ Wt,
    const float* __restrict__ bq, const float* __restrict__ bk, const float* __restrict__ bv,
    const int* __restrict__ qpos, const int* __restrict__ kpos,
    const float* __restrict__ q_scale, const float* __restrict__ k_scale,
    u16* __restrict__ qh, u16* __restrict__ kh, u16* __restrict__ vt)
{
    __shared__ __align__(16) u16 sh[32768];   // 64 KB: staging, then epilogue stash

    const int z = blockIdx.z;
    const u16* A        = (z == 0) ? qb : kvb;
    const u16* B        = Wt + (size_t)z * (KK * NN);
    const float* bias   = (z == 0) ? bq : (z == 1) ? bk : bv;
    const float* scl    = (z == 0) ? q_scale : k_scale;
    const int* pos_arr  = (z == 0) ? qpos : kpos;
    u16* dst            = (z == 0) ? qh : (z == 1) ? kh : vt;

    int m_idx, n_idx;
    xcd_swizzle_4x32(m_idx, n_idx);
    const int m0 = m_idx * 256, n0 = n_idx * 256;

    float4v acc[8][4];
    #pragma unroll
    for (int i = 0; i < 8; i++)
        #pragma unroll
        for (int j = 0; j < 4; j++) acc[i][j] = (float4v){0.f, 0.f, 0.f, 0.f};

    gemm256_mainloop(A, B, m0, n0, sh, acc);

    const int tid = threadIdx.x;
    const int lane = tid & 63, wave = tid >> 6;
    const int l15 = lane & 15, lg = lane >> 4;
    const int wm = wave >> 2, wn = wave & 3;

    // per-lane constants: column c = n0 + wn*64 + nj*16 + l15; bias[c];
    // dih = nj*16 + l15 (wave covers exactly one 64-col head)
    float bia[4], sc[4];
    #pragma unroll
    for (int nj = 0; nj < 4; nj++) {
        bia[nj] = bias[n0 + wn * 64 + nj * 16 + l15];
        sc[nj]  = 1.0f + scl[nj * 16 + l15];
    }
    float invts[2];
    #pragma unroll
    for (int p = 0; p < 2; p++)
        invts[p] = powf(10000.0f, -(float)(p * 16 + l15) * (1.0f / 32.0f));

    const float QMUL = 0.125f * 1.44269504088896340736f;
    const int bb_ = m0 >> 11;       // batch (tile never straddles a batch)
    const int t0g = m0 & 2047;      // global t base of this tile

    if (z < 2) {
        // ---- Q/K epilogue: two passes of 128 rows through the LDS stash ----
        #pragma unroll
        for (int p = 0; p < 2; p++) {
            __syncthreads();
            if (wm == p) {
                #pragma unroll
                for (int mi = 0; mi < 8; mi++) {
                    #pragma unroll
                    for (int r = 0; r < 4; r++) {
                        const int tl = mi * 16 + lg * 4 + r;      // 0..127
                        const int m = m0 + p * 128 + tl;
                        const int b = m >> 11, t = m & 2047;
                        float v[4];
                        #pragma unroll
                        for (int nj = 0; nj < 4; nj++) v[nj] = acc[mi][nj][r] + bia[nj];

                        float ss = v[0]*v[0] + v[1]*v[1] + v[2]*v[2] + v[3]*v[3];
                        ss += __shfl_xor(ss, 1);
                        ss += __shfl_xor(ss, 2);
                        ss += __shfl_xor(ss, 4);
                        ss += __shfl_xor(ss, 8);
                        float rn = rsqrtf(ss * (1.0f / 64.0f) + 1e-6f);
                        #pragma unroll
                        for (int nj = 0; nj < 4; nj++) v[nj] = v[nj] * rn * sc[nj];

                        const float pos = (float)pos_arr[b * TT + t];
                        #pragma unroll
                        for (int pp = 0; pp < 2; pp++) {
                            float ang = pos * invts[pp];
                            float s = sinf(ang), c = cosf(ang);
                            float x1 = v[pp], x2 = v[pp + 2];
                            v[pp]     = x1 * c - x2 * s;
                            v[pp + 2] = x2 * c + x1 * s;
                        }
                        if (z == 0) {
                            #pragma unroll
                            for (int nj = 0; nj < 4; nj++) v[nj] *= QMUL;
                        }
                        #pragma unroll
                        for (int nj = 0; nj < 4; nj++) {
                            const int dl = wn * 64 + nj * 16 + l15;   // 0..255
                            sh[tl * 256 + (dl ^ ((tl & 7) << 3))] = f2bf(v[nj]);
                        }
                    }
                }
            }
            __syncthreads();
            // cooperative coalesced store of rows p*128..p*128+127
            #pragma unroll
            for (int it = 0; it < 8; it++) {
                int idx = it * 512 + tid;       // 0..4095
                int tl  = idx >> 5;             // 0..127
                int c8  = (idx & 31) << 3;      // 0..248 step 8
                short8 v8 = *(const short8*)&sh[tl * 256 + (c8 ^ ((tl & 7) << 3))];
                int cg = n0 + c8;
                int hh_ = cg >> 6, dih = cg & 63;
                int t = t0g + p * 128 + tl;
                *(short8*)&dst[((size_t)(bb_ * HH + hh_) * TT + t) * QKD + dih] = v8;
            }
        }
    } else {
        // ---- V epilogue: transposed stash [256 d][128 t] per pass ----
        #pragma unroll
        for (int p = 0; p < 2; p++) {
            __syncthreads();
            if (wm == p) {
                #pragma unroll
                for (int mi = 0; mi < 8; mi++) {
                    #pragma unroll
                    for (int r = 0; r < 4; r++) {
                        const int tl = mi * 16 + lg * 4 + r;      // 0..127
                        #pragma unroll
                        for (int nj = 0; nj < 4; nj++) {
                            const int dl = wn * 64 + nj * 16 + l15;   // 0..255
                            sh[dl * 128 + (tl ^ ((dl & 7) << 3))] = f2bf(acc[mi][nj][r] + bia[nj]);
                        }
                    }
                }
            }
            __syncthreads();
            #pragma unroll
            for (int it = 0; it < 8; it++) {
                int idx = it * 512 + tid;       // 0..4095
                int dl  = idx >> 4;             // 0..255
                int tc  = (idx & 15) << 3;      // 0..120 step 8
                short8 v8 = *(const short8*)&sh[dl * 128 + (tc ^ ((dl & 7) << 3))];
                int dg = n0 + dl;
                int hh_ = dg >> 6, dih = dg & 63;
                *(short8*)&dst[((size_t)(bb_ * HH + hh_) * QKD + dih) * TT + t0g + p * 128 + tc] = v8;
            }
        }
    }
}

// ---------------------------------------------------------------------------
// Output projection GEMM (256^2): attn_b[M,K] bf16 @ Wo_t[N,K]^T + bo -> fp32
// ---------------------------------------------------------------------------
__global__ __launch_bounds__(512) void out_gemm(
    const u16* __restrict__ A, const u16* __restrict__ Bt,
    const float* __restrict__ bo, float* __restrict__ out)
{
    __shared__ __align__(16) u16 sh[32768];

    int m_idx, n_idx;
    xcd_swizzle_4x32(m_idx, n_idx);
    const int m0 = m_idx * 256, n0 = n_idx * 256;

    float4v acc[8][4];
    #pragma unroll
    for (int i = 0; i < 8; i++)
        #pragma unroll
        for (int j = 0; j < 4; j++) acc[i][j] = (float4v){0.f, 0.f, 0.f, 0.f};

    gemm256_mainloop(A, Bt, m0, n0, sh, acc);

    const int lane = threadIdx.x & 63, wave = threadIdx.x >> 6;
    const int l15 = lane & 15, lg = lane >> 4;
    const int wm = wave >> 2, wn = wave & 3;

    float bov[4];
    #pragma unroll
    for (int nj = 0; nj < 4; nj++) bov[nj] = bo[n0 + wn * 64 + nj * 16 + l15];

    #pragma unroll
    for (int mi = 0; mi < 8; mi++)
        #pragma unroll
        for (int r = 0; r < 4; r++) {
            const int m = m0 + wm * 128 + mi * 16 + lg * 4 + r;
            float* op = out + (size_t)m * NN + n0 + wn * 64 + l15;
            #pragma unroll
            for (int nj = 0; nj < 4; nj++)
                op[nj * 16] = acc[mi][nj][r] + bov[nj];
        }
}

// ---------------------------------------------------------------------------
// MFMA flash attention, causal (unchanged this round):
//  - K rows and V^T rows staged via global_load_lds (16B) into XOR-swizzled
//    linear LDS; double-buffered K/V prefetch (T3 minimal 2-phase)
//  - defer-max rescale (T13, THR=8 in exp2 domain)
//  - packed v_cvt_pk_bf16_f32 for the P->bf16 LDS store
//  - per-lane partial rowsum; cross-lane l-reduce once in the epilogue
// ---------------------------------------------------------------------------
__global__ __launch_bounds__(256) void attn_mfma(
    const u16* __restrict__ qh, const u16* __restrict__ kh,
    const u16* __restrict__ vt, const float* __restrict__ head_scale,
    u16* __restrict__ out)
{
    __shared__ __align__(16) u16 Ks[2][64 * 64];   // K rows (swizzled)
    __shared__ __align__(16) u16 Vs[2][64 * 64];   // V^T rows = d (swizzled)
    __shared__ __align__(16) u16 Ps[4][16 * 64];   // per-wave P tile (swizzled)

    const int b = blockIdx.z, h = blockIdx.y, qt = blockIdx.x;
    const int t0 = qt * 64;
    const int tid  = threadIdx.x;
    const int wave = tid >> 6, lane = tid & 63;
    const int l15 = lane & 15, lg = lane >> 4;
    const int l7 = l15 & 7;

    const size_t bh = (size_t)(b * HH + h);
    const u16* qbh  = qh + bh * TT * QKD;
    const u16* kbh  = kh + bh * TT * QKD;
    const u16* vtbh = vt + bh * QKD * TT;   // [QKD][TT]

    short8 qfrag[2];
    #pragma unroll
    for (int kc = 0; kc < 2; kc++)
        qfrag[kc] = *(const short8*)(qbh + (size_t)(t0 + wave * 16 + l15) * QKD
                                      + kc * 32 + lg * 8);

    auto stage = [&](int buf, int j0s) {
        #pragma unroll
        for (int rr = 0; rr < 2; rr++) {
            const int c   = rr * 256 + tid;     // chunk 0..511 (16B each)
            const int row = c >> 3;             // 0..63
            const int g   = (c & 7) ^ (row & 7);// pre-swizzled global colblock
            u16* ldsK = &Ks[buf][(rr * 256 + (wave << 6)) * 8];
            u16* ldsV = &Vs[buf][(rr * 256 + (wave << 6)) * 8];
            gl2lds16(kbh  + (size_t)(j0s + row) * QKD + g * 8, ldsK);
            gl2lds16(vtbh + (size_t)row * TT + j0s + g * 8, ldsV);
        }
    };

    float4v o_acc[4];
    #pragma unroll
    for (int nt = 0; nt < 4; nt++) o_acc[nt] = (float4v){0.f, 0.f, 0.f, 0.f};
    float m_run[4] = {-INFINITY, -INFINITY, -INFINITY, -INFINITY};
    float l_run[4] = {0.f, 0.f, 0.f, 0.f};

    stage(0, 0);
    __syncthreads();

    const int qbase = t0 + wave * 16 + lg * 4;

    for (int j0 = 0; j0 <= t0; j0 += 64) {
        const int cur = (j0 >> 6) & 1;
        if (j0 + 64 <= t0) stage(cur ^ 1, j0 + 64);   // prefetch next tile

        // ---- QK^T (swizzled K reads) ----
        float4v sarr[4];
        #pragma unroll
        for (int nt = 0; nt < 4; nt++) {
            float4v s = (float4v){0.f, 0.f, 0.f, 0.f};
            #pragma unroll
            for (int kc = 0; kc < 2; kc++) {
                const short8 bfrag = *(const short8*)
                    &Ks[cur][(nt * 16 + l15) * 64 + ((kc * 4 + lg) ^ l7) * 8];
                s = __builtin_amdgcn_mfma_f32_16x16x32_bf16(qfrag[kc], bfrag, s, 0, 0, 0);
            }
            sarr[nt] = s;
        }

        // ---- causal mask (diagonal tile only) ----
        if (j0 == t0) {
            #pragma unroll
            for (int nt = 0; nt < 4; nt++) {
                int jkey = j0 + nt * 16 + l15;
                #pragma unroll
                for (int r = 0; r < 4; r++)
                    if (jkey > qbase + r) sarr[nt][r] = -INFINITY;
            }
        }

        // ---- row max + defer-max rescale (T13) ----
        float pm[4];
        #pragma unroll
        for (int r = 0; r < 4; r++) {
            float m = fmaxf(fmaxf(sarr[0][r], sarr[1][r]), fmaxf(sarr[2][r], sarr[3][r]));
            m = fmaxf(m, __shfl_xor(m, 1));
            m = fmaxf(m, __shfl_xor(m, 2));
            m = fmaxf(m, __shfl_xor(m, 4));
            m = fmaxf(m, __shfl_xor(m, 8));
            pm[r] = m;
        }
        float grow = fmaxf(fmaxf(pm[0] - m_run[0], pm[1] - m_run[1]),
                           fmaxf(pm[2] - m_run[2], pm[3] - m_run[3]));
        if (__any(grow > 8.0f)) {
            #pragma unroll
            for (int r = 0; r < 4; r++) {
                float mn = fmaxf(m_run[r], pm[r]);
                float a  = exp2f(m_run[r] - mn);
                m_run[r] = mn;
                l_run[r] *= a;
                #pragma unroll
                for (int nt = 0; nt < 4; nt++) o_acc[nt][r] *= a;
            }
        }

        // ---- P = exp2(S - m), partial rowsum, packed bf16 store to Ps ----
        u16* pw = Ps[wave];
        float lp[4] = {0.f, 0.f, 0.f, 0.f};
        #pragma unroll
        for (int nt = 0; nt < 4; nt++) {
            float p0 = exp2f(sarr[nt][0] - m_run[0]);
            float p1 = exp2f(sarr[nt][1] - m_run[1]);
            float p2 = exp2f(sarr[nt][2] - m_run[2]);
            float p3 = exp2f(sarr[nt][3] - m_run[3]);
            lp[0] += p0; lp[1] += p1; lp[2] += p2; lp[3] += p3;
            unsigned wlo = cvt_pk_bf16(p0, p1);
            unsigned whi = cvt_pk_bf16(p2, p3);
            const int gb = nt * 2 + (l15 >> 3);
            const int r0 = lg * 4;
            pw[(r0 + 0) * 64 + ((gb ^ ((r0 + 0) & 7))) * 8 + l7] = (u16)wlo;
            pw[(r0 + 1) * 64 + ((gb ^ ((r0 + 1) & 7))) * 8 + l7] = (u16)(wlo >> 16);
            pw[(r0 + 2) * 64 + ((gb ^ ((r0 + 2) & 7))) * 8 + l7] = (u16)whi;
            pw[(r0 + 3) * 64 + ((gb ^ ((r0 + 3) & 7))) * 8 + l7] = (u16)(whi >> 16);
        }
        #pragma unroll
        for (int r = 0; r < 4; r++) l_run[r] += lp[r];

        // ---- read P fragments back (same wave; lgkmcnt ordered) ----
        short8 pf[2];
        #pragma unroll
        for (int kc = 0; kc < 2; kc++)
            pf[kc] = *(const short8*)&pw[l15 * 64 + ((kc * 4 + lg) ^ l7) * 8];

        // ---- PV (swizzled V^T reads) ----
        #pragma unroll
        for (int nt = 0; nt < 4; nt++) {
            #pragma unroll
            for (int kc = 0; kc < 2; kc++) {
                const short8 vfrag = *(const short8*)
                    &Vs[cur][(nt * 16 + l15) * 64 + ((kc * 4 + lg) ^ l7) * 8];
                o_acc[nt] = __builtin_amdgcn_mfma_f32_16x16x32_bf16(pf[kc], vfrag, o_acc[nt], 0, 0, 0);
            }
        }
        __syncthreads();   // drains prefetch vmcnt + protects buffer reuse
    }

    const float hs = 1.0f + head_scale[h];
    #pragma unroll
    for (int r = 0; r < 4; r++) {
        float l = l_run[r];
        l += __shfl_xor(l, 1);
        l += __shfl_xor(l, 2);
        l += __shfl_xor(l, 4);
        l += __shfl_xor(l, 8);
        const int q = t0 + wave * 16 + lg * 4 + r;
        const float f = hs / l;
        u16* op = out + ((size_t)(b * TT + q) * NN) + h * QKD + l15;
        #pragma unroll
        for (int nt = 0; nt < 4; nt++)
            op[nt * 16] = f2bf(o_acc[nt][r] * f);
    }
}

// ---------------------------------------------------------------------------
extern "C" void kernel_launch(void* const* d_in, const int* in_sizes, int n_in,
                              void* d_out, int out_size, void* d_ws, size_t ws_size,
                              hipStream_t stream)
{
    const float* q          = (const float*)d_in[0];
    const float* kv         = (const float*)d_in[1];
    /* d_in[2] = causal mask -- handled analytically */
    const int*   qpos       = (const int*)d_in[3];
    const int*   kpos       = (const int*)d_in[4];
    const float* Wq         = (const float*)d_in[5];
    const float* bq         = (const float*)d_in[6];
    const float* Wk         = (const float*)d_in[7];
    const float* bk         = (const float*)d_in[8];
    const float* Wv         = (const float*)d_in[9];
    const float* bv         = (const float*)d_in[10];
    const float* q_scale    = (const float*)d_in[11];
    const float* k_scale    = (const float*)d_in[12];
    const float* head_scale = (const float*)d_in[13];
    const float* Wo         = (const float*)d_in[14];
    const float* bo         = (const float*)d_in[15];
    float* out = (float*)d_out;

    // workspace layout (bytes):
    //   [  0 MB, 16 MB)  qb    (M,K) bf16
    //   [ 16 MB, 32 MB)  kvb   (M,K) bf16
    //   [ 32 MB, 40 MB)  Wt    4 x (N,K) bf16 transposed: Wq,Wk,Wv,Wo
    //   [ 40 MB, 56 MB)  qh_b  (B,H,T,QK) bf16
    //   [ 56 MB, 72 MB)  kh_b  (B,H,T,QK) bf16
    //   [ 72 MB, 88 MB)  vt_b  (B,H,QK,T) bf16  <-- V stored transposed
    //   [ 88 MB,104 MB)  attn_b (B,T,N) bf16
    char* ws = (char*)d_ws;
    u16* qb     = (u16*)(ws);
    u16* kvb    = (u16*)(ws + (16u << 20));
    u16* Wt     = (u16*)(ws + (32u << 20));
    u16* qh_b   = (u16*)(ws + (40u << 20));
    u16* kh_b   = (u16*)(ws + (56u << 20));
    u16* vt_b   = (u16*)(ws + (72u << 20));
    u16* attn_b = (u16*)(ws + (88u << 20));

    // 1. cast activations to bf16
    acast_kernel<<<dim3(MM * DD / (256 * 4), 2), 256, 0, stream>>>(q, kv, qb, kvb);
    // 2. transpose+cast the four weight matrices
    wt_kernel<<<dim3(16, 16, 4), 256, 0, stream>>>(Wq, Wk, Wv, Wo, Wt);
    // 3. fused QKV projection (256^2 tile) -> Q,K:(B,H,T,QK), V:(B,H,QK,T)
    qkv_gemm<<<dim3(NN / 256, MM / 256, 3), 512, 0, stream>>>(
        qb, kvb, Wt, bq, bk, bv, qpos, kpos, q_scale, k_scale, qh_b, kh_b, vt_b);
    // 4. causal MFMA flash attention + head_scale -> (B,T,N) bf16
    attn_mfma<<<dim3(TT / 64, HH, BB), 256, 0, stream>>>(qh_b, kh_b, vt_b, head_scale, attn_b);
    // 5. output projection (256^2 tile) + bias -> fp32
    out_gemm<<<dim3(NN / 256, MM / 256), 512, 0, stream>>>(attn_b, Wt + (size_t)3 * KK * NN, bo, out);
}

// Round 7
// 487.795 us; speedup vs baseline: 1.4496x; 1.1161x over previous
//
#include <hip/hip_runtime.h>
#include <math.h>

// Problem constants
#define BB 4
#define TT 2048
#define DD 1024
#define HH 16
#define QKD 64
#define MM (BB*TT)          // 8192
#define NN 1024             // H*QK == D
#define KK 1024

// 256x256 GEMM tile geometry
#define BKQ 32              // K-step
#define NTS (KK/BKQ)        // 32 k-steps

typedef unsigned short u16;
typedef __attribute__((ext_vector_type(8))) short short8;   // 8 bf16 = 4 VGPRs
typedef __attribute__((ext_vector_type(4))) float float4v;  // MFMA C/D

// fp32 -> bf16 round-to-nearest-even
__device__ __forceinline__ u16 f2bf(float f) {
    union { float f; unsigned u; } v; v.f = f;
    unsigned r = (v.u + 0x7FFFu + ((v.u >> 16) & 1u)) >> 16;
    return (u16)r;
}

// packed fp32x2 -> bf16x2 (RTNE), single instruction on gfx950
__device__ __forceinline__ unsigned cvt_pk_bf16(float lo, float hi) {
    unsigned r;
    asm("v_cvt_pk_bf16_f32 %0, %1, %2" : "=v"(r) : "v"(lo), "v"(hi));
    return r;
}

// async global->LDS, 16B per lane; LDS dest = wave-uniform base + lane*16
typedef __attribute__((address_space(3))) unsigned lds_u32_t;
typedef __attribute__((address_space(1))) const unsigned glb_u32_t;
__device__ __forceinline__ void gl2lds16(const u16* g, u16* l) {
    __builtin_amdgcn_global_load_lds((glb_u32_t*)g, (lds_u32_t*)l, 16, 0, 0);
}

// ---------------------------------------------------------------------------
// fp32 -> bf16 cast for activations (q, kv)
// ---------------------------------------------------------------------------
__global__ __launch_bounds__(256) void acast_kernel(
    const float* __restrict__ a, const float* __restrict__ b,
    u16* __restrict__ da, u16* __restrict__ db)
{
    const float* s = blockIdx.y ? b : a;
    u16* d = blockIdx.y ? db : da;
    size_t i = ((size_t)blockIdx.x * 256 + threadIdx.x) * 4;
    float4 v = *(const float4*)&s[i];
    ushort4 o = { f2bf(v.x), f2bf(v.y), f2bf(v.z), f2bf(v.w) };
    *(ushort4*)&d[i] = o;
}

// ---------------------------------------------------------------------------
// Weight transpose + cast: W[K][N] fp32 -> Wt[N][K] bf16, z selects matrix
// ---------------------------------------------------------------------------
__global__ __launch_bounds__(256) void wt_kernel(
    const float* __restrict__ Wq, const float* __restrict__ Wk,
    const float* __restrict__ Wv, const float* __restrict__ Wo,
    u16* __restrict__ dstbase)
{
    const int z = blockIdx.z;
    const float* src = (z == 0) ? Wq : (z == 1) ? Wk : (z == 2) ? Wv : Wo;
    u16* out = dstbase + (size_t)z * (KK * NN);
    const int bi = blockIdx.y, bj = blockIdx.x;  // 64x64 tile: k-block, n-block
    __shared__ float tile[64][65];
    const int t = threadIdx.x;
    #pragma unroll
    for (int p = 0; p < 4; p++) {
        int idx = p * 256 + t;
        int r = idx >> 4, c4 = (idx & 15) << 2;
        float4 v = *(const float4*)&src[(size_t)(bi * 64 + r) * NN + bj * 64 + c4];
        tile[r][c4 + 0] = v.x; tile[r][c4 + 1] = v.y;
        tile[r][c4 + 2] = v.z; tile[r][c4 + 3] = v.w;
    }
    __syncthreads();
    #pragma unroll
    for (int p = 0; p < 4; p++) {
        int idx = p * 256 + t;
        int rn = idx >> 4, c4 = (idx & 15) << 2;
        ushort4 o = { f2bf(tile[c4 + 0][rn]), f2bf(tile[c4 + 1][rn]),
                      f2bf(tile[c4 + 2][rn]), f2bf(tile[c4 + 3][rn]) };
        *(ushort4*)&out[(size_t)(bj * 64 + rn) * KK + bi * 64 + c4] = o;
    }
}

// ---------------------------------------------------------------------------
// 256x256 bf16 MFMA GEMM mainloop.  8 waves (512 thr), wave grid 2(m)x4(n),
// per-wave output 128x64 = acc[8][4].  BK=32, double-buffered 64KB LDS,
// gl_lds staging with pre-swizzled global source (slot cb of row r holds
// global colblock cb^(r&3)), raw s_barrier + counted vmcnt(4) (never 0 in
// steady state), setprio(1) around the 32-MFMA cluster.
// A: [M,K] bf16 row-major.  Bt: [N,K] bf16 row-major (i.e. W^T).
// sh: 64KB u16[32768]: A bufs at [0], B bufs at [16384].
// ---------------------------------------------------------------------------
__device__ __forceinline__ void gemm256_mainloop(
    const u16* __restrict__ A, const u16* __restrict__ Bt,
    int m0, int n0, u16* __restrict__ sh, float4v (&acc)[8][4])
{
    const int tid = threadIdx.x;          // 0..511
    const int lane = tid & 63;
    const int l15 = lane & 15, lg = lane >> 4;
    const int wave = tid >> 6;
    const int wm = wave >> 2, wn = wave & 3;

    u16* sA = sh;                 // [2][256*32]
    u16* sB = sh + 16384;         // [2][256*32]

    const int c0 = tid, c1 = 512 + tid;
    const int r0s = c0 >> 2, g0 = (c0 & 3) ^ (r0s & 3);
    const int r1s = c1 >> 2, g1 = (c1 & 3) ^ (r1s & 3);

    const u16* gA0 = A  + (size_t)(m0 + r0s) * KK + g0 * 8;
    const u16* gA1 = A  + (size_t)(m0 + r1s) * KK + g1 * 8;
    const u16* gB0 = Bt + (size_t)(n0 + r0s) * KK + g0 * 8;
    const u16* gB1 = Bt + (size_t)(n0 + r1s) * KK + g1 * 8;

    auto issue = [&](int buf, int k0) {
        u16* dA = sA + buf * (256 * 32);
        u16* dB = sB + buf * (256 * 32);
        gl2lds16(gA0 + k0, dA + c0 * 8);
        gl2lds16(gA1 + k0, dA + c1 * 8);
        gl2lds16(gB0 + k0, dB + c0 * 8);
        gl2lds16(gB1 + k0, dB + c1 * 8);
    };

    issue(0, 0);
    issue(1, BKQ);
    asm volatile("s_waitcnt vmcnt(4)" ::: "memory");   // tile 0 landed
    __builtin_amdgcn_s_barrier();
    __builtin_amdgcn_sched_barrier(0);

    for (int t = 0; t < NTS; t++) {
        const int buf = t & 1;
        const u16* cA = sA + buf * (256 * 32);
        const u16* cB = sB + buf * (256 * 32);

        short8 af[8], bf[4];
        #pragma unroll
        for (int x = 0; x < 8; x++) {
            int ra = wm * 128 + x * 16 + l15;
            af[x] = *(const short8*)(cA + (ra * 4 + (lg ^ (ra & 3))) * 8);
        }
        #pragma unroll
        for (int x = 0; x < 4; x++) {
            int rb = wn * 64 + x * 16 + l15;
            bf[x] = *(const short8*)(cB + (rb * 4 + (lg ^ (rb & 3))) * 8);
        }
        __builtin_amdgcn_s_setprio(1);
        #pragma unroll
        for (int mi = 0; mi < 8; mi++)
            #pragma unroll
            for (int nj = 0; nj < 4; nj++)
                acc[mi][nj] = __builtin_amdgcn_mfma_f32_16x16x32_bf16(af[mi], bf[nj], acc[mi][nj], 0, 0, 0);
        __builtin_amdgcn_s_setprio(0);

        __builtin_amdgcn_s_barrier();          // all waves done reading buf
        if (t + 2 < NTS) {
            issue(buf, (t + 2) * BKQ);         // refill just-freed buffer
            asm volatile("s_waitcnt vmcnt(4)" ::: "memory");  // tile t+1 landed
        } else {
            asm volatile("s_waitcnt vmcnt(0)" ::: "memory");  // tail drain
        }
        __builtin_amdgcn_s_barrier();          // collective: t+1 visible to all
        __builtin_amdgcn_sched_barrier(0);
    }
}

// XCD band swizzle for a 4(n) x 32(m) grid: flat -> (m_idx, n_idx) so each
// XCD owns a contiguous band of 4 m-rows x all 4 n-tiles (A 2MB + B 2MB fits
// the 4MB per-XCD L2).  Bijective (128 = 8 x 16).
__device__ __forceinline__ void xcd_swizzle_4x32(int& m_idx, int& n_idx) {
    const int flat = blockIdx.y * 4 + blockIdx.x;   // 0..127
    const int xcd = flat & 7, q = flat >> 3;        // q: 0..15
    m_idx = xcd * 4 + (q & 3);                      // 0..31
    n_idx = q >> 2;                                 // 0..3
}

// ---------------------------------------------------------------------------
// QKV projection GEMM (256^2 tile), z in {0:Q, 1:K, 2:V}.
// Q,K: bias + RMSNorm + RoPE -> (B,H,T,QK) bf16 (Q also * 0.125*log2e).
// V:   bias -> transposed (B,H,QK,T) bf16.
// Epilogue stores route through the freed 64KB LDS in two 128-row passes so
// every global store instruction writes full 128B lines.
// ---------------------------------------------------------------------------
__global__ __launch_bounds__(512) void qkv_gemm(
    const u16* __restrict__ qb, const u16* __restrict__ kvb,
    const u16* __restrict__ Wt,
    const float* __restrict__ bq, const float* __restrict__ bk, const float* __restrict__ bv,
    const int* __restrict__ qpos, const int* __restrict__ kpos,
    const float* __restrict__ q_scale, const float* __restrict__ k_scale,
    u16* __restrict__ qh, u16* __restrict__ kh, u16* __restrict__ vt)
{
    __shared__ __align__(16) u16 sh[32768];   // 64 KB: staging, then epilogue stash

    const int z = blockIdx.z;
    const u16* A        = (z == 0) ? qb : kvb;
    const u16* B        = Wt + (size_t)z * (KK * NN);
    const float* bias   = (z == 0) ? bq : (z == 1) ? bk : bv;
    const float* scl    = (z == 0) ? q_scale : k_scale;
    const int* pos_arr  = (z == 0) ? qpos : kpos;
    u16* dst            = (z == 0) ? qh : (z == 1) ? kh : vt;

    int m_idx, n_idx;
    xcd_swizzle_4x32(m_idx, n_idx);
    const int m0 = m_idx * 256, n0 = n_idx * 256;

    float4v acc[8][4];
    #pragma unroll
    for (int i = 0; i < 8; i++)
        #pragma unroll
        for (int j = 0; j < 4; j++) acc[i][j] = (float4v){0.f, 0.f, 0.f, 0.f};

    gemm256_mainloop(A, B, m0, n0, sh, acc);

    const int tid = threadIdx.x;
    const int lane = tid & 63, wave = tid >> 6;
    const int l15 = lane & 15, lg = lane >> 4;
    const int wm = wave >> 2, wn = wave & 3;

    float bia[4], sc[4];
    #pragma unroll
    for (int nj = 0; nj < 4; nj++) {
        bia[nj] = bias[n0 + wn * 64 + nj * 16 + l15];
        sc[nj]  = 1.0f + scl[nj * 16 + l15];
    }
    float invts[2];
    #pragma unroll
    for (int p = 0; p < 2; p++)
        invts[p] = powf(10000.0f, -(float)(p * 16 + l15) * (1.0f / 32.0f));

    const float QMUL = 0.125f * 1.44269504088896340736f;
    const int bb_ = m0 >> 11;       // batch (tile never straddles a batch)
    const int t0g = m0 & 2047;      // global t base of this tile

    if (z < 2) {
        // ---- Q/K epilogue: two passes of 128 rows through the LDS stash ----
        #pragma unroll
        for (int p = 0; p < 2; p++) {
            __syncthreads();
            if (wm == p) {
                #pragma unroll
                for (int mi = 0; mi < 8; mi++) {
                    #pragma unroll
                    for (int r = 0; r < 4; r++) {
                        const int tl = mi * 16 + lg * 4 + r;      // 0..127
                        const int m = m0 + p * 128 + tl;
                        const int b = m >> 11, t = m & 2047;
                        float v[4];
                        #pragma unroll
                        for (int nj = 0; nj < 4; nj++) v[nj] = acc[mi][nj][r] + bia[nj];

                        float ss = v[0]*v[0] + v[1]*v[1] + v[2]*v[2] + v[3]*v[3];
                        ss += __shfl_xor(ss, 1);
                        ss += __shfl_xor(ss, 2);
                        ss += __shfl_xor(ss, 4);
                        ss += __shfl_xor(ss, 8);
                        float rn = rsqrtf(ss * (1.0f / 64.0f) + 1e-6f);
                        #pragma unroll
                        for (int nj = 0; nj < 4; nj++) v[nj] = v[nj] * rn * sc[nj];

                        const float pos = (float)pos_arr[b * TT + t];
                        #pragma unroll
                        for (int pp = 0; pp < 2; pp++) {
                            float ang = pos * invts[pp];
                            float s = sinf(ang), c = cosf(ang);
                            float x1 = v[pp], x2 = v[pp + 2];
                            v[pp]     = x1 * c - x2 * s;
                            v[pp + 2] = x2 * c + x1 * s;
                        }
                        if (z == 0) {
                            #pragma unroll
                            for (int nj = 0; nj < 4; nj++) v[nj] *= QMUL;
                        }
                        #pragma unroll
                        for (int nj = 0; nj < 4; nj++) {
                            const int dl = wn * 64 + nj * 16 + l15;   // 0..255
                            sh[tl * 256 + (dl ^ ((tl & 7) << 3))] = f2bf(v[nj]);
                        }
                    }
                }
            }
            __syncthreads();
            // cooperative coalesced store of rows p*128..p*128+127
            #pragma unroll
            for (int it = 0; it < 8; it++) {
                int idx = it * 512 + tid;       // 0..4095
                int tl  = idx >> 5;             // 0..127
                int c8  = (idx & 31) << 3;      // 0..248 step 8
                short8 v8 = *(const short8*)&sh[tl * 256 + (c8 ^ ((tl & 7) << 3))];
                int cg = n0 + c8;
                int hh_ = cg >> 6, dih = cg & 63;
                int t = t0g + p * 128 + tl;
                *(short8*)&dst[((size_t)(bb_ * HH + hh_) * TT + t) * QKD + dih] = v8;
            }
        }
    } else {
        // ---- V epilogue: transposed stash [256 d][128 t] per pass ----
        #pragma unroll
        for (int p = 0; p < 2; p++) {
            __syncthreads();
            if (wm == p) {
                #pragma unroll
                for (int mi = 0; mi < 8; mi++) {
                    #pragma unroll
                    for (int r = 0; r < 4; r++) {
                        const int tl = mi * 16 + lg * 4 + r;      // 0..127
                        #pragma unroll
                        for (int nj = 0; nj < 4; nj++) {
                            const int dl = wn * 64 + nj * 16 + l15;   // 0..255
                            sh[dl * 128 + (tl ^ ((dl & 7) << 3))] = f2bf(acc[mi][nj][r] + bia[nj]);
                        }
                    }
                }
            }
            __syncthreads();
            #pragma unroll
            for (int it = 0; it < 8; it++) {
                int idx = it * 512 + tid;       // 0..4095
                int dl  = idx >> 4;             // 0..255
                int tc  = (idx & 15) << 3;      // 0..120 step 8
                short8 v8 = *(const short8*)&sh[dl * 128 + (tc ^ ((dl & 7) << 3))];
                int dg = n0 + dl;
                int hh_ = dg >> 6, dih = dg & 63;
                *(short8*)&vt[((size_t)(bb_ * HH + hh_) * QKD + dih) * TT + t0g + p * 128 + tc] = v8;
            }
        }
    }
}

// ---------------------------------------------------------------------------
// Output projection GEMM (256^2): attn_b[M,K] bf16 @ Wo_t[N,K]^T + bo -> fp32
// ---------------------------------------------------------------------------
__global__ __launch_bounds__(512) void out_gemm(
    const u16* __restrict__ A, const u16* __restrict__ Bt,
    const float* __restrict__ bo, float* __restrict__ out)
{
    __shared__ __align__(16) u16 sh[32768];

    int m_idx, n_idx;
    xcd_swizzle_4x32(m_idx, n_idx);
    const int m0 = m_idx * 256, n0 = n_idx * 256;

    float4v acc[8][4];
    #pragma unroll
    for (int i = 0; i < 8; i++)
        #pragma unroll
        for (int j = 0; j < 4; j++) acc[i][j] = (float4v){0.f, 0.f, 0.f, 0.f};

    gemm256_mainloop(A, Bt, m0, n0, sh, acc);

    const int lane = threadIdx.x & 63, wave = threadIdx.x >> 6;
    const int l15 = lane & 15, lg = lane >> 4;
    const int wm = wave >> 2, wn = wave & 3;

    float bov[4];
    #pragma unroll
    for (int nj = 0; nj < 4; nj++) bov[nj] = bo[n0 + wn * 64 + nj * 16 + l15];

    #pragma unroll
    for (int mi = 0; mi < 8; mi++)
        #pragma unroll
        for (int r = 0; r < 4; r++) {
            const int m = m0 + wm * 128 + mi * 16 + lg * 4 + r;
            float* op = out + (size_t)m * NN + n0 + wn * 64 + l15;
            #pragma unroll
            for (int nj = 0; nj < 4; nj++)
                op[nj * 16] = acc[mi][nj][r] + bov[nj];
        }
}

// ---------------------------------------------------------------------------
// MFMA flash attention, causal.  PAIRED COMPLEMENTARY Q-TILES.
// Block p processes qt_a = p and qt_b = 31-p: per-block work = 33 row-tiles
// (uniform), grid = 16x16x4 = 1024 blocks = exactly 4/CU (one residency
// wave, no tail).  K/V tile jt is staged ONCE and consumed by both Q-tiles
// (qt_b always, qt_a while jt <= p) -- 2x MFMA per stage+barrier on the
// shared prefix.  Per-tile machinery: gl_lds XOR-swizzled staging,
// double-buffered prefetch, defer-max (T13), cvt_pk bf16 P-store, lazy
// l-reduction.
// ---------------------------------------------------------------------------
__global__ __launch_bounds__(256) void attn_mfma(
    const u16* __restrict__ qh, const u16* __restrict__ kh,
    const u16* __restrict__ vt, const float* __restrict__ head_scale,
    u16* __restrict__ out)
{
    __shared__ __align__(16) u16 Ks[2][64 * 64];   // K rows (swizzled)
    __shared__ __align__(16) u16 Vs[2][64 * 64];   // V^T rows = d (swizzled)
    __shared__ __align__(16) u16 Ps[4][16 * 64];   // per-wave P tile (swizzled)

    const int b = blockIdx.z, h = blockIdx.y;
    const int qta = blockIdx.x;          // 0..15  (small tile)
    const int qtb = 31 - qta;            // 16..31 (big tile)
    const int t0a = qta * 64, t0b = qtb * 64;

    const int tid  = threadIdx.x;
    const int wave = tid >> 6, lane = tid & 63;
    const int l15 = lane & 15, lg = lane >> 4;
    const int l7 = l15 & 7;

    const size_t bh = (size_t)(b * HH + h);
    const u16* qbh  = qh + bh * TT * QKD;
    const u16* kbh  = kh + bh * TT * QKD;
    const u16* vtbh = vt + bh * QKD * TT;   // [QKD][TT]

    short8 qfA[2], qfB[2];
    #pragma unroll
    for (int kc = 0; kc < 2; kc++) {
        qfA[kc] = *(const short8*)(qbh + (size_t)(t0a + wave * 16 + l15) * QKD
                                    + kc * 32 + lg * 8);
        qfB[kc] = *(const short8*)(qbh + (size_t)(t0b + wave * 16 + l15) * QKD
                                    + kc * 32 + lg * 8);
    }

    auto stage = [&](int buf, int j0s) {
        #pragma unroll
        for (int rr = 0; rr < 2; rr++) {
            const int c   = rr * 256 + tid;     // chunk 0..511 (16B each)
            const int row = c >> 3;             // 0..63
            const int g   = (c & 7) ^ (row & 7);// pre-swizzled global colblock
            u16* ldsK = &Ks[buf][(rr * 256 + (wave << 6)) * 8];
            u16* ldsV = &Vs[buf][(rr * 256 + (wave << 6)) * 8];
            gl2lds16(kbh  + (size_t)(j0s + row) * QKD + g * 8, ldsK);
            gl2lds16(vtbh + (size_t)row * TT + j0s + g * 8, ldsV);
        }
    };

    float4v oA[4], oB[4];
    #pragma unroll
    for (int nt = 0; nt < 4; nt++) {
        oA[nt] = (float4v){0.f, 0.f, 0.f, 0.f};
        oB[nt] = (float4v){0.f, 0.f, 0.f, 0.f};
    }
    float mA[4] = {-INFINITY, -INFINITY, -INFINITY, -INFINITY};
    float mB[4] = {-INFINITY, -INFINITY, -INFINITY, -INFINITY};
    float lA[4] = {0.f, 0.f, 0.f, 0.f};
    float lB[4] = {0.f, 0.f, 0.f, 0.f};

    // one flash step for one Q-tile against the staged tile `cur` at key
    // offset j0 = jt*64.  Intra-wave P round-trip through Ps[wave].
    auto flash_step = [&](int cur, int jt, int qt_self,
                          short8 (&qf)[2], float4v (&oa)[4],
                          float (&mr)[4], float (&lr)[4]) {
        // ---- QK^T (swizzled K reads) ----
        float4v sarr[4];
        #pragma unroll
        for (int nt = 0; nt < 4; nt++) {
            float4v s = (float4v){0.f, 0.f, 0.f, 0.f};
            #pragma unroll
            for (int kc = 0; kc < 2; kc++) {
                const short8 bfrag = *(const short8*)
                    &Ks[cur][(nt * 16 + l15) * 64 + ((kc * 4 + lg) ^ l7) * 8];
                s = __builtin_amdgcn_mfma_f32_16x16x32_bf16(qf[kc], bfrag, s, 0, 0, 0);
            }
            sarr[nt] = s;
        }

        // ---- causal mask (diagonal tile only) ----
        if (jt == qt_self) {
            const int qbase = qt_self * 64 + wave * 16 + lg * 4;
            #pragma unroll
            for (int nt = 0; nt < 4; nt++) {
                int jkey = jt * 64 + nt * 16 + l15;
                #pragma unroll
                for (int r = 0; r < 4; r++)
                    if (jkey > qbase + r) sarr[nt][r] = -INFINITY;
            }
        }

        // ---- row max + defer-max rescale (T13) ----
        float pm[4];
        #pragma unroll
        for (int r = 0; r < 4; r++) {
            float m = fmaxf(fmaxf(sarr[0][r], sarr[1][r]), fmaxf(sarr[2][r], sarr[3][r]));
            m = fmaxf(m, __shfl_xor(m, 1));
            m = fmaxf(m, __shfl_xor(m, 2));
            m = fmaxf(m, __shfl_xor(m, 4));
            m = fmaxf(m, __shfl_xor(m, 8));
            pm[r] = m;
        }
        float grow = fmaxf(fmaxf(pm[0] - mr[0], pm[1] - mr[1]),
                           fmaxf(pm[2] - mr[2], pm[3] - mr[3]));
        if (__any(grow > 8.0f)) {
            #pragma unroll
            for (int r = 0; r < 4; r++) {
                float mn = fmaxf(mr[r], pm[r]);
                float a  = exp2f(mr[r] - mn);
                mr[r] = mn;
                lr[r] *= a;
                #pragma unroll
                for (int nt = 0; nt < 4; nt++) oa[nt][r] *= a;
            }
        }

        // ---- P = exp2(S - m), partial rowsum, packed bf16 store to Ps ----
        u16* pw = Ps[wave];
        float lp[4] = {0.f, 0.f, 0.f, 0.f};
        #pragma unroll
        for (int nt = 0; nt < 4; nt++) {
            float p0 = exp2f(sarr[nt][0] - mr[0]);
            float p1 = exp2f(sarr[nt][1] - mr[1]);
            float p2 = exp2f(sarr[nt][2] - mr[2]);
            float p3 = exp2f(sarr[nt][3] - mr[3]);
            lp[0] += p0; lp[1] += p1; lp[2] += p2; lp[3] += p3;
            unsigned wlo = cvt_pk_bf16(p0, p1);
            unsigned whi = cvt_pk_bf16(p2, p3);
            const int gb = nt * 2 + (l15 >> 3);
            const int r0 = lg * 4;
            pw[(r0 + 0) * 64 + ((gb ^ ((r0 + 0) & 7))) * 8 + l7] = (u16)wlo;
            pw[(r0 + 1) * 64 + ((gb ^ ((r0 + 1) & 7))) * 8 + l7] = (u16)(wlo >> 16);
            pw[(r0 + 2) * 64 + ((gb ^ ((r0 + 2) & 7))) * 8 + l7] = (u16)whi;
            pw[(r0 + 3) * 64 + ((gb ^ ((r0 + 3) & 7))) * 8 + l7] = (u16)(whi >> 16);
        }
        #pragma unroll
        for (int r = 0; r < 4; r++) lr[r] += lp[r];

        // ---- read P fragments back (same wave; lgkmcnt ordered) ----
        short8 pf[2];
        #pragma unroll
        for (int kc = 0; kc < 2; kc++)
            pf[kc] = *(const short8*)&pw[l15 * 64 + ((kc * 4 + lg) ^ l7) * 8];

        // ---- PV (swizzled V^T reads) ----
        #pragma unroll
        for (int nt = 0; nt < 4; nt++) {
            #pragma unroll
            for (int kc = 0; kc < 2; kc++) {
                const short8 vfrag = *(const short8*)
                    &Vs[cur][(nt * 16 + l15) * 64 + ((kc * 4 + lg) ^ l7) * 8];
                oa[nt] = __builtin_amdgcn_mfma_f32_16x16x32_bf16(pf[kc], vfrag, oa[nt], 0, 0, 0);
            }
        }
    };

    stage(0, 0);
    __syncthreads();

    const int njt = qtb + 1;     // jt = 0..qtb
    for (int jt = 0; jt < njt; jt++) {
        const int cur = jt & 1;
        if (jt + 1 < njt) stage(cur ^ 1, (jt + 1) * 64);   // prefetch next tile

        flash_step(cur, jt, qtb, qfB, oB, mB, lB);          // big tile: always
        if (jt <= qta)
            flash_step(cur, jt, qta, qfA, oA, mA, lA);      // small tile: prefix

        __syncthreads();   // drains prefetch vmcnt + protects buffer reuse
    }

    // ---- epilogue: both Q-tiles ----
    const float hs = 1.0f + head_scale[h];
    auto epilogue = [&](int t0, float4v (&oa)[4], float (&lr)[4]) {
        #pragma unroll
        for (int r = 0; r < 4; r++) {
            float l = lr[r];
            l += __shfl_xor(l, 1);
            l += __shfl_xor(l, 2);
            l += __shfl_xor(l, 4);
            l += __shfl_xor(l, 8);
            const int q = t0 + wave * 16 + lg * 4 + r;
            const float f = hs / l;
            u16* op = out + ((size_t)(b * TT + q) * NN) + h * QKD + l15;
            #pragma unroll
            for (int nt = 0; nt < 4; nt++)
                op[nt * 16] = f2bf(oa[nt][r] * f);
        }
    };
    epilogue(t0b, oB, lB);
    epilogue(t0a, oA, lA);
}

// ---------------------------------------------------------------------------
extern "C" void kernel_launch(void* const* d_in, const int* in_sizes, int n_in,
                              void* d_out, int out_size, void* d_ws, size_t ws_size,
                              hipStream_t stream)
{
    const float* q          = (const float*)d_in[0];
    const float* kv         = (const float*)d_in[1];
    /* d_in[2] = causal mask -- handled analytically */
    const int*   qpos       = (const int*)d_in[3];
    const int*   kpos       = (const int*)d_in[4];
    const float* Wq         = (const float*)d_in[5];
    const float* bq         = (const float*)d_in[6];
    const float* Wk         = (const float*)d_in[7];
    const float* bk         = (const float*)d_in[8];
    const float* Wv         = (const float*)d_in[9];
    const float* bv         = (const float*)d_in[10];
    const float* q_scale    = (const float*)d_in[11];
    const float* k_scale    = (const float*)d_in[12];
    const float* head_scale = (const float*)d_in[13];
    const float* Wo         = (const float*)d_in[14];
    const float* bo         = (const float*)d_in[15];
    float* out = (float*)d_out;

    // workspace layout (bytes):
    //   [  0 MB, 16 MB)  qb    (M,K) bf16
    //   [ 16 MB, 32 MB)  kvb   (M,K) bf16
    //   [ 32 MB, 40 MB)  Wt    4 x (N,K) bf16 transposed: Wq,Wk,Wv,Wo
    //   [ 40 MB, 56 MB)  qh_b  (B,H,T,QK) bf16
    //   [ 56 MB, 72 MB)  kh_b  (B,H,T,QK) bf16
    //   [ 72 MB, 88 MB)  vt_b  (B,H,QK,T) bf16  <-- V stored transposed
    //   [ 88 MB,104 MB)  attn_b (B,T,N) bf16
    char* ws = (char*)d_ws;
    u16* qb     = (u16*)(ws);
    u16* kvb    = (u16*)(ws + (16u << 20));
    u16* Wt     = (u16*)(ws + (32u << 20));
    u16* qh_b   = (u16*)(ws + (40u << 20));
    u16* kh_b   = (u16*)(ws + (56u << 20));
    u16* vt_b   = (u16*)(ws + (72u << 20));
    u16* attn_b = (u16*)(ws + (88u << 20));

    // 1. cast activations to bf16
    acast_kernel<<<dim3(MM * DD / (256 * 4), 2), 256, 0, stream>>>(q, kv, qb, kvb);
    // 2. transpose+cast the four weight matrices
    wt_kernel<<<dim3(16, 16, 4), 256, 0, stream>>>(Wq, Wk, Wv, Wo, Wt);
    // 3. fused QKV projection (256^2 tile) -> Q,K:(B,H,T,QK), V:(B,H,QK,T)
    qkv_gemm<<<dim3(NN / 256, MM / 256, 3), 512, 0, stream>>>(
        qb, kvb, Wt, bq, bk, bv, qpos, kpos, q_scale, k_scale, qh_b, kh_b, vt_b);
    // 4. causal MFMA flash attention, paired complementary Q-tiles -> (B,T,N) bf16
    attn_mfma<<<dim3(TT / 128, HH, BB), 256, 0, stream>>>(qh_b, kh_b, vt_b, head_scale, attn_b);
    // 5. output projection (256^2 tile) + bias -> fp32
    out_gemm<<<dim3(NN / 256, MM / 256), 512, 0, stream>>>(attn_b, Wt + (size_t)3 * KK * NN, bo, out);
}

// Round 8
// 482.284 us; speedup vs baseline: 1.4662x; 1.0114x over previous
//
#include <hip/hip_runtime.h>
#include <math.h>

// Problem constants
#define BB 4
#define TT 2048
#define DD 1024
#define HH 16
#define QKD 64
#define MM (BB*TT)          // 8192
#define NN 1024             // H*QK == D
#define KK 1024

// 256x256 GEMM tile geometry
#define BKQ 32              // K-step
#define NTS (KK/BKQ)        // 32 k-steps

typedef unsigned short u16;
typedef __attribute__((ext_vector_type(8))) short short8;   // 8 bf16 = 4 VGPRs
typedef __attribute__((ext_vector_type(4))) float float4v;  // MFMA C/D

// fp32 -> bf16 round-to-nearest-even
__device__ __forceinline__ u16 f2bf(float f) {
    union { float f; unsigned u; } v; v.f = f;
    unsigned r = (v.u + 0x7FFFu + ((v.u >> 16) & 1u)) >> 16;
    return (u16)r;
}

// packed fp32x2 -> bf16x2 (RTNE), single instruction on gfx950
__device__ __forceinline__ unsigned cvt_pk_bf16(float lo, float hi) {
    unsigned r;
    asm("v_cvt_pk_bf16_f32 %0, %1, %2" : "=v"(r) : "v"(lo), "v"(hi));
    return r;
}

// async global->LDS, 16B per lane; LDS dest = wave-uniform base + lane*16
typedef __attribute__((address_space(3))) unsigned lds_u32_t;
typedef __attribute__((address_space(1))) const unsigned glb_u32_t;
__device__ __forceinline__ void gl2lds16(const u16* g, u16* l) {
    __builtin_amdgcn_global_load_lds((glb_u32_t*)g, (lds_u32_t*)l, 16, 0, 0);
}

// ---------------------------------------------------------------------------
// fp32 -> bf16 cast for activations (q, kv)
// ---------------------------------------------------------------------------
__global__ __launch_bounds__(256) void acast_kernel(
    const float* __restrict__ a, const float* __restrict__ b,
    u16* __restrict__ da, u16* __restrict__ db)
{
    const float* s = blockIdx.y ? b : a;
    u16* d = blockIdx.y ? db : da;
    size_t i = ((size_t)blockIdx.x * 256 + threadIdx.x) * 4;
    float4 v = *(const float4*)&s[i];
    ushort4 o = { f2bf(v.x), f2bf(v.y), f2bf(v.z), f2bf(v.w) };
    *(ushort4*)&d[i] = o;
}

// ---------------------------------------------------------------------------
// Weight transpose + cast: W[K][N] fp32 -> Wt[N][K] bf16, z selects matrix
// ---------------------------------------------------------------------------
__global__ __launch_bounds__(256) void wt_kernel(
    const float* __restrict__ Wq, const float* __restrict__ Wk,
    const float* __restrict__ Wv, const float* __restrict__ Wo,
    u16* __restrict__ dstbase)
{
    const int z = blockIdx.z;
    const float* src = (z == 0) ? Wq : (z == 1) ? Wk : (z == 2) ? Wv : Wo;
    u16* out = dstbase + (size_t)z * (KK * NN);
    const int bi = blockIdx.y, bj = blockIdx.x;  // 64x64 tile: k-block, n-block
    __shared__ float tile[64][65];
    const int t = threadIdx.x;
    #pragma unroll
    for (int p = 0; p < 4; p++) {
        int idx = p * 256 + t;
        int r = idx >> 4, c4 = (idx & 15) << 2;
        float4 v = *(const float4*)&src[(size_t)(bi * 64 + r) * NN + bj * 64 + c4];
        tile[r][c4 + 0] = v.x; tile[r][c4 + 1] = v.y;
        tile[r][c4 + 2] = v.z; tile[r][c4 + 3] = v.w;
    }
    __syncthreads();
    #pragma unroll
    for (int p = 0; p < 4; p++) {
        int idx = p * 256 + t;
        int rn = idx >> 4, c4 = (idx & 15) << 2;
        ushort4 o = { f2bf(tile[c4 + 0][rn]), f2bf(tile[c4 + 1][rn]),
                      f2bf(tile[c4 + 2][rn]), f2bf(tile[c4 + 3][rn]) };
        *(ushort4*)&out[(size_t)(bj * 64 + rn) * KK + bi * 64 + c4] = o;
    }
}

// ---------------------------------------------------------------------------
// 256x256 bf16 MFMA GEMM mainloop, v2: TRIPLE-buffered 96KB LDS, 2-step
// prefetch depth.  8 waves (512 thr), wave grid 2(m)x4(n), per-wave output
// 128x64 = acc[8][4].  BK=32.  gl_lds staging with pre-swizzled global
// source; CONFLICT-FREE slot swizzle: slot cb of row r holds global colblock
// cb ^ ((r>>1)&3)  (granule = (4r + slot) mod 8 takes 8 distinct values over
// 8 consecutive rows -> 2 lanes/granule = free).  Counted vmcnt(8) in steady
// state (2 newer tiles in flight), issue(t+3) AFTER the post-read barrier so
// tile t gets ~2 full steps of HBM-latency cover.  setprio(1) around MFMA.
// A: [M,K] bf16 row-major.  Bt: [N,K] bf16 row-major (i.e. W^T).
// sh: 96KB u16[49152]: buf b at sh + b*16384 (A 8192 u16, then B 8192 u16).
// ---------------------------------------------------------------------------
__device__ __forceinline__ void gemm256_mainloop(
    const u16* __restrict__ A, const u16* __restrict__ Bt,
    int m0, int n0, u16* __restrict__ sh, float4v (&acc)[8][4])
{
    const int tid = threadIdx.x;          // 0..511
    const int lane = tid & 63;
    const int l15 = lane & 15, lg = lane >> 4;
    const int wave = tid >> 6;
    const int wm = wave >> 2, wn = wave & 3;

    // staging chunks: c0 = tid, c1 = 512+tid; chunk c -> row r=c>>2, cb=c&3,
    // global colblock g = cb ^ ((r>>1)&3)
    const int c0 = tid, c1 = 512 + tid;
    const int r0s = c0 >> 2, g0 = (c0 & 3) ^ ((r0s >> 1) & 3);
    const int r1s = c1 >> 2, g1 = (c1 & 3) ^ ((r1s >> 1) & 3);

    const u16* gA0 = A  + (size_t)(m0 + r0s) * KK + g0 * 8;
    const u16* gA1 = A  + (size_t)(m0 + r1s) * KK + g1 * 8;
    const u16* gB0 = Bt + (size_t)(n0 + r0s) * KK + g0 * 8;
    const u16* gB1 = Bt + (size_t)(n0 + r1s) * KK + g1 * 8;

    auto issue = [&](int buf, int k0) {
        u16* dA = sh + buf * 16384;
        u16* dB = dA + 8192;
        gl2lds16(gA0 + k0, dA + c0 * 8);
        gl2lds16(gA1 + k0, dA + c1 * 8);
        gl2lds16(gB0 + k0, dB + c0 * 8);
        gl2lds16(gB1 + k0, dB + c1 * 8);
    };

    issue(0, 0);
    issue(1, BKQ);
    issue(2, 2 * BKQ);

    int buf = 0;
    for (int t = 0; t < NTS; t++) {
        // tile t landed?  steady state: 2 newer tiles (8 loads) may be in
        // flight; tail peeled so the count is exact.
        if (t < NTS - 2)       asm volatile("s_waitcnt vmcnt(8)" ::: "memory");
        else if (t == NTS - 2) asm volatile("s_waitcnt vmcnt(4)" ::: "memory");
        else                   asm volatile("s_waitcnt vmcnt(0)" ::: "memory");
        __builtin_amdgcn_s_barrier();          // tile t visible to ALL waves
        __builtin_amdgcn_sched_barrier(0);

        const u16* cA = sh + buf * 16384;
        const u16* cB = cA + 8192;

        short8 bf[4];
        #pragma unroll
        for (int x = 0; x < 4; x++) {
            int rb = wn * 64 + x * 16 + l15;
            bf[x] = *(const short8*)(cB + (rb * 4 + (lg ^ ((rb >> 1) & 3))) * 8);
        }
        // phase 0: af-lo (rows 0..63 of the wave's 128) + 16 MFMA
        short8 afl[4];
        #pragma unroll
        for (int x = 0; x < 4; x++) {
            int ra = wm * 128 + x * 16 + l15;
            afl[x] = *(const short8*)(cA + (ra * 4 + (lg ^ ((ra >> 1) & 3))) * 8);
        }
        __builtin_amdgcn_s_setprio(1);
        #pragma unroll
        for (int mi = 0; mi < 4; mi++)
            #pragma unroll
            for (int nj = 0; nj < 4; nj++)
                acc[mi][nj] = __builtin_amdgcn_mfma_f32_16x16x32_bf16(afl[mi], bf[nj], acc[mi][nj], 0, 0, 0);
        __builtin_amdgcn_s_setprio(0);
        // phase 1: af-hi (rows 64..127) + 16 MFMA
        short8 afh[4];
        #pragma unroll
        for (int x = 0; x < 4; x++) {
            int ra = wm * 128 + (4 + x) * 16 + l15;
            afh[x] = *(const short8*)(cA + (ra * 4 + (lg ^ ((ra >> 1) & 3))) * 8);
        }
        __builtin_amdgcn_s_setprio(1);
        #pragma unroll
        for (int mi = 0; mi < 4; mi++)
            #pragma unroll
            for (int nj = 0; nj < 4; nj++)
                acc[4 + mi][nj] = __builtin_amdgcn_mfma_f32_16x16x32_bf16(afh[mi], bf[nj], acc[4 + mi][nj], 0, 0, 0);
        __builtin_amdgcn_s_setprio(0);

        __builtin_amdgcn_s_barrier();          // all waves done reading buf
        if (t + 3 < NTS) issue(buf, (t + 3) * BKQ);   // refill just-freed buffer
        buf = (buf == 2) ? 0 : buf + 1;
        __builtin_amdgcn_sched_barrier(0);
    }
}

// XCD band swizzle for a 4(n) x 32(m) grid: flat -> (m_idx, n_idx) so each
// XCD owns a contiguous band of 4 m-rows x all 4 n-tiles (A 2MB + B 2MB fits
// the 4MB per-XCD L2).  Bijective (128 = 8 x 16).
__device__ __forceinline__ void xcd_swizzle_4x32(int& m_idx, int& n_idx) {
    const int flat = blockIdx.y * 4 + blockIdx.x;   // 0..127
    const int xcd = flat & 7, q = flat >> 3;        // q: 0..15
    m_idx = xcd * 4 + (q & 3);                      // 0..31
    n_idx = q >> 2;                                 // 0..3
}

// ---------------------------------------------------------------------------
// QKV projection GEMM (256^2 tile), z in {0:Q, 1:K, 2:V}.
// Q,K: bias + RMSNorm + RoPE -> (B,H,T,QK) bf16 (Q also * 0.125*log2e).
// V:   bias -> transposed (B,H,QK,T) bf16.
// Epilogue stores route through the (now free) LDS in two 128-row passes so
// every global store instruction writes full 128B lines.
// ---------------------------------------------------------------------------
__global__ __launch_bounds__(512, 2) void qkv_gemm(
    const u16* __restrict__ qb, const u16* __restrict__ kvb,
    const u16* __restrict__ Wt,
    const float* __restrict__ bq, const float* __restrict__ bk, const float* __restrict__ bv,
    const int* __restrict__ qpos, const int* __restrict__ kpos,
    const float* __restrict__ q_scale, const float* __restrict__ k_scale,
    u16* __restrict__ qh, u16* __restrict__ kh, u16* __restrict__ vt)
{
    __shared__ __align__(16) u16 sh[49152];   // 96 KB: 3-buf staging, then epilogue stash

    const int z = blockIdx.z;
    const u16* A        = (z == 0) ? qb : kvb;
    const u16* B        = Wt + (size_t)z * (KK * NN);
    const float* bias   = (z == 0) ? bq : (z == 1) ? bk : bv;
    const float* scl    = (z == 0) ? q_scale : k_scale;
    const int* pos_arr  = (z == 0) ? qpos : kpos;
    u16* dst            = (z == 0) ? qh : (z == 1) ? kh : vt;

    int m_idx, n_idx;
    xcd_swizzle_4x32(m_idx, n_idx);
    const int m0 = m_idx * 256, n0 = n_idx * 256;

    float4v acc[8][4];
    #pragma unroll
    for (int i = 0; i < 8; i++)
        #pragma unroll
        for (int j = 0; j < 4; j++) acc[i][j] = (float4v){0.f, 0.f, 0.f, 0.f};

    gemm256_mainloop(A, B, m0, n0, sh, acc);

    const int tid = threadIdx.x;
    const int lane = tid & 63, wave = tid >> 6;
    const int l15 = lane & 15, lg = lane >> 4;
    const int wm = wave >> 2, wn = wave & 3;

    float bia[4], sc[4];
    #pragma unroll
    for (int nj = 0; nj < 4; nj++) {
        bia[nj] = bias[n0 + wn * 64 + nj * 16 + l15];
        sc[nj]  = 1.0f + scl[nj * 16 + l15];
    }
    float invts[2];
    #pragma unroll
    for (int p = 0; p < 2; p++)
        invts[p] = powf(10000.0f, -(float)(p * 16 + l15) * (1.0f / 32.0f));

    const float QMUL = 0.125f * 1.44269504088896340736f;
    const int bb_ = m0 >> 11;       // batch (tile never straddles a batch)
    const int t0g = m0 & 2047;      // global t base of this tile

    if (z < 2) {
        // ---- Q/K epilogue: two passes of 128 rows through the LDS stash ----
        #pragma unroll
        for (int p = 0; p < 2; p++) {
            __syncthreads();
            if (wm == p) {
                #pragma unroll
                for (int mi = 0; mi < 8; mi++) {
                    #pragma unroll
                    for (int r = 0; r < 4; r++) {
                        const int tl = mi * 16 + lg * 4 + r;      // 0..127
                        const int m = m0 + p * 128 + tl;
                        const int b = m >> 11, t = m & 2047;
                        float v[4];
                        #pragma unroll
                        for (int nj = 0; nj < 4; nj++) v[nj] = acc[mi][nj][r] + bia[nj];

                        float ss = v[0]*v[0] + v[1]*v[1] + v[2]*v[2] + v[3]*v[3];
                        ss += __shfl_xor(ss, 1);
                        ss += __shfl_xor(ss, 2);
                        ss += __shfl_xor(ss, 4);
                        ss += __shfl_xor(ss, 8);
                        float rn = rsqrtf(ss * (1.0f / 64.0f) + 1e-6f);
                        #pragma unroll
                        for (int nj = 0; nj < 4; nj++) v[nj] = v[nj] * rn * sc[nj];

                        const float pos = (float)pos_arr[b * TT + t];
                        #pragma unroll
                        for (int pp = 0; pp < 2; pp++) {
                            float ang = pos * invts[pp];
                            float s = sinf(ang), c = cosf(ang);
                            float x1 = v[pp], x2 = v[pp + 2];
                            v[pp]     = x1 * c - x2 * s;
                            v[pp + 2] = x2 * c + x1 * s;
                        }
                        if (z == 0) {
                            #pragma unroll
                            for (int nj = 0; nj < 4; nj++) v[nj] *= QMUL;
                        }
                        #pragma unroll
                        for (int nj = 0; nj < 4; nj++) {
                            const int dl = wn * 64 + nj * 16 + l15;   // 0..255
                            sh[tl * 256 + (dl ^ ((tl & 7) << 3))] = f2bf(v[nj]);
                        }
                    }
                }
            }
            __syncthreads();
            // cooperative coalesced store of rows p*128..p*128+127
            #pragma unroll
            for (int it = 0; it < 8; it++) {
                int idx = it * 512 + tid;       // 0..4095
                int tl  = idx >> 5;             // 0..127
                int c8  = (idx & 31) << 3;      // 0..248 step 8
                short8 v8 = *(const short8*)&sh[tl * 256 + (c8 ^ ((tl & 7) << 3))];
                int cg = n0 + c8;
                int hh_ = cg >> 6, dih = cg & 63;
                int t = t0g + p * 128 + tl;
                *(short8*)&dst[((size_t)(bb_ * HH + hh_) * TT + t) * QKD + dih] = v8;
            }
        }
    } else {
        // ---- V epilogue: transposed stash [256 d][128 t] per pass ----
        #pragma unroll
        for (int p = 0; p < 2; p++) {
            __syncthreads();
            if (wm == p) {
                #pragma unroll
                for (int mi = 0; mi < 8; mi++) {
                    #pragma unroll
                    for (int r = 0; r < 4; r++) {
                        const int tl = mi * 16 + lg * 4 + r;      // 0..127
                        #pragma unroll
                        for (int nj = 0; nj < 4; nj++) {
                            const int dl = wn * 64 + nj * 16 + l15;   // 0..255
                            sh[dl * 128 + (tl ^ ((dl & 7) << 3))] = f2bf(acc[mi][nj][r] + bia[nj]);
                        }
                    }
                }
            }
            __syncthreads();
            #pragma unroll
            for (int it = 0; it < 8; it++) {
                int idx = it * 512 + tid;       // 0..4095
                int dl  = idx >> 4;             // 0..255
                int tc  = (idx & 15) << 3;      // 0..120 step 8
                short8 v8 = *(const short8*)&sh[dl * 128 + (tc ^ ((dl & 7) << 3))];
                int dg = n0 + dl;
                int hh_ = dg >> 6, dih = dg & 63;
                *(short8*)&vt[((size_t)(bb_ * HH + hh_) * QKD + dih) * TT + t0g + p * 128 + tc] = v8;
            }
        }
    }
}

// ---------------------------------------------------------------------------
// Output projection GEMM (256^2): attn_b[M,K] bf16 @ Wo_t[N,K]^T + bo -> fp32
// ---------------------------------------------------------------------------
__global__ __launch_bounds__(512, 2) void out_gemm(
    const u16* __restrict__ A, const u16* __restrict__ Bt,
    const float* __restrict__ bo, float* __restrict__ out)
{
    __shared__ __align__(16) u16 sh[49152];

    int m_idx, n_idx;
    xcd_swizzle_4x32(m_idx, n_idx);
    const int m0 = m_idx * 256, n0 = n_idx * 256;

    float4v acc[8][4];
    #pragma unroll
    for (int i = 0; i < 8; i++)
        #pragma unroll
        for (int j = 0; j < 4; j++) acc[i][j] = (float4v){0.f, 0.f, 0.f, 0.f};

    gemm256_mainloop(A, Bt, m0, n0, sh, acc);

    const int lane = threadIdx.x & 63, wave = threadIdx.x >> 6;
    const int l15 = lane & 15, lg = lane >> 4;
    const int wm = wave >> 2, wn = wave & 3;

    float bov[4];
    #pragma unroll
    for (int nj = 0; nj < 4; nj++) bov[nj] = bo[n0 + wn * 64 + nj * 16 + l15];

    #pragma unroll
    for (int mi = 0; mi < 8; mi++)
        #pragma unroll
        for (int r = 0; r < 4; r++) {
            const int m = m0 + wm * 128 + mi * 16 + lg * 4 + r;
            float* op = out + (size_t)m * NN + n0 + wn * 64 + l15;
            #pragma unroll
            for (int nj = 0; nj < 4; nj++)
                op[nj * 16] = acc[mi][nj][r] + bov[nj];
        }
}

// ---------------------------------------------------------------------------
// MFMA flash attention, causal.  PAIRED COMPLEMENTARY Q-TILES (unchanged).
// Block p processes qt_a = p and qt_b = 31-p: per-block work = 33 row-tiles
// (uniform), grid = 16x16x4 = 1024 blocks = exactly 4/CU.  K/V tile jt is
// staged ONCE and consumed by both Q-tiles (qt_b always, qt_a while jt <= p).
// ---------------------------------------------------------------------------
__global__ __launch_bounds__(256) void attn_mfma(
    const u16* __restrict__ qh, const u16* __restrict__ kh,
    const u16* __restrict__ vt, const float* __restrict__ head_scale,
    u16* __restrict__ out)
{
    __shared__ __align__(16) u16 Ks[2][64 * 64];   // K rows (swizzled)
    __shared__ __align__(16) u16 Vs[2][64 * 64];   // V^T rows = d (swizzled)
    __shared__ __align__(16) u16 Ps[4][16 * 64];   // per-wave P tile (swizzled)

    const int b = blockIdx.z, h = blockIdx.y;
    const int qta = blockIdx.x;          // 0..15  (small tile)
    const int qtb = 31 - qta;            // 16..31 (big tile)
    const int t0a = qta * 64, t0b = qtb * 64;

    const int tid  = threadIdx.x;
    const int wave = tid >> 6, lane = tid & 63;
    const int l15 = lane & 15, lg = lane >> 4;
    const int l7 = l15 & 7;

    const size_t bh = (size_t)(b * HH + h);
    const u16* qbh  = qh + bh * TT * QKD;
    const u16* kbh  = kh + bh * TT * QKD;
    const u16* vtbh = vt + bh * QKD * TT;   // [QKD][TT]

    short8 qfA[2], qfB[2];
    #pragma unroll
    for (int kc = 0; kc < 2; kc++) {
        qfA[kc] = *(const short8*)(qbh + (size_t)(t0a + wave * 16 + l15) * QKD
                                    + kc * 32 + lg * 8);
        qfB[kc] = *(const short8*)(qbh + (size_t)(t0b + wave * 16 + l15) * QKD
                                    + kc * 32 + lg * 8);
    }

    auto stage = [&](int buf, int j0s) {
        #pragma unroll
        for (int rr = 0; rr < 2; rr++) {
            const int c   = rr * 256 + tid;     // chunk 0..511 (16B each)
            const int row = c >> 3;             // 0..63
            const int g   = (c & 7) ^ (row & 7);// pre-swizzled global colblock
            u16* ldsK = &Ks[buf][(rr * 256 + (wave << 6)) * 8];
            u16* ldsV = &Vs[buf][(rr * 256 + (wave << 6)) * 8];
            gl2lds16(kbh  + (size_t)(j0s + row) * QKD + g * 8, ldsK);
            gl2lds16(vtbh + (size_t)row * TT + j0s + g * 8, ldsV);
        }
    };

    float4v oA[4], oB[4];
    #pragma unroll
    for (int nt = 0; nt < 4; nt++) {
        oA[nt] = (float4v){0.f, 0.f, 0.f, 0.f};
        oB[nt] = (float4v){0.f, 0.f, 0.f, 0.f};
    }
    float mA[4] = {-INFINITY, -INFINITY, -INFINITY, -INFINITY};
    float mB[4] = {-INFINITY, -INFINITY, -INFINITY, -INFINITY};
    float lA[4] = {0.f, 0.f, 0.f, 0.f};
    float lB[4] = {0.f, 0.f, 0.f, 0.f};

    auto flash_step = [&](int cur, int jt, int qt_self,
                          short8 (&qf)[2], float4v (&oa)[4],
                          float (&mr)[4], float (&lr)[4]) {
        // ---- QK^T (swizzled K reads) ----
        float4v sarr[4];
        #pragma unroll
        for (int nt = 0; nt < 4; nt++) {
            float4v s = (float4v){0.f, 0.f, 0.f, 0.f};
            #pragma unroll
            for (int kc = 0; kc < 2; kc++) {
                const short8 bfrag = *(const short8*)
                    &Ks[cur][(nt * 16 + l15) * 64 + ((kc * 4 + lg) ^ l7) * 8];
                s = __builtin_amdgcn_mfma_f32_16x16x32_bf16(qf[kc], bfrag, s, 0, 0, 0);
            }
            sarr[nt] = s;
        }

        // ---- causal mask (diagonal tile only) ----
        if (jt == qt_self) {
            const int qbase = qt_self * 64 + wave * 16 + lg * 4;
            #pragma unroll
            for (int nt = 0; nt < 4; nt++) {
                int jkey = jt * 64 + nt * 16 + l15;
                #pragma unroll
                for (int r = 0; r < 4; r++)
                    if (jkey > qbase + r) sarr[nt][r] = -INFINITY;
            }
        }

        // ---- row max + defer-max rescale (T13) ----
        float pm[4];
        #pragma unroll
        for (int r = 0; r < 4; r++) {
            float m = fmaxf(fmaxf(sarr[0][r], sarr[1][r]), fmaxf(sarr[2][r], sarr[3][r]));
            m = fmaxf(m, __shfl_xor(m, 1));
            m = fmaxf(m, __shfl_xor(m, 2));
            m = fmaxf(m, __shfl_xor(m, 4));
            m = fmaxf(m, __shfl_xor(m, 8));
            pm[r] = m;
        }
        float grow = fmaxf(fmaxf(pm[0] - mr[0], pm[1] - mr[1]),
                           fmaxf(pm[2] - mr[2], pm[3] - mr[3]));
        if (__any(grow > 8.0f)) {
            #pragma unroll
            for (int r = 0; r < 4; r++) {
                float mn = fmaxf(mr[r], pm[r]);
                float a  = exp2f(mr[r] - mn);
                mr[r] = mn;
                lr[r] *= a;
                #pragma unroll
                for (int nt = 0; nt < 4; nt++) oa[nt][r] *= a;
            }
        }

        // ---- P = exp2(S - m), partial rowsum, packed bf16 store to Ps ----
        u16* pw = Ps[wave];
        float lp[4] = {0.f, 0.f, 0.f, 0.f};
        #pragma unroll
        for (int nt = 0; nt < 4; nt++) {
            float p0 = exp2f(sarr[nt][0] - mr[0]);
            float p1 = exp2f(sarr[nt][1] - mr[1]);
            float p2 = exp2f(sarr[nt][2] - mr[2]);
            float p3 = exp2f(sarr[nt][3] - mr[3]);
            lp[0] += p0; lp[1] += p1; lp[2] += p2; lp[3] += p3;
            unsigned wlo = cvt_pk_bf16(p0, p1);
            unsigned whi = cvt_pk_bf16(p2, p3);
            const int gb = nt * 2 + (l15 >> 3);
            const int r0 = lg * 4;
            pw[(r0 + 0) * 64 + ((gb ^ ((r0 + 0) & 7))) * 8 + l7] = (u16)wlo;
            pw[(r0 + 1) * 64 + ((gb ^ ((r0 + 1) & 7))) * 8 + l7] = (u16)(wlo >> 16);
            pw[(r0 + 2) * 64 + ((gb ^ ((r0 + 2) & 7))) * 8 + l7] = (u16)whi;
            pw[(r0 + 3) * 64 + ((gb ^ ((r0 + 3) & 7))) * 8 + l7] = (u16)(whi >> 16);
        }
        #pragma unroll
        for (int r = 0; r < 4; r++) lr[r] += lp[r];

        // ---- read P fragments back (same wave; lgkmcnt ordered) ----
        short8 pf[2];
        #pragma unroll
        for (int kc = 0; kc < 2; kc++)
            pf[kc] = *(const short8*)&pw[l15 * 64 + ((kc * 4 + lg) ^ l7) * 8];

        // ---- PV (swizzled V^T reads) ----
        #pragma unroll
        for (int nt = 0; nt < 4; nt++) {
            #pragma unroll
            for (int kc = 0; kc < 2; kc++) {
                const short8 vfrag = *(const short8*)
                    &Vs[cur][(nt * 16 + l15) * 64 + ((kc * 4 + lg) ^ l7) * 8];
                oa[nt] = __builtin_amdgcn_mfma_f32_16x16x32_bf16(pf[kc], vfrag, oa[nt], 0, 0, 0);
            }
        }
    };

    stage(0, 0);
    __syncthreads();

    const int njt = qtb + 1;     // jt = 0..qtb
    for (int jt = 0; jt < njt; jt++) {
        const int cur = jt & 1;
        if (jt + 1 < njt) stage(cur ^ 1, (jt + 1) * 64);   // prefetch next tile

        flash_step(cur, jt, qtb, qfB, oB, mB, lB);          // big tile: always
        if (jt <= qta)
            flash_step(cur, jt, qta, qfA, oA, mA, lA);      // small tile: prefix

        __syncthreads();   // drains prefetch vmcnt + protects buffer reuse
    }

    // ---- epilogue: both Q-tiles ----
    const float hs = 1.0f + head_scale[h];
    auto epilogue = [&](int t0, float4v (&oa)[4], float (&lr)[4]) {
        #pragma unroll
        for (int r = 0; r < 4; r++) {
            float l = lr[r];
            l += __shfl_xor(l, 1);
            l += __shfl_xor(l, 2);
            l += __shfl_xor(l, 4);
            l += __shfl_xor(l, 8);
            const int q = t0 + wave * 16 + lg * 4 + r;
            const float f = hs / l;
            u16* op = out + ((size_t)(b * TT + q) * NN) + h * QKD + l15;
            #pragma unroll
            for (int nt = 0; nt < 4; nt++)
                op[nt * 16] = f2bf(oa[nt][r] * f);
        }
    };
    epilogue(t0b, oB, lB);
    epilogue(t0a, oA, lA);
}

// ---------------------------------------------------------------------------
extern "C" void kernel_launch(void* const* d_in, const int* in_sizes, int n_in,
                              void* d_out, int out_size, void* d_ws, size_t ws_size,
                              hipStream_t stream)
{
    const float* q          = (const float*)d_in[0];
    const float* kv         = (const float*)d_in[1];
    /* d_in[2] = causal mask -- handled analytically */
    const int*   qpos       = (const int*)d_in[3];
    const int*   kpos       = (const int*)d_in[4];
    const float* Wq         = (const float*)d_in[5];
    const float* bq         = (const float*)d_in[6];
    const float* Wk         = (const float*)d_in[7];
    const float* bk         = (const float*)d_in[8];
    const float* Wv         = (const float*)d_in[9];
    const float* bv         = (const float*)d_in[10];
    const float* q_scale    = (const float*)d_in[11];
    const float* k_scale    = (const float*)d_in[12];
    const float* head_scale = (const float*)d_in[13];
    const float* Wo         = (const float*)d_in[14];
    const float* bo         = (const float*)d_in[15];
    float* out = (float*)d_out;

    // workspace layout (bytes):
    //   [  0 MB, 16 MB)  qb    (M,K) bf16
    //   [ 16 MB, 32 MB)  kvb   (M,K) bf16
    //   [ 32 MB, 40 MB)  Wt    4 x (N,K) bf16 transposed: Wq,Wk,Wv,Wo
    //   [ 40 MB, 56 MB)  qh_b  (B,H,T,QK) bf16
    //   [ 56 MB, 72 MB)  kh_b  (B,H,T,QK) bf16
    //   [ 72 MB, 88 MB)  vt_b  (B,H,QK,T) bf16  <-- V stored transposed
    //   [ 88 MB,104 MB)  attn_b (B,T,N) bf16
    char* ws = (char*)d_ws;
    u16* qb     = (u16*)(ws);
    u16* kvb    = (u16*)(ws + (16u << 20));
    u16* Wt     = (u16*)(ws + (32u << 20));
    u16* qh_b   = (u16*)(ws + (40u << 20));
    u16* kh_b   = (u16*)(ws + (56u << 20));
    u16* vt_b   = (u16*)(ws + (72u << 20));
    u16* attn_b = (u16*)(ws + (88u << 20));

    // 1. cast activations to bf16
    acast_kernel<<<dim3(MM * DD / (256 * 4), 2), 256, 0, stream>>>(q, kv, qb, kvb);
    // 2. transpose+cast the four weight matrices
    wt_kernel<<<dim3(16, 16, 4), 256, 0, stream>>>(Wq, Wk, Wv, Wo, Wt);
    // 3. fused QKV projection (256^2 tile, 3-buf deep pipeline)
    qkv_gemm<<<dim3(NN / 256, MM / 256, 3), 512, 0, stream>>>(
        qb, kvb, Wt, bq, bk, bv, qpos, kpos, q_scale, k_scale, qh_b, kh_b, vt_b);
    // 4. causal MFMA flash attention, paired complementary Q-tiles -> (B,T,N) bf16
    attn_mfma<<<dim3(TT / 128, HH, BB), 256, 0, stream>>>(qh_b, kh_b, vt_b, head_scale, attn_b);
    // 5. output projection (256^2 tile, 3-buf deep pipeline) + bias -> fp32
    out_gemm<<<dim3(NN / 256, MM / 256), 512, 0, stream>>>(attn_b, Wt + (size_t)3 * KK * NN, bo, out);
}